// Round 3
// baseline (1627.154 us; speedup 1.0000x reference)
//
#include <hip/hip_runtime.h>
#include <math.h>

#define DEV __device__ __forceinline__

constexpr int NB = 2;
constexpr int HI = 512, WI = 896;
constexpr int HO = 256, WO = 448;
constexpr int HWO = HO * WO;   // 114688
constexpr int HWI = HI * WI;   // 458752

// ---------------- downsample (jax.image.resize bilinear, antialias=True, scale 1/2) ----------
// interior weights (1,3,3,1)/8 per dim over inputs 2i-1..2i+2; borders renormalized by the
// sum of in-range weights (matches jax compute_weight_mat + column normalization).
DEV float ds_half(const float* __restrict__ p, int i, int j) {
  const float w4[4] = {1.f, 3.f, 3.f, 1.f};
  float wc[4]; int cc[4];
  float cs = 0.f;
#pragma unroll
  for (int k = 0; k < 4; ++k) {
    int c = 2 * j - 1 + k;
    bool v = (c >= 0) && (c < WI);
    wc[k] = v ? w4[k] : 0.f;
    cc[k] = v ? c : 0;
    cs += wc[k];
  }
  float acc = 0.f, rs = 0.f;
#pragma unroll
  for (int k = 0; k < 4; ++k) {
    int r = 2 * i - 1 + k;
    if (r < 0 || r >= HI) continue;
    const float* row = p + (size_t)r * WI;
    float racc = 0.f;
#pragma unroll
    for (int b = 0; b < 4; ++b) racc += wc[b] * row[cc[b]];
    acc += w4[k] * racc;
    rs += w4[k];
  }
  return acc / (rs * cs);
}

__global__ void ds_enc_kernel(const float* __restrict__ enc, float* __restrict__ t1,
                              float* __restrict__ t2, float* __restrict__ wm) {
  int gid = blockIdx.x * blockDim.x + threadIdx.x;
  int total = NB * 3 * HWO;
  if (gid >= total) return;
  int p = gid % HWO;
  int nc = gid / HWO;
  int c = nc % 3, n = nc / 3;
  int i = p / WO, j = p % WO;
  float v = ds_half(enc + (size_t)(n * 3 + c) * HWI, i, j);
  float* dst = (c == 0) ? t1 : (c == 1 ? t2 : wm);
  dst[(size_t)n * HWO + p] = v;
}

// ---------------- convds first conv: 3x3 stride2 pad1, 3->16, prelu ----------
__global__ void convds1_kernel(const float* __restrict__ x0, const float* __restrict__ x1,
                               const float* __restrict__ x2, const float* __restrict__ w,
                               const float* __restrict__ bias, const float* __restrict__ alpha,
                               float* __restrict__ out /* [3*NB][16][HWO] */) {
  __shared__ float sw[16 * 3 * 9];
  __shared__ float sb[16];
  __shared__ float sa[16];
  for (int idx = threadIdx.x; idx < 432; idx += blockDim.x) sw[idx] = w[idx];
  if (threadIdx.x < 16) { sb[threadIdx.x] = bias[threadIdx.x]; sa[threadIdx.x] = alpha[threadIdx.x]; }
  __syncthreads();
  int gid = blockIdx.x * blockDim.x + threadIdx.x;
  int total = 3 * NB * HWO;
  if (gid >= total) return;
  int p = gid % HWO;
  int ni = gid / HWO;            // img*2 + n
  int img = ni >> 1, n = ni & 1;
  int i = p / WO, j = p % WO;
  const float* x = (img == 0 ? x0 : (img == 1 ? x1 : x2)) + (size_t)n * 3 * HWI;
  float in[27];
  int q = 0;
#pragma unroll
  for (int ci = 0; ci < 3; ++ci)
#pragma unroll
    for (int ky = 0; ky < 3; ++ky) {
      int r = 2 * i + ky - 1;
#pragma unroll
      for (int kx = 0; kx < 3; ++kx) {
        int c = 2 * j + kx - 1;
        in[q++] = (r >= 0 && r < HI && c >= 0 && c < WI) ? x[((size_t)ci * HI + r) * WI + c] : 0.f;
      }
    }
  float* o = out + (size_t)ni * 16 * HWO + p;
#pragma unroll
  for (int co = 0; co < 16; ++co) {
    float acc = sb[co];
    const float* wp = sw + co * 27;
#pragma unroll
    for (int k = 0; k < 27; ++k) acc += wp[k] * in[k];
    o[(size_t)co * HWO] = acc >= 0.f ? acc : sa[co] * acc;
  }
}

// ---------------- generic 3x3 stride1 pad1 conv, per-thread all CO ----------
template <int CI, int CO, bool PRELU>
__global__ void conv3x3_kernel(const float* __restrict__ in, const float* __restrict__ w,
                               const float* __restrict__ bias, const float* __restrict__ alpha,
                               float* __restrict__ out, int B) {
  __shared__ float sw[CO * CI * 9];
  __shared__ float sb[CO];
  __shared__ float sa[CO];
  for (int idx = threadIdx.x; idx < CO * CI * 9; idx += blockDim.x) sw[idx] = w[idx];
  if (threadIdx.x < CO) {
    sb[threadIdx.x] = bias[threadIdx.x];
    sa[threadIdx.x] = PRELU ? alpha[threadIdx.x] : 0.f;
  }
  __syncthreads();
  int gid = blockIdx.x * blockDim.x + threadIdx.x;
  int total = B * HWO;
  if (gid >= total) return;
  int p = gid % HWO, b = gid / HWO;
  int i = p / WO, j = p % WO;
  const float* xb = in + (size_t)b * CI * HWO;
  float acc[CO];
#pragma unroll
  for (int co = 0; co < CO; ++co) acc[co] = sb[co];
  for (int ci = 0; ci < CI; ++ci) {
    const float* xc = xb + (size_t)ci * HWO;
    float taps[9];
    int q = 0;
#pragma unroll
    for (int ky = 0; ky < 3; ++ky) {
      int r = i + ky - 1;
#pragma unroll
      for (int kx = 0; kx < 3; ++kx) {
        int c = j + kx - 1;
        taps[q++] = (r >= 0 && r < HO && c >= 0 && c < WO) ? xc[(size_t)r * WO + c] : 0.f;
      }
    }
#pragma unroll
    for (int co = 0; co < CO; ++co) {
      const float* wp = sw + (co * CI + ci) * 9;
      float s = acc[co];
#pragma unroll
      for (int k = 0; k < 9; ++k) s += wp[k] * taps[k];
      acc[co] = s;
    }
  }
  float* ob = out + (size_t)b * CO * HWO + p;
#pragma unroll
  for (int co = 0; co < CO; ++co) {
    float v = acc[co];
    if (PRELU) v = v >= 0.f ? v : sa[co] * v;
    ob[(size_t)co * HWO] = v;
  }
}

// ---------------- forward splat (fwarp), fused with flow downsample, all 4 flows ----------
// half-res flow fl = 0.5 * ds_half(full-res flow). Splat displacement = s*fl (s = t or 1-t);
// the splatted image is fl itself. ch0 -> col shift, ch1 -> row shift.
// splat buffer layout (u = NB*HWO floats), per side (left=0,right=1), side stride 6u:
//   imgwA [NB][2][HWO] (2u) | imgwB (2u) | nA (u) | nB (u)
DEV void splat_one(float f0, float f1, float s, int n, int i, int j,
                   float* __restrict__ imgw, float* __restrict__ nw) {
  float xr = s * f1;  // row displacement
  float yc = s * f0;  // col displacement
  float x1f = floorf(xr), y1f = floorf(yc);
#pragma unroll
  for (int dx = 0; dx < 2; ++dx)
#pragma unroll
    for (int dy = 0; dy < 2; ++dy) {
      float sx = x1f + (float)dx;
      float sy = y1f + (float)dy;
      float ddx = xr - sx, ddy = yc - sy;
      float wgt = expf(-(ddx * ddx + ddy * ddy));
      int r = (int)sx + i;
      int c = (int)sy + j;
      if (r >= 0 && r < HO && c >= 0 && c < WO) {
        size_t o = (size_t)r * WO + c;
        atomicAdd(&imgw[((size_t)n * 2 + 0) * HWO + o], f0 * wgt);
        atomicAdd(&imgw[((size_t)n * 2 + 1) * HWO + o], f1 * wgt);
        atomicAdd(&nw[(size_t)n * HWO + o], wgt);
      }
    }
}

__global__ void fwarp_all_kernel(const float* __restrict__ flow0, const float* __restrict__ flow1,
                                 const float* __restrict__ flow2, const float* __restrict__ flow3,
                                 const float* __restrict__ t1, const float* __restrict__ t2,
                                 float* __restrict__ S /* 12u splat region, zeroed */) {
  const size_t u = (size_t)NB * HWO;
  int gid = blockIdx.x * blockDim.x + threadIdx.x;
  int total = 2 * NB * HWO;
  if (gid >= total) return;
  int side = gid / (NB * HWO);
  int rem = gid % (NB * HWO);
  int n = rem / HWO, p = rem % HWO;
  int i = p / WO, j = p % WO;
  const float* fA = side ? flow2 : flow0;
  const float* fB = side ? flow3 : flow1;
  const float* t  = side ? t2 : t1;
  float* base = S + (size_t)side * 6 * u;
  float* imgwA = base;
  float* imgwB = base + 2 * u;
  float* nA = base + 4 * u;
  float* nB = base + 5 * u;
  float tv = t[(size_t)n * HWO + p];
  // flow A: displacement t * flA
  {
    float f0 = 0.5f * ds_half(fA + ((size_t)n * 2 + 0) * HWI, i, j);
    float f1 = 0.5f * ds_half(fA + ((size_t)n * 2 + 1) * HWI, i, j);
    splat_one(f0, f1, tv, n, i, j, imgwA, nA);
  }
  // flow B: displacement (1-t) * flB
  {
    float f0 = 0.5f * ds_half(fB + ((size_t)n * 2 + 0) * HWI, i, j);
    float f1 = 0.5f * ds_half(fB + ((size_t)n * 2 + 1) * HWI, i, j);
    splat_one(f0, f1, 1.f - tv, n, i, j, imgwB, nB);
  }
}

__global__ void cfr_all_kernel(const float* __restrict__ S /* 12u splat region */,
                               const float* __restrict__ t1, const float* __restrict__ t2,
                               float* __restrict__ ft0l, float* __restrict__ ft1l,
                               float* __restrict__ ft1r, float* __restrict__ ft2r) {
  const size_t u = (size_t)NB * HWO;
  int gid = blockIdx.x * blockDim.x + threadIdx.x;
  int total = 2 * NB * HWO;
  if (gid >= total) return;
  int side = gid / (NB * HWO);
  int rem = gid % (NB * HWO);
  int n = rem / HWO, p = rem % HWO;
  const float* base = S + (size_t)side * 6 * u;
  const float* f01w = base;
  const float* f10w = base + 2 * u;
  const float* n0 = base + 4 * u;
  const float* n1 = base + 5 * u;
  const float* t = side ? t2 : t1;
  float* ft0 = side ? ft1r : ft0l;
  float* ft1 = side ? ft2r : ft1l;
  size_t np = (size_t)n * HWO + p;
  float tv = t[np];
  float norm = (1.f - tv) * n0[np] + tv * n1[np];
  bool pos = norm > 0.f;
#pragma unroll
  for (int ch = 0; ch < 2; ++ch) {
    size_t idx = ((size_t)n * 2 + ch) * HWO + p;
    float a = f01w[idx];
    float b = f10w[idx];
    float v0 = -(1.f - tv) * tv * a + tv * tv * b;
    float v1 = (1.f - tv) * (1.f - tv) * a - tv * (1.f - tv) * b;
    ft0[idx] = pos ? v0 / norm : v0;
    ft1[idx] = pos ? v1 / norm : v1;
  }
}

// ---------------- masknet conv1: 5x5 pad2, 36->32, prelu (inputs from 4 buffers) ----------
// weight accesses are wave-uniform -> scalar loads; 800 v_fmac per ci-iter vs 25 vector loads.
__global__ void mask_conv1_kernel(const float* __restrict__ xsa, const float* __restrict__ xsb,
                                  const float* __restrict__ fta, const float* __restrict__ ftb,
                                  const float* __restrict__ w, const float* __restrict__ bias,
                                  const float* __restrict__ alpha, float* __restrict__ out) {
  int gid = blockIdx.x * blockDim.x + threadIdx.x;
  int total = NB * HWO;
  if (gid >= total) return;
  int p = gid % HWO, n = gid / HWO;
  int i = p / WO, j = p % WO;
  float acc[32];
#pragma unroll
  for (int co = 0; co < 32; ++co) acc[co] = bias[co];
  for (int ci = 0; ci < 36; ++ci) {
    const float* src;
    if (ci < 16)      src = xsa + (size_t)(n * 16 + ci) * HWO;
    else if (ci < 32) src = xsb + (size_t)(n * 16 + (ci - 16)) * HWO;
    else if (ci < 34) src = fta + (size_t)(n * 2 + (ci - 32)) * HWO;
    else              src = ftb + (size_t)(n * 2 + (ci - 34)) * HWO;
    float taps[25];
    int q = 0;
#pragma unroll
    for (int ky = 0; ky < 5; ++ky) {
      int r = i + ky - 2;
#pragma unroll
      for (int kx = 0; kx < 5; ++kx) {
        int c = j + kx - 2;
        taps[q++] = (r >= 0 && r < HO && c >= 0 && c < WO) ? src[(size_t)r * WO + c] : 0.f;
      }
    }
    const float* wp = w + ci * 25;
#pragma unroll
    for (int co = 0; co < 32; ++co) {
      const float* wq = wp + co * 900;
      float s = acc[co];
#pragma unroll
      for (int k = 0; k < 25; ++k) s += wq[k] * taps[k];
      acc[co] = s;
    }
  }
  float* ob = out + (size_t)n * 32 * HWO + p;
#pragma unroll
  for (int co = 0; co < 32; ++co) {
    float v = acc[co];
    ob[(size_t)co * HWO] = v >= 0.f ? v : alpha[co] * v;
  }
}

// ---------------- backward warp + occlusion blend + final 1x1 conv ----------
DEV float sigmoidf_(float x) { return 1.f / (1.f + expf(-x)); }

DEV void bwarp16(const float* __restrict__ x /* [16][HWO] */, const float* __restrict__ flo /* [2][HWO] */,
                 int p, int i, int j, float* o) {
  float fx = flo[p];
  float fy = flo[HWO + p];
  float gx = (float)j + fx, gy = (float)i + fy;
  float nx = 2.f * gx / (float)(WO - 1) - 1.f;
  float ny = 2.f * gy / (float)(HO - 1) - 1.f;
  float px = ((nx + 1.f) * (float)WO - 1.f) * 0.5f;
  float py = ((ny + 1.f) * (float)HO - 1.f) * 0.5f;
  // image path: clamped (border padding)
  float cx = fminf(fmaxf(px, 0.f), (float)(WO - 1));
  float cy = fminf(fmaxf(py, 0.f), (float)(HO - 1));
  float x0f = floorf(cx), y0f = floorf(cy);
  float wx = cx - x0f, wy = cy - y0f;
  int x0i = (int)x0f; x0i = x0i < 0 ? 0 : (x0i > WO - 1 ? WO - 1 : x0i);
  int y0i = (int)y0f; y0i = y0i < 0 ? 0 : (y0i > HO - 1 ? HO - 1 : y0i);
  int x1i = x0i + 1 > WO - 1 ? WO - 1 : x0i + 1;
  int y1i = y0i + 1 > HO - 1 ? HO - 1 : y0i + 1;
  // mask path: unclamped (zeros padding), threshold 0.999
  float fx0 = floorf(px), fy0 = floorf(py);
  float ux = px - fx0, uy = py - fy0;
  float WOf = (float)WO, HOf = (float)HO;
  float i00 = (fx0 >= 0.f && fx0 < WOf && fy0 >= 0.f && fy0 < HOf) ? 1.f : 0.f;
  float i10 = (fx0 + 1.f >= 0.f && fx0 + 1.f < WOf && fy0 >= 0.f && fy0 < HOf) ? 1.f : 0.f;
  float i01 = (fx0 >= 0.f && fx0 < WOf && fy0 + 1.f >= 0.f && fy0 + 1.f < HOf) ? 1.f : 0.f;
  float i11 = (fx0 + 1.f >= 0.f && fx0 + 1.f < WOf && fy0 + 1.f >= 0.f && fy0 + 1.f < HOf) ? 1.f : 0.f;
  float mv = (1.f - ux) * (1.f - uy) * i00 + ux * (1.f - uy) * i10
           + (1.f - ux) * uy * i01 + ux * uy * i11;
  float mask = mv >= 0.999f ? 1.f : 0.f;
  float w00 = (1.f - wx) * (1.f - wy), w10 = wx * (1.f - wy);
  float w01 = (1.f - wx) * wy, w11 = wx * wy;
  int a00 = y0i * WO + x0i, a10 = y0i * WO + x1i;
  int a01 = y1i * WO + x0i, a11 = y1i * WO + x1i;
#pragma unroll
  for (int c = 0; c < 16; ++c) {
    const float* xc = x + (size_t)c * HWO;
    o[c] = (w00 * xc[a00] + w10 * xc[a10] + w01 * xc[a01] + w11 * xc[a11]) * mask;
  }
}

__global__ void blend_out_kernel(const float* __restrict__ xs0, const float* __restrict__ xs1,
                                 const float* __restrict__ xs2, const float* __restrict__ ft0l,
                                 const float* __restrict__ ft1l, const float* __restrict__ ft1r,
                                 const float* __restrict__ ft2r, const float* __restrict__ occl,
                                 const float* __restrict__ occr, const float* __restrict__ t1,
                                 const float* __restrict__ t2, const float* __restrict__ wm,
                                 const float* __restrict__ fw, const float* __restrict__ fb,
                                 const float* __restrict__ fa,
                                 float* __restrict__ out /* [NB][16][HWO] */) {
  __shared__ float sw[512];
  __shared__ float sb[16];
  __shared__ float sa[16];
  for (int idx = threadIdx.x; idx < 512; idx += blockDim.x) sw[idx] = fw[idx];
  if (threadIdx.x < 16) { sb[threadIdx.x] = fb[threadIdx.x]; sa[threadIdx.x] = fa[threadIdx.x]; }
  __syncthreads();
  int gid = blockIdx.x * blockDim.x + threadIdx.x;
  int total = NB * HWO;
  if (gid >= total) return;
  int p = gid % HWO, n = gid / HWO;
  int i = p / WO, j = p % WO;
  size_t np = (size_t)n * HWO + p;
  float wmv = wm[np];
  float A[16], B[16];
  float bw0[16], bw1[16];
  // left -> A = Ftl * wm
  {
    float t = t1[np];
    float o0 = sigmoidf_(occl[np]);
    float o1 = 1.f - o0;
    bwarp16(xs0 + (size_t)n * 16 * HWO, ft0l + (size_t)n * 2 * HWO, p, i, j, bw0);
    bwarp16(xs1 + (size_t)n * 16 * HWO, ft1l + (size_t)n * 2 * HWO, p, i, j, bw1);
    float c0 = (1.f - t) * o0, c1 = t * o1;
    float r = wmv / (c0 + c1);
#pragma unroll
    for (int c = 0; c < 16; ++c) A[c] = (c0 * bw0[c] + c1 * bw1[c]) * r;
  }
  // right -> B = Ftr * (1-wm)
  {
    float t = t2[np];
    float o0 = sigmoidf_(occr[np]);
    float o1 = 1.f - o0;
    bwarp16(xs1 + (size_t)n * 16 * HWO, ft1r + (size_t)n * 2 * HWO, p, i, j, bw0);
    bwarp16(xs2 + (size_t)n * 16 * HWO, ft2r + (size_t)n * 2 * HWO, p, i, j, bw1);
    float c0 = (1.f - t) * o0, c1 = t * o1;
    float r = (1.f - wmv) / (c0 + c1);
#pragma unroll
    for (int c = 0; c < 16; ++c) B[c] = (c0 * bw0[c] + c1 * bw1[c]) * r;
  }
  // fused 1x1 conv 32->16 + prelu
  float* ob = out + (size_t)n * 16 * HWO + p;
#pragma unroll
  for (int co = 0; co < 16; ++co) {
    float s = sb[co];
    const float* wp = sw + co * 32;
#pragma unroll
    for (int ci = 0; ci < 16; ++ci) s += wp[ci] * A[ci];
#pragma unroll
    for (int ci = 0; ci < 16; ++ci) s += wp[16 + ci] * B[ci];
    ob[(size_t)co * HWO] = s >= 0.f ? s : sa[co] * s;
  }
}

extern "C" void kernel_launch(void* const* d_in, const int* in_sizes, int n_in,
                              void* d_out, int out_size, void* d_ws, size_t ws_size,
                              hipStream_t stream) {
  const float* x0 = (const float*)d_in[0];
  const float* x1 = (const float*)d_in[1];
  const float* x2 = (const float*)d_in[2];
  const float* flw[4] = {(const float*)d_in[3], (const float*)d_in[4],
                         (const float*)d_in[5], (const float*)d_in[6]};
  const float* enc  = (const float*)d_in[7];
  const float* c_w1 = (const float*)d_in[8];
  const float* c_b1 = (const float*)d_in[9];
  const float* c_a1 = (const float*)d_in[10];
  const float* c_w2 = (const float*)d_in[11];
  const float* c_b2 = (const float*)d_in[12];
  const float* c_a2 = (const float*)d_in[13];
  const float* m_w1 = (const float*)d_in[14];
  const float* m_b1 = (const float*)d_in[15];
  const float* m_a1 = (const float*)d_in[16];
  const float* m_w2 = (const float*)d_in[17];
  const float* m_b2 = (const float*)d_in[18];
  const float* m_a2 = (const float*)d_in[19];
  const float* m_w3 = (const float*)d_in[20];
  const float* m_b3 = (const float*)d_in[21];
  const float* f_w  = (const float*)d_in[22];
  const float* f_b  = (const float*)d_in[23];
  const float* f_a  = (const float*)d_in[24];
  float* out = (float*)d_out;

  const size_t u = (size_t)NB * HWO;  // 229376 floats
  float* base = (float*)d_ws;
  size_t off = 0;
  auto alloc = [&](size_t nfl) { float* pp = base + off; off += nfl; return pp; };
  float* t1  = alloc(u);
  float* t2  = alloc(u);
  float* wmb = alloc(u);
  float* xs   = alloc(48 * u);  // [3][NB][16][HWO] convds output
  float* xsc1 = alloc(48 * u);  // convds1 scratch; later mn1 (32u) + mn2 (16u)
  float* splat = alloc(12 * u); // [2 sides][imgwA 2u | imgwB 2u | nA u | nB u]
  float* ft0l = alloc(2 * u);
  float* ft1l = alloc(2 * u);
  float* ft1r = alloc(2 * u);
  float* ft2r = alloc(2 * u);
  float* occl = alloc(u);
  float* occr = alloc(u);
  float* mn1 = xsc1;                 // [NB][32][HWO] = 32u
  float* mn2 = xsc1 + 32 * u;        // [NB][16][HWO] = 16u

  const int TPB = 256;
  auto NBLK = [](long long t) { return (unsigned)((t + 255) / 256); };

  ds_enc_kernel<<<NBLK((long long)NB * 3 * HWO), TPB, 0, stream>>>(enc, t1, t2, wmb);

  convds1_kernel<<<NBLK((long long)3 * NB * HWO), TPB, 0, stream>>>(x0, x1, x2, c_w1, c_b1, c_a1, xsc1);
  conv3x3_kernel<16, 16, true><<<NBLK((long long)3 * NB * HWO), TPB, 0, stream>>>(
      xsc1, c_w2, c_b2, c_a2, xs, 3 * NB);

  // flow splat path: one memset, one fused splat over both sides, one combine
  hipMemsetAsync(splat, 0, 12 * u * sizeof(float), stream);
  fwarp_all_kernel<<<NBLK((long long)2 * NB * HWO), TPB, 0, stream>>>(
      flw[0], flw[1], flw[2], flw[3], t1, t2, splat);
  cfr_all_kernel<<<NBLK((long long)2 * NB * HWO), TPB, 0, stream>>>(
      splat, t1, t2, ft0l, ft1l, ft1r, ft2r);

  const float* xs0 = xs;
  const float* xs1s = xs + 16 * u;
  const float* xs2s = xs + 32 * u;

  // masknet left
  mask_conv1_kernel<<<NBLK((long long)NB * HWO), TPB, 0, stream>>>(xs0, xs1s, ft0l, ft1l,
                                                                   m_w1, m_b1, m_a1, mn1);
  conv3x3_kernel<32, 16, true><<<NBLK((long long)NB * HWO), TPB, 0, stream>>>(mn1, m_w2, m_b2, m_a2, mn2, NB);
  conv3x3_kernel<16, 1, false><<<NBLK((long long)NB * HWO), TPB, 0, stream>>>(mn2, m_w3, m_b3, m_b3, occl, NB);
  // masknet right
  mask_conv1_kernel<<<NBLK((long long)NB * HWO), TPB, 0, stream>>>(xs1s, xs2s, ft1r, ft2r,
                                                                   m_w1, m_b1, m_a1, mn1);
  conv3x3_kernel<32, 16, true><<<NBLK((long long)NB * HWO), TPB, 0, stream>>>(mn1, m_w2, m_b2, m_a2, mn2, NB);
  conv3x3_kernel<16, 1, false><<<NBLK((long long)NB * HWO), TPB, 0, stream>>>(mn2, m_w3, m_b3, m_b3, occr, NB);

  // blend + fused final 1x1 -> d_out
  blend_out_kernel<<<NBLK((long long)NB * HWO), TPB, 0, stream>>>(
      xs0, xs1s, xs2s, ft0l, ft1l, ft1r, ft2r, occl, occr, t1, t2, wmb, f_w, f_b, f_a, out);
}

// Round 4
// 1543.211 us; speedup vs baseline: 1.0544x; 1.0544x over previous
//
#include <hip/hip_runtime.h>
#include <math.h>

#define DEV __device__ __forceinline__

constexpr int NB = 2;
constexpr int HI = 512, WI = 896;
constexpr int HO = 256, WO = 448;
constexpr int HWO = HO * WO;   // 114688
constexpr int HWI = HI * WI;   // 458752

// ---------------- downsample (jax.image.resize bilinear, antialias=True, scale 1/2) ----------
DEV float ds_half(const float* __restrict__ p, int i, int j) {
  const float w4[4] = {1.f, 3.f, 3.f, 1.f};
  float wc[4]; int cc[4];
  float cs = 0.f;
#pragma unroll
  for (int k = 0; k < 4; ++k) {
    int c = 2 * j - 1 + k;
    bool v = (c >= 0) && (c < WI);
    wc[k] = v ? w4[k] : 0.f;
    cc[k] = v ? c : 0;
    cs += wc[k];
  }
  float acc = 0.f, rs = 0.f;
#pragma unroll
  for (int k = 0; k < 4; ++k) {
    int r = 2 * i - 1 + k;
    if (r < 0 || r >= HI) continue;
    const float* row = p + (size_t)r * WI;
    float racc = 0.f;
#pragma unroll
    for (int b = 0; b < 4; ++b) racc += wc[b] * row[cc[b]];
    acc += w4[k] * racc;
    rs += w4[k];
  }
  return acc / (rs * cs);
}

__global__ void ds_enc_kernel(const float* __restrict__ enc, float* __restrict__ t1,
                              float* __restrict__ t2, float* __restrict__ wm) {
  int gid = blockIdx.x * blockDim.x + threadIdx.x;
  int total = NB * 3 * HWO;
  if (gid >= total) return;
  int p = gid % HWO;
  int nc = gid / HWO;
  int c = nc % 3, n = nc / 3;
  int i = p / WO, j = p % WO;
  float v = ds_half(enc + (size_t)(n * 3 + c) * HWI, i, j);
  float* dst = (c == 0) ? t1 : (c == 1 ? t2 : wm);
  dst[(size_t)n * HWO + p] = v;
}

// ---------------- weight transpose: [CO][CI][KK] -> [CI][KK][CO] ----------
__global__ void wtrans_kernel(const float* __restrict__ w, float* __restrict__ wT,
                              int CO, int CI, int KK) {
  int idx = blockIdx.x * blockDim.x + threadIdx.x;
  int total = CO * CI * KK;
  if (idx >= total) return;
  int co = idx / (CI * KK);
  int r = idx % (CI * KK);
  int ci = r / KK, k = r % KK;
  wT[((size_t)ci * KK + k) * CO + co] = w[idx];
}

// ---------------- convds first conv: 3x3 stride2 pad1, 3->16, prelu ----------
// b = n*3+img so outputs land n-major: [NB][3][16][HWO]
__global__ void convds1_kernel(const float* __restrict__ x0, const float* __restrict__ x1,
                               const float* __restrict__ x2, const float* __restrict__ w,
                               const float* __restrict__ bias, const float* __restrict__ alpha,
                               float* __restrict__ out) {
  __shared__ float sw[16 * 3 * 9];
  __shared__ float sb[16];
  __shared__ float sa[16];
  for (int idx = threadIdx.x; idx < 432; idx += blockDim.x) sw[idx] = w[idx];
  if (threadIdx.x < 16) { sb[threadIdx.x] = bias[threadIdx.x]; sa[threadIdx.x] = alpha[threadIdx.x]; }
  __syncthreads();
  int gid = blockIdx.x * blockDim.x + threadIdx.x;
  int total = 3 * NB * HWO;
  if (gid >= total) return;
  int p = gid % HWO;
  int ni = gid / HWO;            // n*3+img
  int n = ni / 3, img = ni % 3;
  int i = p / WO, j = p % WO;
  const float* x = (img == 0 ? x0 : (img == 1 ? x1 : x2)) + (size_t)n * 3 * HWI;
  float in[27];
  int q = 0;
#pragma unroll
  for (int ci = 0; ci < 3; ++ci)
#pragma unroll
    for (int ky = 0; ky < 3; ++ky) {
      int r = 2 * i + ky - 1;
#pragma unroll
      for (int kx = 0; kx < 3; ++kx) {
        int c = 2 * j + kx - 1;
        in[q++] = (r >= 0 && r < HI && c >= 0 && c < WI) ? x[((size_t)ci * HI + r) * WI + c] : 0.f;
      }
    }
  float* o = out + (size_t)ni * 16 * HWO + p;
#pragma unroll
  for (int co = 0; co < 16; ++co) {
    float acc = sb[co];
    const float* wp = sw + co * 27;
#pragma unroll
    for (int k = 0; k < 27; ++k) acc += wp[k] * in[k];
    o[(size_t)co * HWO] = acc >= 0.f ? acc : sa[co] * acc;
  }
}

// ---------------- generic conv, stride1, 2 px/thread, LDS-staged transposed weights ----------
// weights wT layout [CI][KS*KS][CO]; per-ci slice double-buffered in LDS; broadcast
// ds_read_b128 gives 4 weights -> 8 FMA per LDS read. Input channels come from two
// buffers: ci<CI1 -> in1 + b*s1, else in2 + b*s2. Grid must exactly cover B*HWO/2 threads.
template <int CI1, int CI2, int CO, int KS, bool PRELU>
__global__ void conv2px_kernel(const float* __restrict__ in1, long s1,
                               const float* __restrict__ in2, long s2,
                               const float* __restrict__ wT, const float* __restrict__ bias,
                               const float* __restrict__ alpha,
                               float* __restrict__ out, long so) {
  constexpr int CI = CI1 + CI2;
  constexpr int KK = KS * KS;
  constexpr int WSL = KK * CO;       // weights per ci-slice (multiple of 4)
  constexpr int PAD = KS / 2;
  __shared__ __align__(16) float sw[2][WSL];
  __shared__ float sb[CO];
  __shared__ float sa[CO];
  int tx = threadIdx.x;
  if (tx < CO) { sb[tx] = bias[tx]; sa[tx] = PRELU ? alpha[tx] : 0.f; }
  for (int idx = tx; idx < WSL; idx += blockDim.x) sw[0][idx] = wT[idx];
  __syncthreads();

  int tid = blockIdx.x * blockDim.x + tx;
  int p0 = tid * 2;
  int b = p0 / HWO, p = p0 % HWO;
  int i = p / WO, j = p % WO;      // j even; j+1 in same row (WO even)

  float acc[CO][2];
#pragma unroll
  for (int co = 0; co < CO; ++co) { acc[co][0] = sb[co]; acc[co][1] = sb[co]; }

  for (int ci = 0; ci < CI; ++ci) {
    // prefetch next weight slice (completes before use: barrier at loop end)
    if (ci + 1 < CI) {
      const float* nsrc = wT + (size_t)(ci + 1) * WSL;
      float* ndst = sw[(ci + 1) & 1];
      for (int idx = tx; idx < WSL; idx += blockDim.x) ndst[idx] = nsrc[idx];
    }
    const float* xc = (ci < CI1) ? in1 + (size_t)b * s1 + (size_t)ci * HWO
                                 : in2 + (size_t)b * s2 + (size_t)(ci - CI1) * HWO;
    float taps[KS][KS + 1];
#pragma unroll
    for (int ky = 0; ky < KS; ++ky) {
      int r = i + ky - PAD;
      bool rv = (r >= 0) && (r < HO);
      const float* row = xc + (size_t)r * WO;
#pragma unroll
      for (int kx = 0; kx <= KS; ++kx) {
        int c = j + kx - PAD;
        taps[ky][kx] = (rv && c >= 0 && c < WO) ? row[c] : 0.f;
      }
    }
    const float* wsl = sw[ci & 1];
#pragma unroll
    for (int ky = 0; ky < KS; ++ky)
#pragma unroll
      for (int kx = 0; kx < KS; ++kx) {
        float t0 = taps[ky][kx];
        float t1 = taps[ky][kx + 1];
        int k = ky * KS + kx;
#pragma unroll
        for (int cq = 0; cq < CO / 4; ++cq) {
          const float4 wv = *reinterpret_cast<const float4*>(&wsl[k * CO + cq * 4]);
          acc[cq * 4 + 0][0] += wv.x * t0; acc[cq * 4 + 0][1] += wv.x * t1;
          acc[cq * 4 + 1][0] += wv.y * t0; acc[cq * 4 + 1][1] += wv.y * t1;
          acc[cq * 4 + 2][0] += wv.z * t0; acc[cq * 4 + 2][1] += wv.z * t1;
          acc[cq * 4 + 3][0] += wv.w * t0; acc[cq * 4 + 3][1] += wv.w * t1;
        }
      }
    __syncthreads();
  }
  float* ob = out + (size_t)b * so + p;
#pragma unroll
  for (int co = 0; co < CO; ++co) {
    float v0 = acc[co][0], v1 = acc[co][1];
    if (PRELU) {
      v0 = v0 >= 0.f ? v0 : sa[co] * v0;
      v1 = v1 >= 0.f ? v1 : sa[co] * v1;
    }
    ob[(size_t)co * HWO] = v0;
    ob[(size_t)co * HWO + 1] = v1;
  }
}

// ---------------- small generic 3x3 conv (kept for 16->1) ----------
template <int CI, int CO, bool PRELU>
__global__ void conv3x3_kernel(const float* __restrict__ in, const float* __restrict__ w,
                               const float* __restrict__ bias, const float* __restrict__ alpha,
                               float* __restrict__ out, int B) {
  __shared__ float sw[CO * CI * 9];
  __shared__ float sb[CO];
  __shared__ float sa[CO];
  for (int idx = threadIdx.x; idx < CO * CI * 9; idx += blockDim.x) sw[idx] = w[idx];
  if (threadIdx.x < CO) {
    sb[threadIdx.x] = bias[threadIdx.x];
    sa[threadIdx.x] = PRELU ? alpha[threadIdx.x] : 0.f;
  }
  __syncthreads();
  int gid = blockIdx.x * blockDim.x + threadIdx.x;
  int total = B * HWO;
  if (gid >= total) return;
  int p = gid % HWO, b = gid / HWO;
  int i = p / WO, j = p % WO;
  const float* xb = in + (size_t)b * CI * HWO;
  float acc[CO];
#pragma unroll
  for (int co = 0; co < CO; ++co) acc[co] = sb[co];
  for (int ci = 0; ci < CI; ++ci) {
    const float* xc = xb + (size_t)ci * HWO;
    float taps[9];
    int q = 0;
#pragma unroll
    for (int ky = 0; ky < 3; ++ky) {
      int r = i + ky - 1;
#pragma unroll
      for (int kx = 0; kx < 3; ++kx) {
        int c = j + kx - 1;
        taps[q++] = (r >= 0 && r < HO && c >= 0 && c < WO) ? xc[(size_t)r * WO + c] : 0.f;
      }
    }
#pragma unroll
    for (int co = 0; co < CO; ++co) {
      const float* wp = sw + (co * CI + ci) * 9;
      float s = acc[co];
#pragma unroll
      for (int k = 0; k < 9; ++k) s += wp[k] * taps[k];
      acc[co] = s;
    }
  }
  float* ob = out + (size_t)b * CO * HWO + p;
#pragma unroll
  for (int co = 0; co < CO; ++co) {
    float v = acc[co];
    if (PRELU) v = v >= 0.f ? v : sa[co] * v;
    ob[(size_t)co * HWO] = v;
  }
}

// ---------------- forward splat (fwarp), fused with flow downsample, all 4 flows ----------
DEV void splat_one(float f0, float f1, float s, int n, int i, int j,
                   float* __restrict__ imgw, float* __restrict__ nw) {
  float xr = s * f1;  // row displacement
  float yc = s * f0;  // col displacement
  float x1f = floorf(xr), y1f = floorf(yc);
#pragma unroll
  for (int dx = 0; dx < 2; ++dx)
#pragma unroll
    for (int dy = 0; dy < 2; ++dy) {
      float sx = x1f + (float)dx;
      float sy = y1f + (float)dy;
      float ddx = xr - sx, ddy = yc - sy;
      float wgt = expf(-(ddx * ddx + ddy * ddy));
      int r = (int)sx + i;
      int c = (int)sy + j;
      if (r >= 0 && r < HO && c >= 0 && c < WO) {
        size_t o = (size_t)r * WO + c;
        atomicAdd(&imgw[((size_t)n * 2 + 0) * HWO + o], f0 * wgt);
        atomicAdd(&imgw[((size_t)n * 2 + 1) * HWO + o], f1 * wgt);
        atomicAdd(&nw[(size_t)n * HWO + o], wgt);
      }
    }
}

__global__ void fwarp_all_kernel(const float* __restrict__ flow0, const float* __restrict__ flow1,
                                 const float* __restrict__ flow2, const float* __restrict__ flow3,
                                 const float* __restrict__ t1, const float* __restrict__ t2,
                                 float* __restrict__ S /* 12u splat region, zeroed */) {
  const size_t u = (size_t)NB * HWO;
  int gid = blockIdx.x * blockDim.x + threadIdx.x;
  int total = 2 * NB * HWO;
  if (gid >= total) return;
  int side = gid / (NB * HWO);
  int rem = gid % (NB * HWO);
  int n = rem / HWO, p = rem % HWO;
  int i = p / WO, j = p % WO;
  const float* fA = side ? flow2 : flow0;
  const float* fB = side ? flow3 : flow1;
  const float* t  = side ? t2 : t1;
  float* base = S + (size_t)side * 6 * u;
  float* imgwA = base;
  float* imgwB = base + 2 * u;
  float* nA = base + 4 * u;
  float* nB = base + 5 * u;
  float tv = t[(size_t)n * HWO + p];
  {
    float f0 = 0.5f * ds_half(fA + ((size_t)n * 2 + 0) * HWI, i, j);
    float f1 = 0.5f * ds_half(fA + ((size_t)n * 2 + 1) * HWI, i, j);
    splat_one(f0, f1, tv, n, i, j, imgwA, nA);
  }
  {
    float f0 = 0.5f * ds_half(fB + ((size_t)n * 2 + 0) * HWI, i, j);
    float f1 = 0.5f * ds_half(fB + ((size_t)n * 2 + 1) * HWI, i, j);
    splat_one(f0, f1, 1.f - tv, n, i, j, imgwB, nB);
  }
}

// combine -> ftL [NB][4][HWO] = (ft0l ch0,ch1, ft1l ch0,ch1); ftR likewise (ft1r, ft2r)
__global__ void cfr_all_kernel(const float* __restrict__ S,
                               const float* __restrict__ t1, const float* __restrict__ t2,
                               float* __restrict__ ftL, float* __restrict__ ftR) {
  const size_t u = (size_t)NB * HWO;
  int gid = blockIdx.x * blockDim.x + threadIdx.x;
  int total = 2 * NB * HWO;
  if (gid >= total) return;
  int side = gid / (NB * HWO);
  int rem = gid % (NB * HWO);
  int n = rem / HWO, p = rem % HWO;
  const float* base = S + (size_t)side * 6 * u;
  const float* f01w = base;
  const float* f10w = base + 2 * u;
  const float* n0 = base + 4 * u;
  const float* n1 = base + 5 * u;
  const float* t = side ? t2 : t1;
  float* ft = side ? ftR : ftL;
  size_t np = (size_t)n * HWO + p;
  float tv = t[np];
  float norm = (1.f - tv) * n0[np] + tv * n1[np];
  bool pos = norm > 0.f;
#pragma unroll
  for (int ch = 0; ch < 2; ++ch) {
    size_t sidx = ((size_t)n * 2 + ch) * HWO + p;
    float a = f01w[sidx];
    float b = f10w[sidx];
    float v0 = -(1.f - tv) * tv * a + tv * tv * b;
    float v1 = (1.f - tv) * (1.f - tv) * a - tv * (1.f - tv) * b;
    ft[((size_t)n * 4 + ch) * HWO + p]     = pos ? v0 / norm : v0;
    ft[((size_t)n * 4 + 2 + ch) * HWO + p] = pos ? v1 / norm : v1;
  }
}

// ---------------- backward warp + occlusion blend + final 1x1 conv ----------
DEV float sigmoidf_(float x) { return 1.f / (1.f + expf(-x)); }

DEV void bwarp16(const float* __restrict__ x /* [16][HWO] */, const float* __restrict__ flo /* [2][HWO] */,
                 int p, int i, int j, float* o) {
  float fx = flo[p];
  float fy = flo[HWO + p];
  float gx = (float)j + fx, gy = (float)i + fy;
  float nx = 2.f * gx / (float)(WO - 1) - 1.f;
  float ny = 2.f * gy / (float)(HO - 1) - 1.f;
  float px = ((nx + 1.f) * (float)WO - 1.f) * 0.5f;
  float py = ((ny + 1.f) * (float)HO - 1.f) * 0.5f;
  float cx = fminf(fmaxf(px, 0.f), (float)(WO - 1));
  float cy = fminf(fmaxf(py, 0.f), (float)(HO - 1));
  float x0f = floorf(cx), y0f = floorf(cy);
  float wx = cx - x0f, wy = cy - y0f;
  int x0i = (int)x0f; x0i = x0i < 0 ? 0 : (x0i > WO - 1 ? WO - 1 : x0i);
  int y0i = (int)y0f; y0i = y0i < 0 ? 0 : (y0i > HO - 1 ? HO - 1 : y0i);
  int x1i = x0i + 1 > WO - 1 ? WO - 1 : x0i + 1;
  int y1i = y0i + 1 > HO - 1 ? HO - 1 : y0i + 1;
  float fx0 = floorf(px), fy0 = floorf(py);
  float ux = px - fx0, uy = py - fy0;
  float WOf = (float)WO, HOf = (float)HO;
  float i00 = (fx0 >= 0.f && fx0 < WOf && fy0 >= 0.f && fy0 < HOf) ? 1.f : 0.f;
  float i10 = (fx0 + 1.f >= 0.f && fx0 + 1.f < WOf && fy0 >= 0.f && fy0 < HOf) ? 1.f : 0.f;
  float i01 = (fx0 >= 0.f && fx0 < WOf && fy0 + 1.f >= 0.f && fy0 + 1.f < HOf) ? 1.f : 0.f;
  float i11 = (fx0 + 1.f >= 0.f && fx0 + 1.f < WOf && fy0 + 1.f >= 0.f && fy0 + 1.f < HOf) ? 1.f : 0.f;
  float mv = (1.f - ux) * (1.f - uy) * i00 + ux * (1.f - uy) * i10
           + (1.f - ux) * uy * i01 + ux * uy * i11;
  float mask = mv >= 0.999f ? 1.f : 0.f;
  float w00 = (1.f - wx) * (1.f - wy), w10 = wx * (1.f - wy);
  float w01 = (1.f - wx) * wy, w11 = wx * wy;
  int a00 = y0i * WO + x0i, a10 = y0i * WO + x1i;
  int a01 = y1i * WO + x0i, a11 = y1i * WO + x1i;
#pragma unroll
  for (int c = 0; c < 16; ++c) {
    const float* xc = x + (size_t)c * HWO;
    o[c] = (w00 * xc[a00] + w10 * xc[a10] + w01 * xc[a01] + w11 * xc[a11]) * mask;
  }
}

__global__ void blend_out_kernel(const float* __restrict__ xs /* [NB][48][HWO] */,
                                 const float* __restrict__ ftL, const float* __restrict__ ftR,
                                 const float* __restrict__ occl, const float* __restrict__ occr,
                                 const float* __restrict__ t1, const float* __restrict__ t2,
                                 const float* __restrict__ wm,
                                 const float* __restrict__ fw, const float* __restrict__ fb,
                                 const float* __restrict__ fa,
                                 float* __restrict__ out /* [NB][16][HWO] */) {
  __shared__ float sw[512];
  __shared__ float sb[16];
  __shared__ float sa[16];
  for (int idx = threadIdx.x; idx < 512; idx += blockDim.x) sw[idx] = fw[idx];
  if (threadIdx.x < 16) { sb[threadIdx.x] = fb[threadIdx.x]; sa[threadIdx.x] = fa[threadIdx.x]; }
  __syncthreads();
  int gid = blockIdx.x * blockDim.x + threadIdx.x;
  int total = NB * HWO;
  if (gid >= total) return;
  int p = gid % HWO, n = gid / HWO;
  int i = p / WO, j = p % WO;
  size_t np = (size_t)n * HWO + p;
  float wmv = wm[np];
  const float* xs0 = xs + (size_t)n * 48 * HWO;
  const float* xs1 = xs0 + (size_t)16 * HWO;
  const float* xs2 = xs0 + (size_t)32 * HWO;
  const float* fl = ftL + (size_t)n * 4 * HWO;
  const float* fr = ftR + (size_t)n * 4 * HWO;
  float A[16], B[16];
  float bw0[16], bw1[16];
  {
    float t = t1[np];
    float o0 = sigmoidf_(occl[np]);
    float o1 = 1.f - o0;
    bwarp16(xs0, fl, p, i, j, bw0);
    bwarp16(xs1, fl + (size_t)2 * HWO, p, i, j, bw1);
    float c0 = (1.f - t) * o0, c1 = t * o1;
    float r = wmv / (c0 + c1);
#pragma unroll
    for (int c = 0; c < 16; ++c) A[c] = (c0 * bw0[c] + c1 * bw1[c]) * r;
  }
  {
    float t = t2[np];
    float o0 = sigmoidf_(occr[np]);
    float o1 = 1.f - o0;
    bwarp16(xs1, fr, p, i, j, bw0);
    bwarp16(xs2, fr + (size_t)2 * HWO, p, i, j, bw1);
    float c0 = (1.f - t) * o0, c1 = t * o1;
    float r = (1.f - wmv) / (c0 + c1);
#pragma unroll
    for (int c = 0; c < 16; ++c) B[c] = (c0 * bw0[c] + c1 * bw1[c]) * r;
  }
  float* ob = out + (size_t)n * 16 * HWO + p;
#pragma unroll
  for (int co = 0; co < 16; ++co) {
    float s = sb[co];
    const float* wp = sw + co * 32;
#pragma unroll
    for (int ci = 0; ci < 16; ++ci) s += wp[ci] * A[ci];
#pragma unroll
    for (int ci = 0; ci < 16; ++ci) s += wp[16 + ci] * B[ci];
    ob[(size_t)co * HWO] = s >= 0.f ? s : sa[co] * s;
  }
}

extern "C" void kernel_launch(void* const* d_in, const int* in_sizes, int n_in,
                              void* d_out, int out_size, void* d_ws, size_t ws_size,
                              hipStream_t stream) {
  const float* x0 = (const float*)d_in[0];
  const float* x1 = (const float*)d_in[1];
  const float* x2 = (const float*)d_in[2];
  const float* flw[4] = {(const float*)d_in[3], (const float*)d_in[4],
                         (const float*)d_in[5], (const float*)d_in[6]};
  const float* enc  = (const float*)d_in[7];
  const float* c_w1 = (const float*)d_in[8];
  const float* c_b1 = (const float*)d_in[9];
  const float* c_a1 = (const float*)d_in[10];
  const float* c_w2 = (const float*)d_in[11];
  const float* c_b2 = (const float*)d_in[12];
  const float* c_a2 = (const float*)d_in[13];
  const float* m_w1 = (const float*)d_in[14];
  const float* m_b1 = (const float*)d_in[15];
  const float* m_a1 = (const float*)d_in[16];
  const float* m_w2 = (const float*)d_in[17];
  const float* m_b2 = (const float*)d_in[18];
  const float* m_a2 = (const float*)d_in[19];
  const float* m_w3 = (const float*)d_in[20];
  const float* m_b3 = (const float*)d_in[21];
  const float* f_w  = (const float*)d_in[22];
  const float* f_b  = (const float*)d_in[23];
  const float* f_a  = (const float*)d_in[24];
  float* out = (float*)d_out;

  const size_t u = (size_t)NB * HWO;  // 229376 floats
  float* base = (float*)d_ws;
  size_t off = 0;
  auto alloc = [&](size_t nfl) { float* pp = base + off; off += nfl; return pp; };
  float* t1  = alloc(u);
  float* t2  = alloc(u);
  float* wmb = alloc(u);
  float* xs   = alloc(48 * u);  // [NB][48][HWO] convds output (n-major)
  float* xsc1 = alloc(48 * u);  // convds1 scratch; later mn1 (32u) + mn2 (16u)
  float* splat = alloc(12 * u); // [2 sides][imgwA 2u | imgwB 2u | nA u | nB u]
  float* ftL = alloc(4 * u);    // [NB][4][HWO] = ft0l, ft1l
  float* ftR = alloc(4 * u);    // [NB][4][HWO] = ft1r, ft2r
  float* occl = alloc(u);
  float* occr = alloc(u);
  float* wT1  = alloc(36 * 25 * 32);  // mask conv1 weights [ci][k][co]
  float* wTc2 = alloc(16 * 9 * 16);   // convds2 weights
  float* wTm2 = alloc(32 * 9 * 16);   // mask conv2 weights
  float* mn1 = xsc1;                  // [NB][32][HWO] = 32u
  float* mn2 = xsc1 + 32 * u;         // [NB][16][HWO] = 16u

  const int TPB = 256;
  auto NBLK = [](long long t) { return (unsigned)((t + 255) / 256); };

  // weight transposes (tiny)
  wtrans_kernel<<<NBLK(32 * 36 * 25), TPB, 0, stream>>>(m_w1, wT1, 32, 36, 25);
  wtrans_kernel<<<NBLK(16 * 16 * 9), TPB, 0, stream>>>(c_w2, wTc2, 16, 16, 9);
  wtrans_kernel<<<NBLK(16 * 32 * 9), TPB, 0, stream>>>(m_w2, wTm2, 16, 32, 9);

  ds_enc_kernel<<<NBLK((long long)NB * 3 * HWO), TPB, 0, stream>>>(enc, t1, t2, wmb);

  convds1_kernel<<<NBLK((long long)3 * NB * HWO), TPB, 0, stream>>>(x0, x1, x2, c_w1, c_b1, c_a1, xsc1);
  // convds2: 16->16 3x3 over 6 batches (b = n*3+img) -> xs [NB][48][HWO]
  conv2px_kernel<16, 0, 16, 3, true><<<(unsigned)(6LL * HWO / 2 / TPB), TPB, 0, stream>>>(
      xsc1, 16L * HWO, nullptr, 0, wTc2, c_b2, c_a2, xs, 16L * HWO);

  // flow splat path
  hipMemsetAsync(splat, 0, 12 * u * sizeof(float), stream);
  fwarp_all_kernel<<<NBLK((long long)2 * NB * HWO), TPB, 0, stream>>>(
      flw[0], flw[1], flw[2], flw[3], t1, t2, splat);
  cfr_all_kernel<<<NBLK((long long)2 * NB * HWO), TPB, 0, stream>>>(splat, t1, t2, ftL, ftR);

  // masknet left: input = xs[n][0:32] ++ ftL[n][0:4]
  conv2px_kernel<32, 4, 32, 5, true><<<(unsigned)((long long)NB * HWO / 2 / TPB), TPB, 0, stream>>>(
      xs, 48L * HWO, ftL, 4L * HWO, wT1, m_b1, m_a1, mn1, 32L * HWO);
  conv2px_kernel<32, 0, 16, 3, true><<<(unsigned)((long long)NB * HWO / 2 / TPB), TPB, 0, stream>>>(
      mn1, 32L * HWO, nullptr, 0, wTm2, m_b2, m_a2, mn2, 16L * HWO);
  conv3x3_kernel<16, 1, false><<<NBLK((long long)NB * HWO), TPB, 0, stream>>>(mn2, m_w3, m_b3, m_b3, occl, NB);
  // masknet right: input = xs[n][16:48] ++ ftR[n][0:4]
  conv2px_kernel<32, 4, 32, 5, true><<<(unsigned)((long long)NB * HWO / 2 / TPB), TPB, 0, stream>>>(
      xs + (size_t)16 * HWO, 48L * HWO, ftR, 4L * HWO, wT1, m_b1, m_a1, mn1, 32L * HWO);
  conv2px_kernel<32, 0, 16, 3, true><<<(unsigned)((long long)NB * HWO / 2 / TPB), TPB, 0, stream>>>(
      mn1, 32L * HWO, nullptr, 0, wTm2, m_b2, m_a2, mn2, 16L * HWO);
  conv3x3_kernel<16, 1, false><<<NBLK((long long)NB * HWO), TPB, 0, stream>>>(mn2, m_w3, m_b3, m_b3, occr, NB);

  // blend + fused final 1x1 -> d_out
  blend_out_kernel<<<NBLK((long long)NB * HWO), TPB, 0, stream>>>(
      xs, ftL, ftR, occl, occr, t1, t2, wmb, f_w, f_b, f_a, out);
}

// Round 5
// 1068.145 us; speedup vs baseline: 1.5233x; 1.4448x over previous
//
#include <hip/hip_runtime.h>
#include <math.h>

#define DEV __device__ __forceinline__

constexpr int NB = 2;
constexpr int HI = 512, WI = 896;
constexpr int HO = 256, WO = 448;
constexpr int HWO = HO * WO;   // 114688
constexpr int HWI = HI * WI;   // 458752

// ---------------- downsample (jax.image.resize bilinear, antialias=True, scale 1/2) ----------
DEV float ds_half(const float* __restrict__ p, int i, int j) {
  const float w4[4] = {1.f, 3.f, 3.f, 1.f};
  float wc[4]; int cc[4];
  float cs = 0.f;
#pragma unroll
  for (int k = 0; k < 4; ++k) {
    int c = 2 * j - 1 + k;
    bool v = (c >= 0) && (c < WI);
    wc[k] = v ? w4[k] : 0.f;
    cc[k] = v ? c : 0;
    cs += wc[k];
  }
  float acc = 0.f, rs = 0.f;
#pragma unroll
  for (int k = 0; k < 4; ++k) {
    int r = 2 * i - 1 + k;
    if (r < 0 || r >= HI) continue;
    const float* row = p + (size_t)r * WI;
    float racc = 0.f;
#pragma unroll
    for (int b = 0; b < 4; ++b) racc += wc[b] * row[cc[b]];
    acc += w4[k] * racc;
    rs += w4[k];
  }
  return acc / (rs * cs);
}

__global__ void ds_enc_kernel(const float* __restrict__ enc, float* __restrict__ t1,
                              float* __restrict__ t2, float* __restrict__ wm) {
  int gid = blockIdx.x * blockDim.x + threadIdx.x;
  int total = NB * 3 * HWO;
  if (gid >= total) return;
  int p = gid % HWO;
  int nc = gid / HWO;
  int c = nc % 3, n = nc / 3;
  int i = p / WO, j = p % WO;
  float v = ds_half(enc + (size_t)(n * 3 + c) * HWI, i, j);
  float* dst = (c == 0) ? t1 : (c == 1 ? t2 : wm);
  dst[(size_t)n * HWO + p] = v;
}

// ---------------- weight transpose: [CO][CI][KK] -> [CI][KK][CO] ----------
__global__ void wtrans_kernel(const float* __restrict__ w, float* __restrict__ wT,
                              int CO, int CI, int KK) {
  int idx = blockIdx.x * blockDim.x + threadIdx.x;
  int total = CO * CI * KK;
  if (idx >= total) return;
  int co = idx / (CI * KK);
  int r = idx % (CI * KK);
  int ci = r / KK, k = r % KK;
  wT[((size_t)ci * KK + k) * CO + co] = w[idx];
}

// ---------------- convds first conv: 3x3 stride2 pad1, 3->16, prelu ----------
// b = n*3+img so outputs land n-major: [NB][3][16][HWO]
__global__ void __launch_bounds__(256, 2)
convds1_kernel(const float* __restrict__ x0, const float* __restrict__ x1,
               const float* __restrict__ x2, const float* __restrict__ w,
               const float* __restrict__ bias, const float* __restrict__ alpha,
               float* __restrict__ out) {
  __shared__ float sw[16 * 3 * 9];
  __shared__ float sb[16];
  __shared__ float sa[16];
  for (int idx = threadIdx.x; idx < 432; idx += blockDim.x) sw[idx] = w[idx];
  if (threadIdx.x < 16) { sb[threadIdx.x] = bias[threadIdx.x]; sa[threadIdx.x] = alpha[threadIdx.x]; }
  __syncthreads();
  int gid = blockIdx.x * blockDim.x + threadIdx.x;
  int total = 3 * NB * HWO;
  if (gid >= total) return;
  int p = gid % HWO;
  int ni = gid / HWO;            // n*3+img
  int n = ni / 3, img = ni % 3;
  int i = p / WO, j = p % WO;
  const float* x = (img == 0 ? x0 : (img == 1 ? x1 : x2)) + (size_t)n * 3 * HWI;
  float in[27];
  int q = 0;
#pragma unroll
  for (int ci = 0; ci < 3; ++ci)
#pragma unroll
    for (int ky = 0; ky < 3; ++ky) {
      int r = 2 * i + ky - 1;
#pragma unroll
      for (int kx = 0; kx < 3; ++kx) {
        int c = 2 * j + kx - 1;
        in[q++] = (r >= 0 && r < HI && c >= 0 && c < WI) ? x[((size_t)ci * HI + r) * WI + c] : 0.f;
      }
    }
  float* o = out + (size_t)ni * 16 * HWO + p;
#pragma unroll
  for (int co = 0; co < 16; ++co) {
    float acc = sb[co];
    const float* wp = sw + co * 27;
#pragma unroll
    for (int k = 0; k < 27; ++k) acc += wp[k] * in[k];
    o[(size_t)co * HWO] = acc >= 0.f ? acc : sa[co] * acc;
  }
}

// ---------------- generic conv, stride1, 2 px/thread, LDS-staged transposed weights ----------
// weights wT layout [CI][KS*KS][CO]; per-ci slice double-buffered in LDS; broadcast
// float4 LDS reads give 4 weights -> 8 FMA per read. Input channels come from two
// buffers: ci<CI1 -> in1 + b*s1, else in2 + b*s2. Grid must exactly cover B*HWO/2 threads.
// __launch_bounds__(256,2): VGPR cap 256 — acc[CO][2] + taps must NOT spill (round-4 lesson:
// default budget was 64 VGPRs -> 173MB scratch traffic, 3x slowdown).
template <int CI1, int CI2, int CO, int KS, bool PRELU>
__global__ void __launch_bounds__(256, 2)
conv2px_kernel(const float* __restrict__ in1, long s1,
               const float* __restrict__ in2, long s2,
               const float* __restrict__ wT, const float* __restrict__ bias,
               const float* __restrict__ alpha,
               float* __restrict__ out, long so) {
  constexpr int CI = CI1 + CI2;
  constexpr int KK = KS * KS;
  constexpr int WSL = KK * CO;       // weights per ci-slice (multiple of 4)
  constexpr int PAD = KS / 2;
  __shared__ __align__(16) float sw[2][WSL];
  __shared__ float sb[CO];
  __shared__ float sa[CO];
  int tx = threadIdx.x;
  if (tx < CO) { sb[tx] = bias[tx]; sa[tx] = PRELU ? alpha[tx] : 0.f; }
  for (int idx = tx; idx < WSL; idx += blockDim.x) sw[0][idx] = wT[idx];
  __syncthreads();

  int tid = blockIdx.x * blockDim.x + tx;
  int p0 = tid * 2;
  int b = p0 / HWO, p = p0 % HWO;
  int i = p / WO, j = p % WO;      // j even; j+1 in same row (WO even)

  float acc[CO][2];
#pragma unroll
  for (int co = 0; co < CO; ++co) { acc[co][0] = sb[co]; acc[co][1] = sb[co]; }

  for (int ci = 0; ci < CI; ++ci) {
    // prefetch next weight slice into the other LDS buffer (safe: consumers of that
    // buffer finished before the barrier at the end of the previous iteration)
    if (ci + 1 < CI) {
      const float* nsrc = wT + (size_t)(ci + 1) * WSL;
      float* ndst = sw[(ci + 1) & 1];
      for (int idx = tx; idx < WSL; idx += blockDim.x) ndst[idx] = nsrc[idx];
    }
    const float* xc = (ci < CI1) ? in1 + (size_t)b * s1 + (size_t)ci * HWO
                                 : in2 + (size_t)b * s2 + (size_t)(ci - CI1) * HWO;
    float taps[KS][KS + 1];
#pragma unroll
    for (int ky = 0; ky < KS; ++ky) {
      int r = i + ky - PAD;
      bool rv = (r >= 0) && (r < HO);
      const float* row = xc + (size_t)r * WO;
#pragma unroll
      for (int kx = 0; kx <= KS; ++kx) {
        int c = j + kx - PAD;
        taps[ky][kx] = (rv && c >= 0 && c < WO) ? row[c] : 0.f;
      }
    }
    const float* wsl = sw[ci & 1];
#pragma unroll
    for (int ky = 0; ky < KS; ++ky)
#pragma unroll
      for (int kx = 0; kx < KS; ++kx) {
        float t0 = taps[ky][kx];
        float t1 = taps[ky][kx + 1];
        int k = ky * KS + kx;
#pragma unroll
        for (int cq = 0; cq < CO / 4; ++cq) {
          const float4 wv = *reinterpret_cast<const float4*>(&wsl[k * CO + cq * 4]);
          acc[cq * 4 + 0][0] += wv.x * t0; acc[cq * 4 + 0][1] += wv.x * t1;
          acc[cq * 4 + 1][0] += wv.y * t0; acc[cq * 4 + 1][1] += wv.y * t1;
          acc[cq * 4 + 2][0] += wv.z * t0; acc[cq * 4 + 2][1] += wv.z * t1;
          acc[cq * 4 + 3][0] += wv.w * t0; acc[cq * 4 + 3][1] += wv.w * t1;
        }
      }
    __syncthreads();
  }
  float* ob = out + (size_t)b * so + p;
#pragma unroll
  for (int co = 0; co < CO; ++co) {
    float v0 = acc[co][0], v1 = acc[co][1];
    if (PRELU) {
      v0 = v0 >= 0.f ? v0 : sa[co] * v0;
      v1 = v1 >= 0.f ? v1 : sa[co] * v1;
    }
    ob[(size_t)co * HWO] = v0;
    ob[(size_t)co * HWO + 1] = v1;
  }
}

// ---------------- small generic 3x3 conv (kept for 16->1) ----------
template <int CI, int CO, bool PRELU>
__global__ void __launch_bounds__(256, 2)
conv3x3_kernel(const float* __restrict__ in, const float* __restrict__ w,
               const float* __restrict__ bias, const float* __restrict__ alpha,
               float* __restrict__ out, int B) {
  __shared__ float sw[CO * CI * 9];
  __shared__ float sb[CO];
  __shared__ float sa[CO];
  for (int idx = threadIdx.x; idx < CO * CI * 9; idx += blockDim.x) sw[idx] = w[idx];
  if (threadIdx.x < CO) {
    sb[threadIdx.x] = bias[threadIdx.x];
    sa[threadIdx.x] = PRELU ? alpha[threadIdx.x] : 0.f;
  }
  __syncthreads();
  int gid = blockIdx.x * blockDim.x + threadIdx.x;
  int total = B * HWO;
  if (gid >= total) return;
  int p = gid % HWO, b = gid / HWO;
  int i = p / WO, j = p % WO;
  const float* xb = in + (size_t)b * CI * HWO;
  float acc[CO];
#pragma unroll
  for (int co = 0; co < CO; ++co) acc[co] = sb[co];
  for (int ci = 0; ci < CI; ++ci) {
    const float* xc = xb + (size_t)ci * HWO;
    float taps[9];
    int q = 0;
#pragma unroll
    for (int ky = 0; ky < 3; ++ky) {
      int r = i + ky - 1;
#pragma unroll
      for (int kx = 0; kx < 3; ++kx) {
        int c = j + kx - 1;
        taps[q++] = (r >= 0 && r < HO && c >= 0 && c < WO) ? xc[(size_t)r * WO + c] : 0.f;
      }
    }
#pragma unroll
    for (int co = 0; co < CO; ++co) {
      const float* wp = sw + (co * CI + ci) * 9;
      float s = acc[co];
#pragma unroll
      for (int k = 0; k < 9; ++k) s += wp[k] * taps[k];
      acc[co] = s;
    }
  }
  float* ob = out + (size_t)b * CO * HWO + p;
#pragma unroll
  for (int co = 0; co < CO; ++co) {
    float v = acc[co];
    if (PRELU) v = v >= 0.f ? v : sa[co] * v;
    ob[(size_t)co * HWO] = v;
  }
}

// ---------------- forward splat (fwarp), fused with flow downsample, all 4 flows ----------
DEV void splat_one(float f0, float f1, float s, int n, int i, int j,
                   float* __restrict__ imgw, float* __restrict__ nw) {
  float xr = s * f1;  // row displacement
  float yc = s * f0;  // col displacement
  float x1f = floorf(xr), y1f = floorf(yc);
#pragma unroll
  for (int dx = 0; dx < 2; ++dx)
#pragma unroll
    for (int dy = 0; dy < 2; ++dy) {
      float sx = x1f + (float)dx;
      float sy = y1f + (float)dy;
      float ddx = xr - sx, ddy = yc - sy;
      float wgt = expf(-(ddx * ddx + ddy * ddy));
      int r = (int)sx + i;
      int c = (int)sy + j;
      if (r >= 0 && r < HO && c >= 0 && c < WO) {
        size_t o = (size_t)r * WO + c;
        atomicAdd(&imgw[((size_t)n * 2 + 0) * HWO + o], f0 * wgt);
        atomicAdd(&imgw[((size_t)n * 2 + 1) * HWO + o], f1 * wgt);
        atomicAdd(&nw[(size_t)n * HWO + o], wgt);
      }
    }
}

__global__ void fwarp_all_kernel(const float* __restrict__ flow0, const float* __restrict__ flow1,
                                 const float* __restrict__ flow2, const float* __restrict__ flow3,
                                 const float* __restrict__ t1, const float* __restrict__ t2,
                                 float* __restrict__ S /* 12u splat region, zeroed */) {
  const size_t u = (size_t)NB * HWO;
  int gid = blockIdx.x * blockDim.x + threadIdx.x;
  int total = 2 * NB * HWO;
  if (gid >= total) return;
  int side = gid / (NB * HWO);
  int rem = gid % (NB * HWO);
  int n = rem / HWO, p = rem % HWO;
  int i = p / WO, j = p % WO;
  const float* fA = side ? flow2 : flow0;
  const float* fB = side ? flow3 : flow1;
  const float* t  = side ? t2 : t1;
  float* base = S + (size_t)side * 6 * u;
  float* imgwA = base;
  float* imgwB = base + 2 * u;
  float* nA = base + 4 * u;
  float* nB = base + 5 * u;
  float tv = t[(size_t)n * HWO + p];
  {
    float f0 = 0.5f * ds_half(fA + ((size_t)n * 2 + 0) * HWI, i, j);
    float f1 = 0.5f * ds_half(fA + ((size_t)n * 2 + 1) * HWI, i, j);
    splat_one(f0, f1, tv, n, i, j, imgwA, nA);
  }
  {
    float f0 = 0.5f * ds_half(fB + ((size_t)n * 2 + 0) * HWI, i, j);
    float f1 = 0.5f * ds_half(fB + ((size_t)n * 2 + 1) * HWI, i, j);
    splat_one(f0, f1, 1.f - tv, n, i, j, imgwB, nB);
  }
}

// combine -> ftL [NB][4][HWO] = (ft0l ch0,ch1, ft1l ch0,ch1); ftR likewise (ft1r, ft2r)
__global__ void cfr_all_kernel(const float* __restrict__ S,
                               const float* __restrict__ t1, const float* __restrict__ t2,
                               float* __restrict__ ftL, float* __restrict__ ftR) {
  const size_t u = (size_t)NB * HWO;
  int gid = blockIdx.x * blockDim.x + threadIdx.x;
  int total = 2 * NB * HWO;
  if (gid >= total) return;
  int side = gid / (NB * HWO);
  int rem = gid % (NB * HWO);
  int n = rem / HWO, p = rem % HWO;
  const float* base = S + (size_t)side * 6 * u;
  const float* f01w = base;
  const float* f10w = base + 2 * u;
  const float* n0 = base + 4 * u;
  const float* n1 = base + 5 * u;
  const float* t = side ? t2 : t1;
  float* ft = side ? ftR : ftL;
  size_t np = (size_t)n * HWO + p;
  float tv = t[np];
  float norm = (1.f - tv) * n0[np] + tv * n1[np];
  bool pos = norm > 0.f;
#pragma unroll
  for (int ch = 0; ch < 2; ++ch) {
    size_t sidx = ((size_t)n * 2 + ch) * HWO + p;
    float a = f01w[sidx];
    float b = f10w[sidx];
    float v0 = -(1.f - tv) * tv * a + tv * tv * b;
    float v1 = (1.f - tv) * (1.f - tv) * a - tv * (1.f - tv) * b;
    ft[((size_t)n * 4 + ch) * HWO + p]     = pos ? v0 / norm : v0;
    ft[((size_t)n * 4 + 2 + ch) * HWO + p] = pos ? v1 / norm : v1;
  }
}

// ---------------- backward warp + occlusion blend + final 1x1 conv ----------
DEV float sigmoidf_(float x) { return 1.f / (1.f + expf(-x)); }

DEV void bwarp16(const float* __restrict__ x /* [16][HWO] */, const float* __restrict__ flo /* [2][HWO] */,
                 int p, int i, int j, float* o) {
  float fx = flo[p];
  float fy = flo[HWO + p];
  float gx = (float)j + fx, gy = (float)i + fy;
  float nx = 2.f * gx / (float)(WO - 1) - 1.f;
  float ny = 2.f * gy / (float)(HO - 1) - 1.f;
  float px = ((nx + 1.f) * (float)WO - 1.f) * 0.5f;
  float py = ((ny + 1.f) * (float)HO - 1.f) * 0.5f;
  float cx = fminf(fmaxf(px, 0.f), (float)(WO - 1));
  float cy = fminf(fmaxf(py, 0.f), (float)(HO - 1));
  float x0f = floorf(cx), y0f = floorf(cy);
  float wx = cx - x0f, wy = cy - y0f;
  int x0i = (int)x0f; x0i = x0i < 0 ? 0 : (x0i > WO - 1 ? WO - 1 : x0i);
  int y0i = (int)y0f; y0i = y0i < 0 ? 0 : (y0i > HO - 1 ? HO - 1 : y0i);
  int x1i = x0i + 1 > WO - 1 ? WO - 1 : x0i + 1;
  int y1i = y0i + 1 > HO - 1 ? HO - 1 : y0i + 1;
  float fx0 = floorf(px), fy0 = floorf(py);
  float ux = px - fx0, uy = py - fy0;
  float WOf = (float)WO, HOf = (float)HO;
  float i00 = (fx0 >= 0.f && fx0 < WOf && fy0 >= 0.f && fy0 < HOf) ? 1.f : 0.f;
  float i10 = (fx0 + 1.f >= 0.f && fx0 + 1.f < WOf && fy0 >= 0.f && fy0 < HOf) ? 1.f : 0.f;
  float i01 = (fx0 >= 0.f && fx0 < WOf && fy0 + 1.f >= 0.f && fy0 + 1.f < HOf) ? 1.f : 0.f;
  float i11 = (fx0 + 1.f >= 0.f && fx0 + 1.f < WOf && fy0 + 1.f >= 0.f && fy0 + 1.f < HOf) ? 1.f : 0.f;
  float mv = (1.f - ux) * (1.f - uy) * i00 + ux * (1.f - uy) * i10
           + (1.f - ux) * uy * i01 + ux * uy * i11;
  float mask = mv >= 0.999f ? 1.f : 0.f;
  float w00 = (1.f - wx) * (1.f - wy), w10 = wx * (1.f - wy);
  float w01 = (1.f - wx) * wy, w11 = wx * wy;
  int a00 = y0i * WO + x0i, a10 = y0i * WO + x1i;
  int a01 = y1i * WO + x0i, a11 = y1i * WO + x1i;
#pragma unroll
  for (int c = 0; c < 16; ++c) {
    const float* xc = x + (size_t)c * HWO;
    o[c] = (w00 * xc[a00] + w10 * xc[a10] + w01 * xc[a01] + w11 * xc[a11]) * mask;
  }
}

__global__ void __launch_bounds__(256, 2)
blend_out_kernel(const float* __restrict__ xs /* [NB][48][HWO] */,
                 const float* __restrict__ ftL, const float* __restrict__ ftR,
                 const float* __restrict__ occl, const float* __restrict__ occr,
                 const float* __restrict__ t1, const float* __restrict__ t2,
                 const float* __restrict__ wm,
                 const float* __restrict__ fw, const float* __restrict__ fb,
                 const float* __restrict__ fa,
                 float* __restrict__ out /* [NB][16][HWO] */) {
  __shared__ float sw[512];
  __shared__ float sb[16];
  __shared__ float sa[16];
  for (int idx = threadIdx.x; idx < 512; idx += blockDim.x) sw[idx] = fw[idx];
  if (threadIdx.x < 16) { sb[threadIdx.x] = fb[threadIdx.x]; sa[threadIdx.x] = fa[threadIdx.x]; }
  __syncthreads();
  int gid = blockIdx.x * blockDim.x + threadIdx.x;
  int total = NB * HWO;
  if (gid >= total) return;
  int p = gid % HWO, n = gid / HWO;
  int i = p / WO, j = p % WO;
  size_t np = (size_t)n * HWO + p;
  float wmv = wm[np];
  const float* xs0 = xs + (size_t)n * 48 * HWO;
  const float* xs1 = xs0 + (size_t)16 * HWO;
  const float* xs2 = xs0 + (size_t)32 * HWO;
  const float* fl = ftL + (size_t)n * 4 * HWO;
  const float* fr = ftR + (size_t)n * 4 * HWO;
  float A[16], B[16];
  float bw0[16], bw1[16];
  {
    float t = t1[np];
    float o0 = sigmoidf_(occl[np]);
    float o1 = 1.f - o0;
    bwarp16(xs0, fl, p, i, j, bw0);
    bwarp16(xs1, fl + (size_t)2 * HWO, p, i, j, bw1);
    float c0 = (1.f - t) * o0, c1 = t * o1;
    float r = wmv / (c0 + c1);
#pragma unroll
    for (int c = 0; c < 16; ++c) A[c] = (c0 * bw0[c] + c1 * bw1[c]) * r;
  }
  {
    float t = t2[np];
    float o0 = sigmoidf_(occr[np]);
    float o1 = 1.f - o0;
    bwarp16(xs1, fr, p, i, j, bw0);
    bwarp16(xs2, fr + (size_t)2 * HWO, p, i, j, bw1);
    float c0 = (1.f - t) * o0, c1 = t * o1;
    float r = (1.f - wmv) / (c0 + c1);
#pragma unroll
    for (int c = 0; c < 16; ++c) B[c] = (c0 * bw0[c] + c1 * bw1[c]) * r;
  }
  float* ob = out + (size_t)n * 16 * HWO + p;
#pragma unroll
  for (int co = 0; co < 16; ++co) {
    float s = sb[co];
    const float* wp = sw + co * 32;
#pragma unroll
    for (int ci = 0; ci < 16; ++ci) s += wp[ci] * A[ci];
#pragma unroll
    for (int ci = 0; ci < 16; ++ci) s += wp[16 + ci] * B[ci];
    ob[(size_t)co * HWO] = s >= 0.f ? s : sa[co] * s;
  }
}

extern "C" void kernel_launch(void* const* d_in, const int* in_sizes, int n_in,
                              void* d_out, int out_size, void* d_ws, size_t ws_size,
                              hipStream_t stream) {
  const float* x0 = (const float*)d_in[0];
  const float* x1 = (const float*)d_in[1];
  const float* x2 = (const float*)d_in[2];
  const float* flw[4] = {(const float*)d_in[3], (const float*)d_in[4],
                         (const float*)d_in[5], (const float*)d_in[6]};
  const float* enc  = (const float*)d_in[7];
  const float* c_w1 = (const float*)d_in[8];
  const float* c_b1 = (const float*)d_in[9];
  const float* c_a1 = (const float*)d_in[10];
  const float* c_w2 = (const float*)d_in[11];
  const float* c_b2 = (const float*)d_in[12];
  const float* c_a2 = (const float*)d_in[13];
  const float* m_w1 = (const float*)d_in[14];
  const float* m_b1 = (const float*)d_in[15];
  const float* m_a1 = (const float*)d_in[16];
  const float* m_w2 = (const float*)d_in[17];
  const float* m_b2 = (const float*)d_in[18];
  const float* m_a2 = (const float*)d_in[19];
  const float* m_w3 = (const float*)d_in[20];
  const float* m_b3 = (const float*)d_in[21];
  const float* f_w  = (const float*)d_in[22];
  const float* f_b  = (const float*)d_in[23];
  const float* f_a  = (const float*)d_in[24];
  float* out = (float*)d_out;

  const size_t u = (size_t)NB * HWO;  // 229376 floats
  float* base = (float*)d_ws;
  size_t off = 0;
  auto alloc = [&](size_t nfl) { float* pp = base + off; off += nfl; return pp; };
  float* t1  = alloc(u);
  float* t2  = alloc(u);
  float* wmb = alloc(u);
  float* xs   = alloc(48 * u);  // [NB][48][HWO] convds output (n-major)
  float* xsc1 = alloc(48 * u);  // convds1 scratch; later mn1 (32u) + mn2 (16u)
  float* splat = alloc(12 * u); // [2 sides][imgwA 2u | imgwB 2u | nA u | nB u]
  float* ftL = alloc(4 * u);    // [NB][4][HWO] = ft0l, ft1l
  float* ftR = alloc(4 * u);    // [NB][4][HWO] = ft1r, ft2r
  float* occl = alloc(u);
  float* occr = alloc(u);
  float* wT1  = alloc(36 * 25 * 32);  // mask conv1 weights [ci][k][co]
  float* wTc2 = alloc(16 * 9 * 16);   // convds2 weights
  float* wTm2 = alloc(32 * 9 * 16);   // mask conv2 weights
  float* mn1 = xsc1;                  // [NB][32][HWO] = 32u
  float* mn2 = xsc1 + 32 * u;         // [NB][16][HWO] = 16u

  const int TPB = 256;
  auto NBLK = [](long long t) { return (unsigned)((t + 255) / 256); };

  // weight transposes (tiny)
  wtrans_kernel<<<NBLK(32 * 36 * 25), TPB, 0, stream>>>(m_w1, wT1, 32, 36, 25);
  wtrans_kernel<<<NBLK(16 * 16 * 9), TPB, 0, stream>>>(c_w2, wTc2, 16, 16, 9);
  wtrans_kernel<<<NBLK(16 * 32 * 9), TPB, 0, stream>>>(m_w2, wTm2, 16, 32, 9);

  ds_enc_kernel<<<NBLK((long long)NB * 3 * HWO), TPB, 0, stream>>>(enc, t1, t2, wmb);

  convds1_kernel<<<NBLK((long long)3 * NB * HWO), TPB, 0, stream>>>(x0, x1, x2, c_w1, c_b1, c_a1, xsc1);
  // convds2: 16->16 3x3 over 6 batches (b = n*3+img) -> xs [NB][48][HWO]
  conv2px_kernel<16, 0, 16, 3, true><<<(unsigned)(6LL * HWO / 2 / TPB), TPB, 0, stream>>>(
      xsc1, 16L * HWO, nullptr, 0, wTc2, c_b2, c_a2, xs, 16L * HWO);

  // flow splat path
  hipMemsetAsync(splat, 0, 12 * u * sizeof(float), stream);
  fwarp_all_kernel<<<NBLK((long long)2 * NB * HWO), TPB, 0, stream>>>(
      flw[0], flw[1], flw[2], flw[3], t1, t2, splat);
  cfr_all_kernel<<<NBLK((long long)2 * NB * HWO), TPB, 0, stream>>>(splat, t1, t2, ftL, ftR);

  // masknet left: input = xs[n][0:32] ++ ftL[n][0:4]
  conv2px_kernel<32, 4, 32, 5, true><<<(unsigned)((long long)NB * HWO / 2 / TPB), TPB, 0, stream>>>(
      xs, 48L * HWO, ftL, 4L * HWO, wT1, m_b1, m_a1, mn1, 32L * HWO);
  conv2px_kernel<32, 0, 16, 3, true><<<(unsigned)((long long)NB * HWO / 2 / TPB), TPB, 0, stream>>>(
      mn1, 32L * HWO, nullptr, 0, wTm2, m_b2, m_a2, mn2, 16L * HWO);
  conv3x3_kernel<16, 1, false><<<NBLK((long long)NB * HWO), TPB, 0, stream>>>(mn2, m_w3, m_b3, m_b3, occl, NB);
  // masknet right: input = xs[n][16:48] ++ ftR[n][0:4]
  conv2px_kernel<32, 4, 32, 5, true><<<(unsigned)((long long)NB * HWO / 2 / TPB), TPB, 0, stream>>>(
      xs + (size_t)16 * HWO, 48L * HWO, ftR, 4L * HWO, wT1, m_b1, m_a1, mn1, 32L * HWO);
  conv2px_kernel<32, 0, 16, 3, true><<<(unsigned)((long long)NB * HWO / 2 / TPB), TPB, 0, stream>>>(
      mn1, 32L * HWO, nullptr, 0, wTm2, m_b2, m_a2, mn2, 16L * HWO);
  conv3x3_kernel<16, 1, false><<<NBLK((long long)NB * HWO), TPB, 0, stream>>>(mn2, m_w3, m_b3, m_b3, occr, NB);

  // blend + fused final 1x1 -> d_out
  blend_out_kernel<<<NBLK((long long)NB * HWO), TPB, 0, stream>>>(
      xs, ftL, ftR, occl, occr, t1, t2, wmb, f_w, f_b, f_a, out);
}

// Round 6
// 783.787 us; speedup vs baseline: 2.0760x; 1.3628x over previous
//
#include <hip/hip_runtime.h>
#include <math.h>

#define DEV __device__ __forceinline__

constexpr int NB = 2;
constexpr int HI = 512, WI = 896;
constexpr int HO = 256, WO = 448;
constexpr int HWO = HO * WO;   // 114688
constexpr int HWI = HI * WI;   // 458752

typedef __bf16 bf16x8 __attribute__((ext_vector_type(8)));
typedef float f32x4 __attribute__((ext_vector_type(4)));

// ---------------- downsample (jax.image.resize bilinear, antialias=True, scale 1/2) ----------
DEV float ds_half(const float* __restrict__ p, int i, int j) {
  const float w4[4] = {1.f, 3.f, 3.f, 1.f};
  float wc[4]; int cc[4];
  float cs = 0.f;
#pragma unroll
  for (int k = 0; k < 4; ++k) {
    int c = 2 * j - 1 + k;
    bool v = (c >= 0) && (c < WI);
    wc[k] = v ? w4[k] : 0.f;
    cc[k] = v ? c : 0;
    cs += wc[k];
  }
  float acc = 0.f, rs = 0.f;
#pragma unroll
  for (int k = 0; k < 4; ++k) {
    int r = 2 * i - 1 + k;
    if (r < 0 || r >= HI) continue;
    const float* row = p + (size_t)r * WI;
    float racc = 0.f;
#pragma unroll
    for (int b = 0; b < 4; ++b) racc += wc[b] * row[cc[b]];
    acc += w4[k] * racc;
    rs += w4[k];
  }
  return acc / (rs * cs);
}

__global__ void ds_enc_kernel(const float* __restrict__ enc, float* __restrict__ t1,
                              float* __restrict__ t2, float* __restrict__ wm) {
  int gid = blockIdx.x * blockDim.x + threadIdx.x;
  int total = NB * 3 * HWO;
  if (gid >= total) return;
  int p = gid % HWO;
  int nc = gid / HWO;
  int c = nc % 3, n = nc / 3;
  int i = p / WO, j = p % WO;
  float v = ds_half(enc + (size_t)(n * 3 + c) * HWI, i, j);
  float* dst = (c == 0) ? t1 : (c == 1 ? t2 : wm);
  dst[(size_t)n * HWO + p] = v;
}

// ---------------- weight prep: [CO][CIr][KS*KS] fp32 -> B-fragment-swizzled bf16 hi/lo ----------
// K ordering: k = kpos*CIP + ci (kpos = ky*KS+kx). K padded to KTOT (mult of 32).
// Output layout matches MFMA B fragment: lane l holds B[k = s*32+(l>>4)*8+j][n = nt*16+(l&15)]
// flat: ((s*NT + nt)*64 + l)*8 + j.  k's with kpos>=KS*KS or ci>=CIr get 0 (covers both pads).
__global__ void prep_w_kernel(const float* __restrict__ w, __bf16* __restrict__ bh,
                              __bf16* __restrict__ bl, int CO, int CIr, int CIP, int KS,
                              int KTOT) {
  int idx = blockIdx.x * blockDim.x + threadIdx.x;
  int total = KTOT * CO;
  if (idx >= total) return;
  int NT = CO / 16;
  int j = idx & 7;
  int l = (idx >> 3) & 63;
  int rest = idx >> 9;
  int s = rest / NT, nt = rest % NT;
  int k = s * 32 + ((l >> 4) & 3) * 8 + j;
  int n = nt * 16 + (l & 15);
  int kpos = k / CIP, ci = k % CIP;
  float v = (kpos < KS * KS && ci < CIr) ? w[((size_t)n * CIr + ci) * KS * KS + kpos] : 0.f;
  __bf16 h = (__bf16)v;
  bh[idx] = h;
  bl[idx] = (__bf16)(v - (float)h);
}

// ---------------- convds first conv: 3x3 stride2 pad1, 3->16, prelu ----------
__global__ void __launch_bounds__(256, 2)
convds1_kernel(const float* __restrict__ x0, const float* __restrict__ x1,
               const float* __restrict__ x2, const float* __restrict__ w,
               const float* __restrict__ bias, const float* __restrict__ alpha,
               float* __restrict__ out) {
  __shared__ float sw[16 * 3 * 9];
  __shared__ float sb[16];
  __shared__ float sa[16];
  for (int idx = threadIdx.x; idx < 432; idx += blockDim.x) sw[idx] = w[idx];
  if (threadIdx.x < 16) { sb[threadIdx.x] = bias[threadIdx.x]; sa[threadIdx.x] = alpha[threadIdx.x]; }
  __syncthreads();
  int gid = blockIdx.x * blockDim.x + threadIdx.x;
  int total = 3 * NB * HWO;
  if (gid >= total) return;
  int p = gid % HWO;
  int ni = gid / HWO;            // n*3+img
  int n = ni / 3, img = ni % 3;
  int i = p / WO, j = p % WO;
  const float* x = (img == 0 ? x0 : (img == 1 ? x1 : x2)) + (size_t)n * 3 * HWI;
  float in[27];
  int q = 0;
#pragma unroll
  for (int ci = 0; ci < 3; ++ci)
#pragma unroll
    for (int ky = 0; ky < 3; ++ky) {
      int r = 2 * i + ky - 1;
#pragma unroll
      for (int kx = 0; kx < 3; ++kx) {
        int c = 2 * j + kx - 1;
        in[q++] = (r >= 0 && r < HI && c >= 0 && c < WI) ? x[((size_t)ci * HI + r) * WI + c] : 0.f;
      }
    }
  float* o = out + (size_t)ni * 16 * HWO + p;
#pragma unroll
  for (int co = 0; co < 16; ++co) {
    float acc = sb[co];
    const float* wp = sw + co * 27;
#pragma unroll
    for (int k = 0; k < 27; ++k) acc += wp[k] * in[k];
    o[(size_t)co * HWO] = acc >= 0.f ? acc : sa[co] * acc;
  }
}

// ---------------- implicit-GEMM conv via MFMA, split-bf16 for fp32 accuracy ----------
// stride-1, pad KS/2. Output tile/block: 8 rows x 16 cols; 4 waves, each 2 row-M-tiles.
// M-tile = 16 px along x. A staged in LDS as [y][x][ci] bf16 (hi+lo), so a lane's
// 8-ci fragment is one contiguous 16B read. B pre-swizzled by prep_w_kernel, staged
// SB slices at a time. Split product: AhBh + AhBl + AlBh (alo*blo dropped, ~2^-18).
template <int CIr1, int CIr2, int CIP, int KS, int CO, int SB, bool PRELU>
__global__ void __launch_bounds__(256, 2)
conv_mfma_kernel(const float* __restrict__ in1, long s1,
                 const float* __restrict__ in2, long s2,
                 const __bf16* __restrict__ wBh, const __bf16* __restrict__ wBl,
                 const float* __restrict__ bias, const float* __restrict__ alpha,
                 float* __restrict__ out, long so) {
  constexpr int TR = 8;
  constexpr int TRH = TR + KS - 1;
  constexpr int TCH = 16 + KS - 1;
  constexpr int NPX = TRH * TCH;
  constexpr int NT = CO / 16;
  constexpr int KREAL = KS * KS * CIP;
  constexpr int KTOT = ((KREAL + 31) / 32) * 32;
  constexpr int NSLICE = KTOT / 32;
  constexpr int RCHUNK = KREAL / 8;     // real (non-pad) 8-chunks
  constexpr int PAD = KS / 2;
  constexpr int CPC = CIP / 8;          // chunks per kpos
  constexpr int NTY = HO / TR;          // 32
  constexpr int NTX = WO / 16;          // 28

  __shared__ __align__(16) __bf16 Ah[NPX * CIP];
  __shared__ __align__(16) __bf16 Al[NPX * CIP];
  __shared__ __align__(16) __bf16 Bh[SB * NT * 512];
  __shared__ __align__(16) __bf16 Bl[SB * NT * 512];

  int tid = threadIdx.x;
  int bx = blockIdx.x;
  int b = bx / (NTY * NTX);
  int rem = bx % (NTY * NTX);
  int row0 = (rem / NTX) * TR;
  int col0 = (rem % NTX) * 16;

  // ---- A-tile load: [pxi][ci], halo zero-padded; pad-ci slots zeroed (NaN safety) ----
  for (int e = tid; e < NPX * CIP; e += 256) {
    int ci = e / NPX;
    int pxi = e % NPX;           // consecutive tid -> consecutive x: coalesced
    int y = pxi / TCH, x = pxi % TCH;
    int gy = row0 + y - PAD, gx = col0 + x - PAD;
    float v = 0.f;
    if (ci < CIr1 + CIr2 && gy >= 0 && gy < HO && gx >= 0 && gx < WO) {
      v = (ci < CIr1) ? in1[(size_t)b * s1 + (size_t)ci * HWO + gy * WO + gx]
                      : in2[(size_t)b * s2 + (size_t)(ci - CIr1) * HWO + gy * WO + gx];
    }
    __bf16 h = (__bf16)v;
    Ah[pxi * CIP + ci] = h;
    Al[pxi * CIP + ci] = (__bf16)(v - (float)h);
  }

  int lane = tid & 63, wid = tid >> 6;

  f32x4 acc[2][NT];
  float aco[NT];
#pragma unroll
  for (int nt = 0; nt < NT; ++nt) {
    float bv = bias[nt * 16 + (lane & 15)];
    aco[nt] = PRELU ? alpha[nt * 16 + (lane & 15)] : 0.f;
    f32x4 z = {bv, bv, bv, bv};
    acc[0][nt] = z;
    acc[1][nt] = z;
  }

  const uint4* gBh = reinterpret_cast<const uint4*>(wBh);
  const uint4* gBl = reinterpret_cast<const uint4*>(wBl);
  uint4* lBh = reinterpret_cast<uint4*>(Bh);
  uint4* lBl = reinterpret_cast<uint4*>(Bl);

  for (int s0 = 0; s0 < NSLICE; s0 += SB) {
    if (s0 > 0) __syncthreads();
    constexpr int NU = SB * NT * 64;   // uint4 per stage per precision
    for (int u = tid; u < NU; u += 256) {
      lBh[u] = gBh[(size_t)s0 * NT * 64 + u];
      lBl[u] = gBl[(size_t)s0 * NT * 64 + u];
    }
    __syncthreads();
#pragma unroll
    for (int s = 0; s < SB; ++s) {
      int slice = s0 + s;
      bf16x8 bh[NT], bl[NT];
#pragma unroll
      for (int nt = 0; nt < NT; ++nt) {
        bh[nt] = __builtin_bit_cast(bf16x8, lBh[(s * NT + nt) * 64 + lane]);
        bl[nt] = __builtin_bit_cast(bf16x8, lBl[(s * NT + nt) * 64 + lane]);
      }
      int g = slice * 4 + (lane >> 4);
      if (g > RCHUNK - 1) g = RCHUNK - 1;   // pad chunks: B==0 there, A value irrelevant
      int kpos = g / CPC;
      int ci0 = (g % CPC) * 8;
      int ky = kpos / KS, kx = kpos % KS;
      int xoff = ((lane & 15) + kx) * CIP + ci0;
#pragma unroll
      for (int mt = 0; mt < 2; ++mt) {
        int r = wid * 2 + mt;
        int addr = (r + ky) * TCH * CIP + xoff;
        bf16x8 ah = __builtin_bit_cast(bf16x8, *reinterpret_cast<const uint4*>(Ah + addr));
        bf16x8 al = __builtin_bit_cast(bf16x8, *reinterpret_cast<const uint4*>(Al + addr));
#pragma unroll
        for (int nt = 0; nt < NT; ++nt) {
          acc[mt][nt] = __builtin_amdgcn_mfma_f32_16x16x32_bf16(ah, bh[nt], acc[mt][nt], 0, 0, 0);
          acc[mt][nt] = __builtin_amdgcn_mfma_f32_16x16x32_bf16(ah, bl[nt], acc[mt][nt], 0, 0, 0);
          acc[mt][nt] = __builtin_amdgcn_mfma_f32_16x16x32_bf16(al, bh[nt], acc[mt][nt], 0, 0, 0);
        }
      }
    }
  }

  // ---- epilogue: C/D layout col=lane&15 (co), row=(lane>>4)*4+reg (px x-offset) ----
#pragma unroll
  for (int mt = 0; mt < 2; ++mt) {
    int gr = row0 + wid * 2 + mt;
#pragma unroll
    for (int nt = 0; nt < NT; ++nt) {
      int co = nt * 16 + (lane & 15);
      float* op = out + (size_t)b * so + (size_t)co * HWO + (size_t)gr * WO + col0 + (lane >> 4) * 4;
#pragma unroll
      for (int reg = 0; reg < 4; ++reg) {
        float v = acc[mt][nt][reg];
        if (PRELU) v = v >= 0.f ? v : aco[nt] * v;
        op[reg] = v;
      }
    }
  }
}

// ---------------- small generic 3x3 conv (kept for 16->1) ----------
template <int CI, int CO, bool PRELU>
__global__ void __launch_bounds__(256, 2)
conv3x3_kernel(const float* __restrict__ in, const float* __restrict__ w,
               const float* __restrict__ bias, const float* __restrict__ alpha,
               float* __restrict__ out, int B) {
  __shared__ float sw[CO * CI * 9];
  __shared__ float sb[CO];
  __shared__ float sa[CO];
  for (int idx = threadIdx.x; idx < CO * CI * 9; idx += blockDim.x) sw[idx] = w[idx];
  if (threadIdx.x < CO) {
    sb[threadIdx.x] = bias[threadIdx.x];
    sa[threadIdx.x] = PRELU ? alpha[threadIdx.x] : 0.f;
  }
  __syncthreads();
  int gid = blockIdx.x * blockDim.x + threadIdx.x;
  int total = B * HWO;
  if (gid >= total) return;
  int p = gid % HWO, b = gid / HWO;
  int i = p / WO, j = p % WO;
  const float* xb = in + (size_t)b * CI * HWO;
  float acc[CO];
#pragma unroll
  for (int co = 0; co < CO; ++co) acc[co] = sb[co];
  for (int ci = 0; ci < CI; ++ci) {
    const float* xc = xb + (size_t)ci * HWO;
    float taps[9];
    int q = 0;
#pragma unroll
    for (int ky = 0; ky < 3; ++ky) {
      int r = i + ky - 1;
#pragma unroll
      for (int kx = 0; kx < 3; ++kx) {
        int c = j + kx - 1;
        taps[q++] = (r >= 0 && r < HO && c >= 0 && c < WO) ? xc[(size_t)r * WO + c] : 0.f;
      }
    }
#pragma unroll
    for (int co = 0; co < CO; ++co) {
      const float* wp = sw + (co * CI + ci) * 9;
      float s = acc[co];
#pragma unroll
      for (int k = 0; k < 9; ++k) s += wp[k] * taps[k];
      acc[co] = s;
    }
  }
  float* ob = out + (size_t)b * CO * HWO + p;
#pragma unroll
  for (int co = 0; co < CO; ++co) {
    float v = acc[co];
    if (PRELU) v = v >= 0.f ? v : sa[co] * v;
    ob[(size_t)co * HWO] = v;
  }
}

// ---------------- forward splat (fwarp), fused with flow downsample, all 4 flows ----------
DEV void splat_one(float f0, float f1, float s, int n, int i, int j,
                   float* __restrict__ imgw, float* __restrict__ nw) {
  float xr = s * f1;  // row displacement
  float yc = s * f0;  // col displacement
  float x1f = floorf(xr), y1f = floorf(yc);
#pragma unroll
  for (int dx = 0; dx < 2; ++dx)
#pragma unroll
    for (int dy = 0; dy < 2; ++dy) {
      float sx = x1f + (float)dx;
      float sy = y1f + (float)dy;
      float ddx = xr - sx, ddy = yc - sy;
      float wgt = expf(-(ddx * ddx + ddy * ddy));
      int r = (int)sx + i;
      int c = (int)sy + j;
      if (r >= 0 && r < HO && c >= 0 && c < WO) {
        size_t o = (size_t)r * WO + c;
        atomicAdd(&imgw[((size_t)n * 2 + 0) * HWO + o], f0 * wgt);
        atomicAdd(&imgw[((size_t)n * 2 + 1) * HWO + o], f1 * wgt);
        atomicAdd(&nw[(size_t)n * HWO + o], wgt);
      }
    }
}

__global__ void fwarp_all_kernel(const float* __restrict__ flow0, const float* __restrict__ flow1,
                                 const float* __restrict__ flow2, const float* __restrict__ flow3,
                                 const float* __restrict__ t1, const float* __restrict__ t2,
                                 float* __restrict__ S /* 12u splat region, zeroed */) {
  const size_t u = (size_t)NB * HWO;
  int gid = blockIdx.x * blockDim.x + threadIdx.x;
  int total = 2 * NB * HWO;
  if (gid >= total) return;
  int side = gid / (NB * HWO);
  int rem = gid % (NB * HWO);
  int n = rem / HWO, p = rem % HWO;
  int i = p / WO, j = p % WO;
  const float* fA = side ? flow2 : flow0;
  const float* fB = side ? flow3 : flow1;
  const float* t  = side ? t2 : t1;
  float* base = S + (size_t)side * 6 * u;
  float* imgwA = base;
  float* imgwB = base + 2 * u;
  float* nA = base + 4 * u;
  float* nB = base + 5 * u;
  float tv = t[(size_t)n * HWO + p];
  {
    float f0 = 0.5f * ds_half(fA + ((size_t)n * 2 + 0) * HWI, i, j);
    float f1 = 0.5f * ds_half(fA + ((size_t)n * 2 + 1) * HWI, i, j);
    splat_one(f0, f1, tv, n, i, j, imgwA, nA);
  }
  {
    float f0 = 0.5f * ds_half(fB + ((size_t)n * 2 + 0) * HWI, i, j);
    float f1 = 0.5f * ds_half(fB + ((size_t)n * 2 + 1) * HWI, i, j);
    splat_one(f0, f1, 1.f - tv, n, i, j, imgwB, nB);
  }
}

// combine -> ftL [NB][4][HWO] = (ft0l ch0,ch1, ft1l ch0,ch1); ftR likewise (ft1r, ft2r)
__global__ void cfr_all_kernel(const float* __restrict__ S,
                               const float* __restrict__ t1, const float* __restrict__ t2,
                               float* __restrict__ ftL, float* __restrict__ ftR) {
  const size_t u = (size_t)NB * HWO;
  int gid = blockIdx.x * blockDim.x + threadIdx.x;
  int total = 2 * NB * HWO;
  if (gid >= total) return;
  int side = gid / (NB * HWO);
  int rem = gid % (NB * HWO);
  int n = rem / HWO, p = rem % HWO;
  const float* base = S + (size_t)side * 6 * u;
  const float* f01w = base;
  const float* f10w = base + 2 * u;
  const float* n0 = base + 4 * u;
  const float* n1 = base + 5 * u;
  const float* t = side ? t2 : t1;
  float* ft = side ? ftR : ftL;
  size_t np = (size_t)n * HWO + p;
  float tv = t[np];
  float norm = (1.f - tv) * n0[np] + tv * n1[np];
  bool pos = norm > 0.f;
#pragma unroll
  for (int ch = 0; ch < 2; ++ch) {
    size_t sidx = ((size_t)n * 2 + ch) * HWO + p;
    float a = f01w[sidx];
    float b = f10w[sidx];
    float v0 = -(1.f - tv) * tv * a + tv * tv * b;
    float v1 = (1.f - tv) * (1.f - tv) * a - tv * (1.f - tv) * b;
    ft[((size_t)n * 4 + ch) * HWO + p]     = pos ? v0 / norm : v0;
    ft[((size_t)n * 4 + 2 + ch) * HWO + p] = pos ? v1 / norm : v1;
  }
}

// ---------------- backward warp + occlusion blend + final 1x1 conv ----------
DEV float sigmoidf_(float x) { return 1.f / (1.f + expf(-x)); }

DEV void bwarp16(const float* __restrict__ x /* [16][HWO] */, const float* __restrict__ flo /* [2][HWO] */,
                 int p, int i, int j, float* o) {
  float fx = flo[p];
  float fy = flo[HWO + p];
  float gx = (float)j + fx, gy = (float)i + fy;
  float nx = 2.f * gx / (float)(WO - 1) - 1.f;
  float ny = 2.f * gy / (float)(HO - 1) - 1.f;
  float px = ((nx + 1.f) * (float)WO - 1.f) * 0.5f;
  float py = ((ny + 1.f) * (float)HO - 1.f) * 0.5f;
  float cx = fminf(fmaxf(px, 0.f), (float)(WO - 1));
  float cy = fminf(fmaxf(py, 0.f), (float)(HO - 1));
  float x0f = floorf(cx), y0f = floorf(cy);
  float wx = cx - x0f, wy = cy - y0f;
  int x0i = (int)x0f; x0i = x0i < 0 ? 0 : (x0i > WO - 1 ? WO - 1 : x0i);
  int y0i = (int)y0f; y0i = y0i < 0 ? 0 : (y0i > HO - 1 ? HO - 1 : y0i);
  int x1i = x0i + 1 > WO - 1 ? WO - 1 : x0i + 1;
  int y1i = y0i + 1 > HO - 1 ? HO - 1 : y0i + 1;
  float fx0 = floorf(px), fy0 = floorf(py);
  float ux = px - fx0, uy = py - fy0;
  float WOf = (float)WO, HOf = (float)HO;
  float i00 = (fx0 >= 0.f && fx0 < WOf && fy0 >= 0.f && fy0 < HOf) ? 1.f : 0.f;
  float i10 = (fx0 + 1.f >= 0.f && fx0 + 1.f < WOf && fy0 >= 0.f && fy0 < HOf) ? 1.f : 0.f;
  float i01 = (fx0 >= 0.f && fx0 < WOf && fy0 + 1.f >= 0.f && fy0 + 1.f < HOf) ? 1.f : 0.f;
  float i11 = (fx0 + 1.f >= 0.f && fx0 + 1.f < WOf && fy0 + 1.f >= 0.f && fy0 + 1.f < HOf) ? 1.f : 0.f;
  float mv = (1.f - ux) * (1.f - uy) * i00 + ux * (1.f - uy) * i10
           + (1.f - ux) * uy * i01 + ux * uy * i11;
  float mask = mv >= 0.999f ? 1.f : 0.f;
  float w00 = (1.f - wx) * (1.f - wy), w10 = wx * (1.f - wy);
  float w01 = (1.f - wx) * wy, w11 = wx * wy;
  int a00 = y0i * WO + x0i, a10 = y0i * WO + x1i;
  int a01 = y1i * WO + x0i, a11 = y1i * WO + x1i;
#pragma unroll
  for (int c = 0; c < 16; ++c) {
    const float* xc = x + (size_t)c * HWO;
    o[c] = (w00 * xc[a00] + w10 * xc[a10] + w01 * xc[a01] + w11 * xc[a11]) * mask;
  }
}

__global__ void __launch_bounds__(256, 2)
blend_out_kernel(const float* __restrict__ xs /* [NB][48][HWO] */,
                 const float* __restrict__ ftL, const float* __restrict__ ftR,
                 const float* __restrict__ occl, const float* __restrict__ occr,
                 const float* __restrict__ t1, const float* __restrict__ t2,
                 const float* __restrict__ wm,
                 const float* __restrict__ fw, const float* __restrict__ fb,
                 const float* __restrict__ fa,
                 float* __restrict__ out /* [NB][16][HWO] */) {
  __shared__ float sw[512];
  __shared__ float sb[16];
  __shared__ float sa[16];
  for (int idx = threadIdx.x; idx < 512; idx += blockDim.x) sw[idx] = fw[idx];
  if (threadIdx.x < 16) { sb[threadIdx.x] = fb[threadIdx.x]; sa[threadIdx.x] = fa[threadIdx.x]; }
  __syncthreads();
  int gid = blockIdx.x * blockDim.x + threadIdx.x;
  int total = NB * HWO;
  if (gid >= total) return;
  int p = gid % HWO, n = gid / HWO;
  int i = p / WO, j = p % WO;
  size_t np = (size_t)n * HWO + p;
  float wmv = wm[np];
  const float* xs0 = xs + (size_t)n * 48 * HWO;
  const float* xs1 = xs0 + (size_t)16 * HWO;
  const float* xs2 = xs0 + (size_t)32 * HWO;
  const float* fl = ftL + (size_t)n * 4 * HWO;
  const float* fr = ftR + (size_t)n * 4 * HWO;
  float A[16], B[16];
  float bw0[16], bw1[16];
  {
    float t = t1[np];
    float o0 = sigmoidf_(occl[np]);
    float o1 = 1.f - o0;
    bwarp16(xs0, fl, p, i, j, bw0);
    bwarp16(xs1, fl + (size_t)2 * HWO, p, i, j, bw1);
    float c0 = (1.f - t) * o0, c1 = t * o1;
    float r = wmv / (c0 + c1);
#pragma unroll
    for (int c = 0; c < 16; ++c) A[c] = (c0 * bw0[c] + c1 * bw1[c]) * r;
  }
  {
    float t = t2[np];
    float o0 = sigmoidf_(occr[np]);
    float o1 = 1.f - o0;
    bwarp16(xs1, fr, p, i, j, bw0);
    bwarp16(xs2, fr + (size_t)2 * HWO, p, i, j, bw1);
    float c0 = (1.f - t) * o0, c1 = t * o1;
    float r = (1.f - wmv) / (c0 + c1);
#pragma unroll
    for (int c = 0; c < 16; ++c) B[c] = (c0 * bw0[c] + c1 * bw1[c]) * r;
  }
  float* ob = out + (size_t)n * 16 * HWO + p;
#pragma unroll
  for (int co = 0; co < 16; ++co) {
    float s = sb[co];
    const float* wp = sw + co * 32;
#pragma unroll
    for (int ci = 0; ci < 16; ++ci) s += wp[ci] * A[ci];
#pragma unroll
    for (int ci = 0; ci < 16; ++ci) s += wp[16 + ci] * B[ci];
    ob[(size_t)co * HWO] = s >= 0.f ? s : sa[co] * s;
  }
}

extern "C" void kernel_launch(void* const* d_in, const int* in_sizes, int n_in,
                              void* d_out, int out_size, void* d_ws, size_t ws_size,
                              hipStream_t stream) {
  const float* x0 = (const float*)d_in[0];
  const float* x1 = (const float*)d_in[1];
  const float* x2 = (const float*)d_in[2];
  const float* flw[4] = {(const float*)d_in[3], (const float*)d_in[4],
                         (const float*)d_in[5], (const float*)d_in[6]};
  const float* enc  = (const float*)d_in[7];
  const float* c_w1 = (const float*)d_in[8];
  const float* c_b1 = (const float*)d_in[9];
  const float* c_a1 = (const float*)d_in[10];
  const float* c_w2 = (const float*)d_in[11];
  const float* c_b2 = (const float*)d_in[12];
  const float* c_a2 = (const float*)d_in[13];
  const float* m_w1 = (const float*)d_in[14];
  const float* m_b1 = (const float*)d_in[15];
  const float* m_a1 = (const float*)d_in[16];
  const float* m_w2 = (const float*)d_in[17];
  const float* m_b2 = (const float*)d_in[18];
  const float* m_a2 = (const float*)d_in[19];
  const float* m_w3 = (const float*)d_in[20];
  const float* m_b3 = (const float*)d_in[21];
  const float* f_w  = (const float*)d_in[22];
  const float* f_b  = (const float*)d_in[23];
  const float* f_a  = (const float*)d_in[24];
  float* out = (float*)d_out;

  const size_t u = (size_t)NB * HWO;  // 229376 floats
  float* base = (float*)d_ws;
  size_t off = 0;
  auto alloc = [&](size_t nfl) { float* pp = base + off; off += nfl; return pp; };
  float* t1  = alloc(u);
  float* t2  = alloc(u);
  float* wmb = alloc(u);
  float* xs   = alloc(48 * u);  // [NB][48][HWO] convds output (n-major)
  float* xsc1 = alloc(48 * u);  // convds1 scratch; later mn1 (32u) + mn2 (16u)
  float* splat = alloc(12 * u); // [2 sides][imgwA 2u | imgwB 2u | nA u | nB u]
  float* ftL = alloc(4 * u);    // [NB][4][HWO] = ft0l, ft1l
  float* ftR = alloc(4 * u);    // [NB][4][HWO] = ft1r, ft2r
  float* occl = alloc(u);
  float* occr = alloc(u);
  __bf16* wB1h = (__bf16*)alloc(16384);  // mask1: KTOT=1024, CO=32 -> 32768 bf16
  __bf16* wB1l = (__bf16*)alloc(16384);
  __bf16* wB2h = (__bf16*)alloc(2304);   // mask2: KTOT=288, CO=16 -> 4608 bf16
  __bf16* wB2l = (__bf16*)alloc(2304);
  __bf16* wBch = (__bf16*)alloc(1280);   // convds2: KTOT=160, CO=16 -> 2560 bf16
  __bf16* wBcl = (__bf16*)alloc(1280);
  float* mn1 = xsc1;                  // [NB][32][HWO] = 32u
  float* mn2 = xsc1 + 32 * u;         // [NB][16][HWO] = 16u

  const int TPB = 256;
  auto NBLK = [](long long t) { return (unsigned)((t + 255) / 256); };

  // weight prep (tiny): split-bf16 + MFMA B-fragment swizzle
  prep_w_kernel<<<NBLK(1024 * 32), TPB, 0, stream>>>(m_w1, wB1h, wB1l, 32, 36, 40, 5, 1024);
  prep_w_kernel<<<NBLK(288 * 16), TPB, 0, stream>>>(m_w2, wB2h, wB2l, 16, 32, 32, 3, 288);
  prep_w_kernel<<<NBLK(160 * 16), TPB, 0, stream>>>(c_w2, wBch, wBcl, 16, 16, 16, 3, 160);

  ds_enc_kernel<<<NBLK((long long)NB * 3 * HWO), TPB, 0, stream>>>(enc, t1, t2, wmb);

  convds1_kernel<<<NBLK((long long)3 * NB * HWO), TPB, 0, stream>>>(x0, x1, x2, c_w1, c_b1, c_a1, xsc1);
  // convds2: 16->16 3x3 over 6 batches -> xs [NB][48][HWO]
  conv_mfma_kernel<16, 0, 16, 3, 16, 5, true><<<6 * 32 * 28, TPB, 0, stream>>>(
      xsc1, 16L * HWO, nullptr, 0, wBch, wBcl, c_b2, c_a2, xs, 16L * HWO);

  // flow splat path
  hipMemsetAsync(splat, 0, 12 * u * sizeof(float), stream);
  fwarp_all_kernel<<<NBLK((long long)2 * NB * HWO), TPB, 0, stream>>>(
      flw[0], flw[1], flw[2], flw[3], t1, t2, splat);
  cfr_all_kernel<<<NBLK((long long)2 * NB * HWO), TPB, 0, stream>>>(splat, t1, t2, ftL, ftR);

  // masknet left: input = xs[n][0:32] ++ ftL[n][0:4]
  conv_mfma_kernel<32, 4, 40, 5, 32, 4, true><<<NB * 32 * 28, TPB, 0, stream>>>(
      xs, 48L * HWO, ftL, 4L * HWO, wB1h, wB1l, m_b1, m_a1, mn1, 32L * HWO);
  conv_mfma_kernel<32, 0, 32, 3, 16, 9, true><<<NB * 32 * 28, TPB, 0, stream>>>(
      mn1, 32L * HWO, nullptr, 0, wB2h, wB2l, m_b2, m_a2, mn2, 16L * HWO);
  conv3x3_kernel<16, 1, false><<<NBLK((long long)NB * HWO), TPB, 0, stream>>>(mn2, m_w3, m_b3, m_b3, occl, NB);
  // masknet right: input = xs[n][16:48] ++ ftR[n][0:4]
  conv_mfma_kernel<32, 4, 40, 5, 32, 4, true><<<NB * 32 * 28, TPB, 0, stream>>>(
      xs + (size_t)16 * HWO, 48L * HWO, ftR, 4L * HWO, wB1h, wB1l, m_b1, m_a1, mn1, 32L * HWO);
  conv_mfma_kernel<32, 0, 32, 3, 16, 9, true><<<NB * 32 * 28, TPB, 0, stream>>>(
      mn1, 32L * HWO, nullptr, 0, wB2h, wB2l, m_b2, m_a2, mn2, 16L * HWO);
  conv3x3_kernel<16, 1, false><<<NBLK((long long)NB * HWO), TPB, 0, stream>>>(mn2, m_w3, m_b3, m_b3, occr, NB);

  // blend + fused final 1x1 -> d_out
  blend_out_kernel<<<NBLK((long long)NB * HWO), TPB, 0, stream>>>(
      xs, ftL, ftR, occl, occr, t1, t2, wmb, f_w, f_b, f_a, out);
}

// Round 7
// 664.826 us; speedup vs baseline: 2.4475x; 1.1789x over previous
//
#include <hip/hip_runtime.h>
#include <math.h>

#define DEV __device__ __forceinline__

constexpr int NB = 2;
constexpr int HI = 512, WI = 896;
constexpr int HO = 256, WO = 448;
constexpr int HWO = HO * WO;   // 114688
constexpr int HWI = HI * WI;   // 458752

typedef __bf16 bf16x8 __attribute__((ext_vector_type(8)));
typedef float f32x4 __attribute__((ext_vector_type(4)));

// ---------------- downsample (jax.image.resize bilinear, antialias=True, scale 1/2) ----------
DEV float ds_half(const float* __restrict__ p, int i, int j) {
  const float w4[4] = {1.f, 3.f, 3.f, 1.f};
  float wc[4]; int cc[4];
  float cs = 0.f;
#pragma unroll
  for (int k = 0; k < 4; ++k) {
    int c = 2 * j - 1 + k;
    bool v = (c >= 0) && (c < WI);
    wc[k] = v ? w4[k] : 0.f;
    cc[k] = v ? c : 0;
    cs += wc[k];
  }
  float acc = 0.f, rs = 0.f;
#pragma unroll
  for (int k = 0; k < 4; ++k) {
    int r = 2 * i - 1 + k;
    if (r < 0 || r >= HI) continue;
    const float* row = p + (size_t)r * WI;
    float racc = 0.f;
#pragma unroll
    for (int b = 0; b < 4; ++b) racc += wc[b] * row[cc[b]];
    acc += w4[k] * racc;
    rs += w4[k];
  }
  return acc / (rs * cs);
}

__global__ void ds_enc_kernel(const float* __restrict__ enc, float* __restrict__ t1,
                              float* __restrict__ t2, float* __restrict__ wm) {
  int gid = blockIdx.x * blockDim.x + threadIdx.x;
  int total = NB * 3 * HWO;
  if (gid >= total) return;
  int p = gid % HWO;
  int nc = gid / HWO;
  int c = nc % 3, n = nc / 3;
  int i = p / WO, j = p % WO;
  float v = ds_half(enc + (size_t)(n * 3 + c) * HWI, i, j);
  float* dst = (c == 0) ? t1 : (c == 1 ? t2 : wm);
  dst[(size_t)n * HWO + p] = v;
}

// ---------------- weight prep: [CO][CIr][KS*KS] fp32 -> B-fragment-swizzled bf16 hi/lo ----------
__global__ void prep_w_kernel(const float* __restrict__ w, __bf16* __restrict__ bh,
                              __bf16* __restrict__ bl, int CO, int CIr, int CIP, int KS,
                              int KTOT) {
  int idx = blockIdx.x * blockDim.x + threadIdx.x;
  int total = KTOT * CO;
  if (idx >= total) return;
  int NT = CO / 16;
  int j = idx & 7;
  int l = (idx >> 3) & 63;
  int rest = idx >> 9;
  int s = rest / NT, nt = rest % NT;
  int k = s * 32 + ((l >> 4) & 3) * 8 + j;
  int n = nt * 16 + (l & 15);
  int kpos = k / CIP, ci = k % CIP;
  float v = (kpos < KS * KS && ci < CIr) ? w[((size_t)n * CIr + ci) * KS * KS + kpos] : 0.f;
  __bf16 h = (__bf16)v;
  bh[idx] = h;
  bl[idx] = (__bf16)(v - (float)h);
}

// ---------------- convds first conv: 3x3 stride2 pad1, 3->16, prelu ----------
__global__ void __launch_bounds__(256, 2)
convds1_kernel(const float* __restrict__ x0, const float* __restrict__ x1,
               const float* __restrict__ x2, const float* __restrict__ w,
               const float* __restrict__ bias, const float* __restrict__ alpha,
               float* __restrict__ out) {
  __shared__ float sw[16 * 3 * 9];
  __shared__ float sb[16];
  __shared__ float sa[16];
  for (int idx = threadIdx.x; idx < 432; idx += blockDim.x) sw[idx] = w[idx];
  if (threadIdx.x < 16) { sb[threadIdx.x] = bias[threadIdx.x]; sa[threadIdx.x] = alpha[threadIdx.x]; }
  __syncthreads();
  int gid = blockIdx.x * blockDim.x + threadIdx.x;
  int total = 3 * NB * HWO;
  if (gid >= total) return;
  int p = gid % HWO;
  int ni = gid / HWO;            // n*3+img
  int n = ni / 3, img = ni % 3;
  int i = p / WO, j = p % WO;
  const float* x = (img == 0 ? x0 : (img == 1 ? x1 : x2)) + (size_t)n * 3 * HWI;
  float in[27];
  int q = 0;
#pragma unroll
  for (int ci = 0; ci < 3; ++ci)
#pragma unroll
    for (int ky = 0; ky < 3; ++ky) {
      int r = 2 * i + ky - 1;
#pragma unroll
      for (int kx = 0; kx < 3; ++kx) {
        int c = 2 * j + kx - 1;
        in[q++] = (r >= 0 && r < HI && c >= 0 && c < WI) ? x[((size_t)ci * HI + r) * WI + c] : 0.f;
      }
    }
  float* o = out + (size_t)ni * 16 * HWO + p;
#pragma unroll
  for (int co = 0; co < 16; ++co) {
    float acc = sb[co];
    const float* wp = sw + co * 27;
#pragma unroll
    for (int k = 0; k < 27; ++k) acc += wp[k] * in[k];
    o[(size_t)co * HWO] = acc >= 0.f ? acc : sa[co] * acc;
  }
}

// ---------------- implicit-GEMM conv via MFMA, split-bf16 for fp32 accuracy ----------
template <int CIr1, int CIr2, int CIP, int KS, int CO, int SB, bool PRELU>
__global__ void __launch_bounds__(256, 2)
conv_mfma_kernel(const float* __restrict__ in1, long s1,
                 const float* __restrict__ in2, long s2,
                 const __bf16* __restrict__ wBh, const __bf16* __restrict__ wBl,
                 const float* __restrict__ bias, const float* __restrict__ alpha,
                 float* __restrict__ out, long so) {
  constexpr int TR = 8;
  constexpr int TRH = TR + KS - 1;
  constexpr int TCH = 16 + KS - 1;
  constexpr int NPX = TRH * TCH;
  constexpr int NT = CO / 16;
  constexpr int KREAL = KS * KS * CIP;
  constexpr int KTOT = ((KREAL + 31) / 32) * 32;
  constexpr int NSLICE = KTOT / 32;
  constexpr int RCHUNK = KREAL / 8;
  constexpr int PAD = KS / 2;
  constexpr int CPC = CIP / 8;
  constexpr int NTY = HO / TR;
  constexpr int NTX = WO / 16;

  __shared__ __align__(16) __bf16 Ah[NPX * CIP];
  __shared__ __align__(16) __bf16 Al[NPX * CIP];
  __shared__ __align__(16) __bf16 Bh[SB * NT * 512];
  __shared__ __align__(16) __bf16 Bl[SB * NT * 512];

  int tid = threadIdx.x;
  int bx = blockIdx.x;
  int b = bx / (NTY * NTX);
  int rem = bx % (NTY * NTX);
  int row0 = (rem / NTX) * TR;
  int col0 = (rem % NTX) * 16;

  for (int e = tid; e < NPX * CIP; e += 256) {
    int ci = e / NPX;
    int pxi = e % NPX;
    int y = pxi / TCH, x = pxi % TCH;
    int gy = row0 + y - PAD, gx = col0 + x - PAD;
    float v = 0.f;
    if (ci < CIr1 + CIr2 && gy >= 0 && gy < HO && gx >= 0 && gx < WO) {
      v = (ci < CIr1) ? in1[(size_t)b * s1 + (size_t)ci * HWO + gy * WO + gx]
                      : in2[(size_t)b * s2 + (size_t)(ci - CIr1) * HWO + gy * WO + gx];
    }
    __bf16 h = (__bf16)v;
    Ah[pxi * CIP + ci] = h;
    Al[pxi * CIP + ci] = (__bf16)(v - (float)h);
  }

  int lane = tid & 63, wid = tid >> 6;

  f32x4 acc[2][NT];
  float aco[NT];
#pragma unroll
  for (int nt = 0; nt < NT; ++nt) {
    float bv = bias[nt * 16 + (lane & 15)];
    aco[nt] = PRELU ? alpha[nt * 16 + (lane & 15)] : 0.f;
    f32x4 z = {bv, bv, bv, bv};
    acc[0][nt] = z;
    acc[1][nt] = z;
  }

  const uint4* gBh = reinterpret_cast<const uint4*>(wBh);
  const uint4* gBl = reinterpret_cast<const uint4*>(wBl);
  uint4* lBh = reinterpret_cast<uint4*>(Bh);
  uint4* lBl = reinterpret_cast<uint4*>(Bl);

  for (int s0 = 0; s0 < NSLICE; s0 += SB) {
    if (s0 > 0) __syncthreads();
    constexpr int NU = SB * NT * 64;
    for (int u = tid; u < NU; u += 256) {
      lBh[u] = gBh[(size_t)s0 * NT * 64 + u];
      lBl[u] = gBl[(size_t)s0 * NT * 64 + u];
    }
    __syncthreads();
#pragma unroll
    for (int s = 0; s < SB; ++s) {
      int slice = s0 + s;
      bf16x8 bh[NT], bl[NT];
#pragma unroll
      for (int nt = 0; nt < NT; ++nt) {
        bh[nt] = __builtin_bit_cast(bf16x8, lBh[(s * NT + nt) * 64 + lane]);
        bl[nt] = __builtin_bit_cast(bf16x8, lBl[(s * NT + nt) * 64 + lane]);
      }
      int g = slice * 4 + (lane >> 4);
      if (g > RCHUNK - 1) g = RCHUNK - 1;
      int kpos = g / CPC;
      int ci0 = (g % CPC) * 8;
      int ky = kpos / KS, kx = kpos % KS;
      int xoff = ((lane & 15) + kx) * CIP + ci0;
#pragma unroll
      for (int mt = 0; mt < 2; ++mt) {
        int r = wid * 2 + mt;
        int addr = (r + ky) * TCH * CIP + xoff;
        bf16x8 ah = __builtin_bit_cast(bf16x8, *reinterpret_cast<const uint4*>(Ah + addr));
        bf16x8 al = __builtin_bit_cast(bf16x8, *reinterpret_cast<const uint4*>(Al + addr));
#pragma unroll
        for (int nt = 0; nt < NT; ++nt) {
          acc[mt][nt] = __builtin_amdgcn_mfma_f32_16x16x32_bf16(ah, bh[nt], acc[mt][nt], 0, 0, 0);
          acc[mt][nt] = __builtin_amdgcn_mfma_f32_16x16x32_bf16(ah, bl[nt], acc[mt][nt], 0, 0, 0);
          acc[mt][nt] = __builtin_amdgcn_mfma_f32_16x16x32_bf16(al, bh[nt], acc[mt][nt], 0, 0, 0);
        }
      }
    }
  }

#pragma unroll
  for (int mt = 0; mt < 2; ++mt) {
    int gr = row0 + wid * 2 + mt;
#pragma unroll
    for (int nt = 0; nt < NT; ++nt) {
      int co = nt * 16 + (lane & 15);
      float* op = out + (size_t)b * so + (size_t)co * HWO + (size_t)gr * WO + col0 + (lane >> 4) * 4;
#pragma unroll
      for (int reg = 0; reg < 4; ++reg) {
        float v = acc[mt][nt][reg];
        if (PRELU) v = v >= 0.f ? v : aco[nt] * v;
        op[reg] = v;
      }
    }
  }
}

// ---------------- small generic 3x3 conv (kept for 16->1) ----------
template <int CI, int CO, bool PRELU>
__global__ void __launch_bounds__(256, 2)
conv3x3_kernel(const float* __restrict__ in, const float* __restrict__ w,
               const float* __restrict__ bias, const float* __restrict__ alpha,
               float* __restrict__ out, int B) {
  __shared__ float sw[CO * CI * 9];
  __shared__ float sb[CO];
  __shared__ float sa[CO];
  for (int idx = threadIdx.x; idx < CO * CI * 9; idx += blockDim.x) sw[idx] = w[idx];
  if (threadIdx.x < CO) {
    sb[threadIdx.x] = bias[threadIdx.x];
    sa[threadIdx.x] = PRELU ? alpha[threadIdx.x] : 0.f;
  }
  __syncthreads();
  int gid = blockIdx.x * blockDim.x + threadIdx.x;
  int total = B * HWO;
  if (gid >= total) return;
  int p = gid % HWO, b = gid / HWO;
  int i = p / WO, j = p % WO;
  const float* xb = in + (size_t)b * CI * HWO;
  float acc[CO];
#pragma unroll
  for (int co = 0; co < CO; ++co) acc[co] = sb[co];
  for (int ci = 0; ci < CI; ++ci) {
    const float* xc = xb + (size_t)ci * HWO;
    float taps[9];
    int q = 0;
#pragma unroll
    for (int ky = 0; ky < 3; ++ky) {
      int r = i + ky - 1;
#pragma unroll
      for (int kx = 0; kx < 3; ++kx) {
        int c = j + kx - 1;
        taps[q++] = (r >= 0 && r < HO && c >= 0 && c < WO) ? xc[(size_t)r * WO + c] : 0.f;
      }
    }
#pragma unroll
    for (int co = 0; co < CO; ++co) {
      const float* wp = sw + (co * CI + ci) * 9;
      float s = acc[co];
#pragma unroll
      for (int k = 0; k < 9; ++k) s += wp[k] * taps[k];
      acc[co] = s;
    }
  }
  float* ob = out + (size_t)b * CO * HWO + p;
#pragma unroll
  for (int co = 0; co < CO; ++co) {
    float v = acc[co];
    if (PRELU) v = v >= 0.f ? v : sa[co] * v;
    ob[(size_t)co * HWO] = v;
  }
}

// ---------------- forward splat: LDS-tiled (guideline 12: pre-reduce, then few atomics) ----
// One block = one 32x32 tile of one (side, flowA/B, n). Splats within +-RH px accumulate in
// LDS ([cell][3] via ds_add_f32); far splats (<0.2% of px) hit global directly; then one
// dense coalesced flush with ~1 global atomic per touched cell. Replaces 24 scattered
// device-scope RMW/px (round-6: 150MB HBM write, 200us) with ~7 coalesced RMW/px.
constexpr int FTS = 32;              // tile side
constexpr int FRH = 8;               // halo radius
constexpr int FTH = FTS + 2 * FRH;   // 48
constexpr int FNTX = WO / FTS;       // 14
constexpr int FNTY = HO / FTS;       // 8

__global__ void __launch_bounds__(256, 2)
fwarp_tile_kernel(const float* __restrict__ flow0, const float* __restrict__ flow1,
                  const float* __restrict__ flow2, const float* __restrict__ flow3,
                  const float* __restrict__ t1, const float* __restrict__ t2,
                  float* __restrict__ S /* 12u splat region, zeroed */) {
  __shared__ float acc[FTH * FTH * 3];
  int tid = threadIdx.x;
  for (int e = tid; e < FTH * FTH * 3; e += 256) acc[e] = 0.f;
  __syncthreads();

  const size_t u = (size_t)NB * HWO;
  int bx = blockIdx.x;
  int tile = bx % (FNTY * FNTX); bx /= (FNTY * FNTX);
  int n = bx % NB; bx /= NB;
  int ab = bx & 1;
  int side = bx >> 1;
  int row0 = (tile / FNTX) * FTS;
  int col0 = (tile % FNTX) * FTS;

  const float* flo = side ? (ab ? flow3 : flow2) : (ab ? flow1 : flow0);
  const float* t = side ? t2 : t1;
  float* basep = S + (size_t)side * 6 * u;
  float* imgw = basep + (size_t)ab * 2 * u;          // [NB][2][HWO]
  float* nw = basep + 4 * u + (size_t)ab * u;        // [NB][HWO]
  const float* flo0 = flo + ((size_t)n * 2 + 0) * HWI;
  const float* flo1 = flo + ((size_t)n * 2 + 1) * HWI;
  float* iw0 = imgw + ((size_t)n * 2 + 0) * HWO;
  float* iw1 = imgw + ((size_t)n * 2 + 1) * HWO;
  float* nwp = nw + (size_t)n * HWO;

#pragma unroll
  for (int k = 0; k < FTS * FTS / 256; ++k) {
    int pl = tid + k * 256;
    int ly = pl / FTS, lx = pl % FTS;
    int i = row0 + ly, j = col0 + lx;
    float f0 = 0.5f * ds_half(flo0, i, j);   // col shift
    float f1 = 0.5f * ds_half(flo1, i, j);   // row shift
    float tv = t[(size_t)n * HWO + i * WO + j];
    float s = ab ? (1.f - tv) : tv;
    float xr = s * f1;  // row displacement
    float yc = s * f0;  // col displacement
    float x1f = floorf(xr), y1f = floorf(yc);
#pragma unroll
    for (int dx = 0; dx < 2; ++dx)
#pragma unroll
      for (int dy = 0; dy < 2; ++dy) {
        float sx = x1f + (float)dx;
        float sy = y1f + (float)dy;
        float ddx = xr - sx, ddy = yc - sy;
        float wgt = expf(-(ddx * ddx + ddy * ddy));
        int r = (int)sx + i;
        int c = (int)sy + j;
        int lr = r - row0 + FRH, lc = c - col0 + FRH;
        if (lr >= 0 && lr < FTH && lc >= 0 && lc < FTH) {
          int cell = (lr * FTH + lc) * 3;
          atomicAdd(&acc[cell + 0], f0 * wgt);
          atomicAdd(&acc[cell + 1], f1 * wgt);
          atomicAdd(&acc[cell + 2], wgt);
        } else if (r >= 0 && r < HO && c >= 0 && c < WO) {
          size_t o = (size_t)r * WO + c;
          atomicAdd(iw0 + o, f0 * wgt);
          atomicAdd(iw1 + o, f1 * wgt);
          atomicAdd(nwp + o, wgt);
        }
      }
  }
  __syncthreads();
  // dense flush: consecutive tid -> consecutive lx -> coalesced atomics
  for (int e = tid; e < FTH * FTH; e += 256) {
    int ly = e / FTH, lx = e % FTH;
    int r = row0 + ly - FRH, c = col0 + lx - FRH;
    if (r < 0 || r >= HO || c < 0 || c >= WO) continue;
    float v2 = acc[e * 3 + 2];
    if (v2 == 0.f) continue;      // wgt>0 always => untouched cell
    size_t o = (size_t)r * WO + c;
    atomicAdd(iw0 + o, acc[e * 3 + 0]);
    atomicAdd(iw1 + o, acc[e * 3 + 1]);
    atomicAdd(nwp + o, v2);
  }
}

// combine -> ftL [NB][4][HWO] = (ft0l ch0,ch1, ft1l ch0,ch1); ftR likewise (ft1r, ft2r)
__global__ void cfr_all_kernel(const float* __restrict__ S,
                               const float* __restrict__ t1, const float* __restrict__ t2,
                               float* __restrict__ ftL, float* __restrict__ ftR) {
  const size_t u = (size_t)NB * HWO;
  int gid = blockIdx.x * blockDim.x + threadIdx.x;
  int total = 2 * NB * HWO;
  if (gid >= total) return;
  int side = gid / (NB * HWO);
  int rem = gid % (NB * HWO);
  int n = rem / HWO, p = rem % HWO;
  const float* base = S + (size_t)side * 6 * u;
  const float* f01w = base;
  const float* f10w = base + 2 * u;
  const float* n0 = base + 4 * u;
  const float* n1 = base + 5 * u;
  const float* t = side ? t2 : t1;
  float* ft = side ? ftR : ftL;
  size_t np = (size_t)n * HWO + p;
  float tv = t[np];
  float norm = (1.f - tv) * n0[np] + tv * n1[np];
  bool pos = norm > 0.f;
#pragma unroll
  for (int ch = 0; ch < 2; ++ch) {
    size_t sidx = ((size_t)n * 2 + ch) * HWO + p;
    float a = f01w[sidx];
    float b = f10w[sidx];
    float v0 = -(1.f - tv) * tv * a + tv * tv * b;
    float v1 = (1.f - tv) * (1.f - tv) * a - tv * (1.f - tv) * b;
    ft[((size_t)n * 4 + ch) * HWO + p]     = pos ? v0 / norm : v0;
    ft[((size_t)n * 4 + 2 + ch) * HWO + p] = pos ? v1 / norm : v1;
  }
}

// ---------------- backward warp + occlusion blend + final 1x1 conv ----------
DEV float sigmoidf_(float x) { return 1.f / (1.f + expf(-x)); }

DEV void bwarp16(const float* __restrict__ x /* [16][HWO] */, const float* __restrict__ flo /* [2][HWO] */,
                 int p, int i, int j, float* o) {
  float fx = flo[p];
  float fy = flo[HWO + p];
  float gx = (float)j + fx, gy = (float)i + fy;
  float nx = 2.f * gx / (float)(WO - 1) - 1.f;
  float ny = 2.f * gy / (float)(HO - 1) - 1.f;
  float px = ((nx + 1.f) * (float)WO - 1.f) * 0.5f;
  float py = ((ny + 1.f) * (float)HO - 1.f) * 0.5f;
  float cx = fminf(fmaxf(px, 0.f), (float)(WO - 1));
  float cy = fminf(fmaxf(py, 0.f), (float)(HO - 1));
  float x0f = floorf(cx), y0f = floorf(cy);
  float wx = cx - x0f, wy = cy - y0f;
  int x0i = (int)x0f; x0i = x0i < 0 ? 0 : (x0i > WO - 1 ? WO - 1 : x0i);
  int y0i = (int)y0f; y0i = y0i < 0 ? 0 : (y0i > HO - 1 ? HO - 1 : y0i);
  int x1i = x0i + 1 > WO - 1 ? WO - 1 : x0i + 1;
  int y1i = y0i + 1 > HO - 1 ? HO - 1 : y0i + 1;
  float fx0 = floorf(px), fy0 = floorf(py);
  float ux = px - fx0, uy = py - fy0;
  float WOf = (float)WO, HOf = (float)HO;
  float i00 = (fx0 >= 0.f && fx0 < WOf && fy0 >= 0.f && fy0 < HOf) ? 1.f : 0.f;
  float i10 = (fx0 + 1.f >= 0.f && fx0 + 1.f < WOf && fy0 >= 0.f && fy0 < HOf) ? 1.f : 0.f;
  float i01 = (fx0 >= 0.f && fx0 < WOf && fy0 + 1.f >= 0.f && fy0 + 1.f < HOf) ? 1.f : 0.f;
  float i11 = (fx0 + 1.f >= 0.f && fx0 + 1.f < WOf && fy0 + 1.f >= 0.f && fy0 + 1.f < HOf) ? 1.f : 0.f;
  float mv = (1.f - ux) * (1.f - uy) * i00 + ux * (1.f - uy) * i10
           + (1.f - ux) * uy * i01 + ux * uy * i11;
  float mask = mv >= 0.999f ? 1.f : 0.f;
  float w00 = (1.f - wx) * (1.f - wy), w10 = wx * (1.f - wy);
  float w01 = (1.f - wx) * wy, w11 = wx * wy;
  int a00 = y0i * WO + x0i, a10 = y0i * WO + x1i;
  int a01 = y1i * WO + x0i, a11 = y1i * WO + x1i;
#pragma unroll
  for (int c = 0; c < 16; ++c) {
    const float* xc = x + (size_t)c * HWO;
    o[c] = (w00 * xc[a00] + w10 * xc[a10] + w01 * xc[a01] + w11 * xc[a11]) * mask;
  }
}

__global__ void __launch_bounds__(256, 2)
blend_out_kernel(const float* __restrict__ xs /* [NB][48][HWO] */,
                 const float* __restrict__ ftL, const float* __restrict__ ftR,
                 const float* __restrict__ occl, const float* __restrict__ occr,
                 const float* __restrict__ t1, const float* __restrict__ t2,
                 const float* __restrict__ wm,
                 const float* __restrict__ fw, const float* __restrict__ fb,
                 const float* __restrict__ fa,
                 float* __restrict__ out /* [NB][16][HWO] */) {
  __shared__ float sw[512];
  __shared__ float sb[16];
  __shared__ float sa[16];
  for (int idx = threadIdx.x; idx < 512; idx += blockDim.x) sw[idx] = fw[idx];
  if (threadIdx.x < 16) { sb[threadIdx.x] = fb[threadIdx.x]; sa[threadIdx.x] = fa[threadIdx.x]; }
  __syncthreads();
  int gid = blockIdx.x * blockDim.x + threadIdx.x;
  int total = NB * HWO;
  if (gid >= total) return;
  int p = gid % HWO, n = gid / HWO;
  int i = p / WO, j = p % WO;
  size_t np = (size_t)n * HWO + p;
  float wmv = wm[np];
  const float* xs0 = xs + (size_t)n * 48 * HWO;
  const float* xs1 = xs0 + (size_t)16 * HWO;
  const float* xs2 = xs0 + (size_t)32 * HWO;
  const float* fl = ftL + (size_t)n * 4 * HWO;
  const float* fr = ftR + (size_t)n * 4 * HWO;
  float A[16], B[16];
  float bw0[16], bw1[16];
  {
    float t = t1[np];
    float o0 = sigmoidf_(occl[np]);
    float o1 = 1.f - o0;
    bwarp16(xs0, fl, p, i, j, bw0);
    bwarp16(xs1, fl + (size_t)2 * HWO, p, i, j, bw1);
    float c0 = (1.f - t) * o0, c1 = t * o1;
    float r = wmv / (c0 + c1);
#pragma unroll
    for (int c = 0; c < 16; ++c) A[c] = (c0 * bw0[c] + c1 * bw1[c]) * r;
  }
  {
    float t = t2[np];
    float o0 = sigmoidf_(occr[np]);
    float o1 = 1.f - o0;
    bwarp16(xs1, fr, p, i, j, bw0);
    bwarp16(xs2, fr + (size_t)2 * HWO, p, i, j, bw1);
    float c0 = (1.f - t) * o0, c1 = t * o1;
    float r = (1.f - wmv) / (c0 + c1);
#pragma unroll
    for (int c = 0; c < 16; ++c) B[c] = (c0 * bw0[c] + c1 * bw1[c]) * r;
  }
  float* ob = out + (size_t)n * 16 * HWO + p;
#pragma unroll
  for (int co = 0; co < 16; ++co) {
    float s = sb[co];
    const float* wp = sw + co * 32;
#pragma unroll
    for (int ci = 0; ci < 16; ++ci) s += wp[ci] * A[ci];
#pragma unroll
    for (int ci = 0; ci < 16; ++ci) s += wp[16 + ci] * B[ci];
    ob[(size_t)co * HWO] = s >= 0.f ? s : sa[co] * s;
  }
}

extern "C" void kernel_launch(void* const* d_in, const int* in_sizes, int n_in,
                              void* d_out, int out_size, void* d_ws, size_t ws_size,
                              hipStream_t stream) {
  const float* x0 = (const float*)d_in[0];
  const float* x1 = (const float*)d_in[1];
  const float* x2 = (const float*)d_in[2];
  const float* flw[4] = {(const float*)d_in[3], (const float*)d_in[4],
                         (const float*)d_in[5], (const float*)d_in[6]};
  const float* enc  = (const float*)d_in[7];
  const float* c_w1 = (const float*)d_in[8];
  const float* c_b1 = (const float*)d_in[9];
  const float* c_a1 = (const float*)d_in[10];
  const float* c_w2 = (const float*)d_in[11];
  const float* c_b2 = (const float*)d_in[12];
  const float* c_a2 = (const float*)d_in[13];
  const float* m_w1 = (const float*)d_in[14];
  const float* m_b1 = (const float*)d_in[15];
  const float* m_a1 = (const float*)d_in[16];
  const float* m_w2 = (const float*)d_in[17];
  const float* m_b2 = (const float*)d_in[18];
  const float* m_a2 = (const float*)d_in[19];
  const float* m_w3 = (const float*)d_in[20];
  const float* m_b3 = (const float*)d_in[21];
  const float* f_w  = (const float*)d_in[22];
  const float* f_b  = (const float*)d_in[23];
  const float* f_a  = (const float*)d_in[24];
  float* out = (float*)d_out;

  const size_t u = (size_t)NB * HWO;  // 229376 floats
  float* base = (float*)d_ws;
  size_t off = 0;
  auto alloc = [&](size_t nfl) { float* pp = base + off; off += nfl; return pp; };
  float* t1  = alloc(u);
  float* t2  = alloc(u);
  float* wmb = alloc(u);
  float* xs   = alloc(48 * u);  // [NB][48][HWO] convds output (n-major)
  float* xsc1 = alloc(48 * u);  // convds1 scratch; later mn1 (32u) + mn2 (16u)
  float* splat = alloc(12 * u); // [2 sides][imgwA 2u | imgwB 2u | nA u | nB u]
  float* ftL = alloc(4 * u);    // [NB][4][HWO] = ft0l, ft1l
  float* ftR = alloc(4 * u);    // [NB][4][HWO] = ft1r, ft2r
  float* occl = alloc(u);
  float* occr = alloc(u);
  __bf16* wB1h = (__bf16*)alloc(16384);  // mask1: KTOT=1024, CO=32 -> 32768 bf16
  __bf16* wB1l = (__bf16*)alloc(16384);
  __bf16* wB2h = (__bf16*)alloc(2304);   // mask2: KTOT=288, CO=16 -> 4608 bf16
  __bf16* wB2l = (__bf16*)alloc(2304);
  __bf16* wBch = (__bf16*)alloc(1280);   // convds2: KTOT=160, CO=16 -> 2560 bf16
  __bf16* wBcl = (__bf16*)alloc(1280);
  float* mn1 = xsc1;                  // [NB][32][HWO] = 32u
  float* mn2 = xsc1 + 32 * u;         // [NB][16][HWO] = 16u

  const int TPB = 256;
  auto NBLK = [](long long t) { return (unsigned)((t + 255) / 256); };

  // weight prep (tiny): split-bf16 + MFMA B-fragment swizzle
  prep_w_kernel<<<NBLK(1024 * 32), TPB, 0, stream>>>(m_w1, wB1h, wB1l, 32, 36, 40, 5, 1024);
  prep_w_kernel<<<NBLK(288 * 16), TPB, 0, stream>>>(m_w2, wB2h, wB2l, 16, 32, 32, 3, 288);
  prep_w_kernel<<<NBLK(160 * 16), TPB, 0, stream>>>(c_w2, wBch, wBcl, 16, 16, 16, 3, 160);

  ds_enc_kernel<<<NBLK((long long)NB * 3 * HWO), TPB, 0, stream>>>(enc, t1, t2, wmb);

  convds1_kernel<<<NBLK((long long)3 * NB * HWO), TPB, 0, stream>>>(x0, x1, x2, c_w1, c_b1, c_a1, xsc1);
  // convds2: 16->16 3x3 over 6 batches -> xs [NB][48][HWO]
  conv_mfma_kernel<16, 0, 16, 3, 16, 5, true><<<6 * 32 * 28, TPB, 0, stream>>>(
      xsc1, 16L * HWO, nullptr, 0, wBch, wBcl, c_b2, c_a2, xs, 16L * HWO);

  // flow splat path: LDS-tiled splat (2 sides x 2 flows x NB x 112 tiles)
  hipMemsetAsync(splat, 0, 12 * u * sizeof(float), stream);
  fwarp_tile_kernel<<<2 * 2 * NB * FNTY * FNTX, TPB, 0, stream>>>(
      flw[0], flw[1], flw[2], flw[3], t1, t2, splat);
  cfr_all_kernel<<<NBLK((long long)2 * NB * HWO), TPB, 0, stream>>>(splat, t1, t2, ftL, ftR);

  // masknet left: input = xs[n][0:32] ++ ftL[n][0:4]
  conv_mfma_kernel<32, 4, 40, 5, 32, 4, true><<<NB * 32 * 28, TPB, 0, stream>>>(
      xs, 48L * HWO, ftL, 4L * HWO, wB1h, wB1l, m_b1, m_a1, mn1, 32L * HWO);
  conv_mfma_kernel<32, 0, 32, 3, 16, 9, true><<<NB * 32 * 28, TPB, 0, stream>>>(
      mn1, 32L * HWO, nullptr, 0, wB2h, wB2l, m_b2, m_a2, mn2, 16L * HWO);
  conv3x3_kernel<16, 1, false><<<NBLK((long long)NB * HWO), TPB, 0, stream>>>(mn2, m_w3, m_b3, m_b3, occl, NB);
  // masknet right: input = xs[n][16:48] ++ ftR[n][0:4]
  conv_mfma_kernel<32, 4, 40, 5, 32, 4, true><<<NB * 32 * 28, TPB, 0, stream>>>(
      xs + (size_t)16 * HWO, 48L * HWO, ftR, 4L * HWO, wB1h, wB1l, m_b1, m_a1, mn1, 32L * HWO);
  conv_mfma_kernel<32, 0, 32, 3, 16, 9, true><<<NB * 32 * 28, TPB, 0, stream>>>(
      mn1, 32L * HWO, nullptr, 0, wB2h, wB2l, m_b2, m_a2, mn2, 16L * HWO);
  conv3x3_kernel<16, 1, false><<<NBLK((long long)NB * HWO), TPB, 0, stream>>>(mn2, m_w3, m_b3, m_b3, occr, NB);

  // blend + fused final 1x1 -> d_out
  blend_out_kernel<<<NBLK((long long)NB * HWO), TPB, 0, stream>>>(
      xs, ftL, ftR, occl, occr, t1, t2, wmb, f_w, f_b, f_a, out);
}

// Round 8
// 605.644 us; speedup vs baseline: 2.6866x; 1.0977x over previous
//
#include <hip/hip_runtime.h>
#include <math.h>

#define DEV __device__ __forceinline__

constexpr int NB = 2;
constexpr int HI = 512, WI = 896;
constexpr int HO = 256, WO = 448;
constexpr int HWO = HO * WO;   // 114688
constexpr int HWI = HI * WI;   // 458752

typedef __bf16 bf16x8 __attribute__((ext_vector_type(8)));
typedef float f32x4 __attribute__((ext_vector_type(4)));

// ---------------- downsample (jax.image.resize bilinear, antialias=True, scale 1/2) ----------
DEV float ds_half(const float* __restrict__ p, int i, int j) {
  const float w4[4] = {1.f, 3.f, 3.f, 1.f};
  float wc[4]; int cc[4];
  float cs = 0.f;
#pragma unroll
  for (int k = 0; k < 4; ++k) {
    int c = 2 * j - 1 + k;
    bool v = (c >= 0) && (c < WI);
    wc[k] = v ? w4[k] : 0.f;
    cc[k] = v ? c : 0;
    cs += wc[k];
  }
  float acc = 0.f, rs = 0.f;
#pragma unroll
  for (int k = 0; k < 4; ++k) {
    int r = 2 * i - 1 + k;
    if (r < 0 || r >= HI) continue;
    const float* row = p + (size_t)r * WI;
    float racc = 0.f;
#pragma unroll
    for (int b = 0; b < 4; ++b) racc += wc[b] * row[cc[b]];
    acc += w4[k] * racc;
    rs += w4[k];
  }
  return acc / (rs * cs);
}

__global__ void ds_enc_kernel(const float* __restrict__ enc, float* __restrict__ t1,
                              float* __restrict__ t2, float* __restrict__ wm) {
  int gid = blockIdx.x * blockDim.x + threadIdx.x;
  int total = NB * 3 * HWO;
  if (gid >= total) return;
  int p = gid % HWO;
  int nc = gid / HWO;
  int c = nc % 3, n = nc / 3;
  int i = p / WO, j = p % WO;
  float v = ds_half(enc + (size_t)(n * 3 + c) * HWI, i, j);
  float* dst = (c == 0) ? t1 : (c == 1 ? t2 : wm);
  dst[(size_t)n * HWO + p] = v;
}

// ---------------- weight prep: [CO][CIr][KS*KS] fp32 -> B-fragment-swizzled bf16 hi/lo ----------
__global__ void prep_w_kernel(const float* __restrict__ w, __bf16* __restrict__ bh,
                              __bf16* __restrict__ bl, int CO, int CIr, int CIP, int KS,
                              int KTOT) {
  int idx = blockIdx.x * blockDim.x + threadIdx.x;
  int total = KTOT * CO;
  if (idx >= total) return;
  int NT = CO / 16;
  int j = idx & 7;
  int l = (idx >> 3) & 63;
  int rest = idx >> 9;
  int s = rest / NT, nt = rest % NT;
  int k = s * 32 + ((l >> 4) & 3) * 8 + j;
  int n = nt * 16 + (l & 15);
  int kpos = k / CIP, ci = k % CIP;
  float v = (kpos < KS * KS && ci < CIr) ? w[((size_t)n * CIr + ci) * KS * KS + kpos] : 0.f;
  __bf16 h = (__bf16)v;
  bh[idx] = h;
  bl[idx] = (__bf16)(v - (float)h);
}

// ---------------- convds first conv: 3x3 stride2 pad1, 3->16, prelu ----------
__global__ void __launch_bounds__(256, 2)
convds1_kernel(const float* __restrict__ x0, const float* __restrict__ x1,
               const float* __restrict__ x2, const float* __restrict__ w,
               const float* __restrict__ bias, const float* __restrict__ alpha,
               float* __restrict__ out) {
  __shared__ float sw[16 * 3 * 9];
  __shared__ float sb[16];
  __shared__ float sa[16];
  for (int idx = threadIdx.x; idx < 432; idx += blockDim.x) sw[idx] = w[idx];
  if (threadIdx.x < 16) { sb[threadIdx.x] = bias[threadIdx.x]; sa[threadIdx.x] = alpha[threadIdx.x]; }
  __syncthreads();
  int gid = blockIdx.x * blockDim.x + threadIdx.x;
  int total = 3 * NB * HWO;
  if (gid >= total) return;
  int p = gid % HWO;
  int ni = gid / HWO;            // n*3+img
  int n = ni / 3, img = ni % 3;
  int i = p / WO, j = p % WO;
  const float* x = (img == 0 ? x0 : (img == 1 ? x1 : x2)) + (size_t)n * 3 * HWI;
  float in[27];
  int q = 0;
#pragma unroll
  for (int ci = 0; ci < 3; ++ci)
#pragma unroll
    for (int ky = 0; ky < 3; ++ky) {
      int r = 2 * i + ky - 1;
#pragma unroll
      for (int kx = 0; kx < 3; ++kx) {
        int c = 2 * j + kx - 1;
        in[q++] = (r >= 0 && r < HI && c >= 0 && c < WI) ? x[((size_t)ci * HI + r) * WI + c] : 0.f;
      }
    }
  float* o = out + (size_t)ni * 16 * HWO + p;
#pragma unroll
  for (int co = 0; co < 16; ++co) {
    float acc = sb[co];
    const float* wp = sw + co * 27;
#pragma unroll
    for (int k = 0; k < 27; ++k) acc += wp[k] * in[k];
    o[(size_t)co * HWO] = acc >= 0.f ? acc : sa[co] * acc;
  }
}

// ---------------- implicit-GEMM conv via MFMA, split-bf16 for fp32 accuracy ----------
// SB chosen so LDS (A-tile 40KB for mask1 + B-stage) keeps >=3 blocks/CU: round-7 showed
// SB=4 -> 54.8KB -> 2 blocks/CU -> occupancy 20%, both pipes <25% busy (latency-bound).
template <int CIr1, int CIr2, int CIP, int KS, int CO, int SB, bool PRELU>
__global__ void __launch_bounds__(256, 2)
conv_mfma_kernel(const float* __restrict__ in1, long s1,
                 const float* __restrict__ in2, long s2,
                 const __bf16* __restrict__ wBh, const __bf16* __restrict__ wBl,
                 const float* __restrict__ bias, const float* __restrict__ alpha,
                 float* __restrict__ out, long so) {
  constexpr int TR = 8;
  constexpr int TRH = TR + KS - 1;
  constexpr int TCH = 16 + KS - 1;
  constexpr int NPX = TRH * TCH;
  constexpr int NT = CO / 16;
  constexpr int KREAL = KS * KS * CIP;
  constexpr int KTOT = ((KREAL + 31) / 32) * 32;
  constexpr int NSLICE = KTOT / 32;
  constexpr int RCHUNK = KREAL / 8;
  constexpr int PAD = KS / 2;
  constexpr int CPC = CIP / 8;
  constexpr int NTY = HO / TR;
  constexpr int NTX = WO / 16;

  __shared__ __align__(16) __bf16 Ah[NPX * CIP];
  __shared__ __align__(16) __bf16 Al[NPX * CIP];
  __shared__ __align__(16) __bf16 Bh[SB * NT * 512];
  __shared__ __align__(16) __bf16 Bl[SB * NT * 512];

  int tid = threadIdx.x;
  int bx = blockIdx.x;
  int b = bx / (NTY * NTX);
  int rem = bx % (NTY * NTX);
  int row0 = (rem / NTX) * TR;
  int col0 = (rem % NTX) * 16;

  for (int e = tid; e < NPX * CIP; e += 256) {
    int ci = e / NPX;
    int pxi = e % NPX;
    int y = pxi / TCH, x = pxi % TCH;
    int gy = row0 + y - PAD, gx = col0 + x - PAD;
    float v = 0.f;
    if (ci < CIr1 + CIr2 && gy >= 0 && gy < HO && gx >= 0 && gx < WO) {
      v = (ci < CIr1) ? in1[(size_t)b * s1 + (size_t)ci * HWO + gy * WO + gx]
                      : in2[(size_t)b * s2 + (size_t)(ci - CIr1) * HWO + gy * WO + gx];
    }
    __bf16 h = (__bf16)v;
    Ah[pxi * CIP + ci] = h;
    Al[pxi * CIP + ci] = (__bf16)(v - (float)h);
  }

  int lane = tid & 63, wid = tid >> 6;

  f32x4 acc[2][NT];
  float aco[NT];
#pragma unroll
  for (int nt = 0; nt < NT; ++nt) {
    float bv = bias[nt * 16 + (lane & 15)];
    aco[nt] = PRELU ? alpha[nt * 16 + (lane & 15)] : 0.f;
    f32x4 z = {bv, bv, bv, bv};
    acc[0][nt] = z;
    acc[1][nt] = z;
  }

  const uint4* gBh = reinterpret_cast<const uint4*>(wBh);
  const uint4* gBl = reinterpret_cast<const uint4*>(wBl);
  uint4* lBh = reinterpret_cast<uint4*>(Bh);
  uint4* lBl = reinterpret_cast<uint4*>(Bl);

  for (int s0 = 0; s0 < NSLICE; s0 += SB) {
    if (s0 > 0) __syncthreads();
    constexpr int NU = SB * NT * 64;
    for (int u = tid; u < NU; u += 256) {
      lBh[u] = gBh[(size_t)s0 * NT * 64 + u];
      lBl[u] = gBl[(size_t)s0 * NT * 64 + u];
    }
    __syncthreads();
#pragma unroll
    for (int s = 0; s < SB; ++s) {
      int slice = s0 + s;
      bf16x8 bh[NT], bl[NT];
#pragma unroll
      for (int nt = 0; nt < NT; ++nt) {
        bh[nt] = __builtin_bit_cast(bf16x8, lBh[(s * NT + nt) * 64 + lane]);
        bl[nt] = __builtin_bit_cast(bf16x8, lBl[(s * NT + nt) * 64 + lane]);
      }
      int g = slice * 4 + (lane >> 4);
      if (g > RCHUNK - 1) g = RCHUNK - 1;
      int kpos = g / CPC;
      int ci0 = (g % CPC) * 8;
      int ky = kpos / KS, kx = kpos % KS;
      int xoff = ((lane & 15) + kx) * CIP + ci0;
#pragma unroll
      for (int mt = 0; mt < 2; ++mt) {
        int r = wid * 2 + mt;
        int addr = (r + ky) * TCH * CIP + xoff;
        bf16x8 ah = __builtin_bit_cast(bf16x8, *reinterpret_cast<const uint4*>(Ah + addr));
        bf16x8 al = __builtin_bit_cast(bf16x8, *reinterpret_cast<const uint4*>(Al + addr));
#pragma unroll
        for (int nt = 0; nt < NT; ++nt) {
          acc[mt][nt] = __builtin_amdgcn_mfma_f32_16x16x32_bf16(ah, bh[nt], acc[mt][nt], 0, 0, 0);
          acc[mt][nt] = __builtin_amdgcn_mfma_f32_16x16x32_bf16(ah, bl[nt], acc[mt][nt], 0, 0, 0);
          acc[mt][nt] = __builtin_amdgcn_mfma_f32_16x16x32_bf16(al, bh[nt], acc[mt][nt], 0, 0, 0);
        }
      }
    }
  }

#pragma unroll
  for (int mt = 0; mt < 2; ++mt) {
    int gr = row0 + wid * 2 + mt;
#pragma unroll
    for (int nt = 0; nt < NT; ++nt) {
      int co = nt * 16 + (lane & 15);
      float* op = out + (size_t)b * so + (size_t)co * HWO + (size_t)gr * WO + col0 + (lane >> 4) * 4;
#pragma unroll
      for (int reg = 0; reg < 4; ++reg) {
        float v = acc[mt][nt][reg];
        if (PRELU) v = v >= 0.f ? v : aco[nt] * v;
        op[reg] = v;
      }
    }
  }
}

// ---------------- small generic 3x3 conv (kept for 16->1) ----------
template <int CI, int CO, bool PRELU>
__global__ void __launch_bounds__(256, 2)
conv3x3_kernel(const float* __restrict__ in, const float* __restrict__ w,
               const float* __restrict__ bias, const float* __restrict__ alpha,
               float* __restrict__ out, int B) {
  __shared__ float sw[CO * CI * 9];
  __shared__ float sb[CO];
  __shared__ float sa[CO];
  for (int idx = threadIdx.x; idx < CO * CI * 9; idx += blockDim.x) sw[idx] = w[idx];
  if (threadIdx.x < CO) {
    sb[threadIdx.x] = bias[threadIdx.x];
    sa[threadIdx.x] = PRELU ? alpha[threadIdx.x] : 0.f;
  }
  __syncthreads();
  int gid = blockIdx.x * blockDim.x + threadIdx.x;
  int total = B * HWO;
  if (gid >= total) return;
  int p = gid % HWO, b = gid / HWO;
  int i = p / WO, j = p % WO;
  const float* xb = in + (size_t)b * CI * HWO;
  float acc[CO];
#pragma unroll
  for (int co = 0; co < CO; ++co) acc[co] = sb[co];
  for (int ci = 0; ci < CI; ++ci) {
    const float* xc = xb + (size_t)ci * HWO;
    float taps[9];
    int q = 0;
#pragma unroll
    for (int ky = 0; ky < 3; ++ky) {
      int r = i + ky - 1;
#pragma unroll
      for (int kx = 0; kx < 3; ++kx) {
        int c = j + kx - 1;
        taps[q++] = (r >= 0 && r < HO && c >= 0 && c < WO) ? xc[(size_t)r * WO + c] : 0.f;
      }
    }
#pragma unroll
    for (int co = 0; co < CO; ++co) {
      const float* wp = sw + (co * CI + ci) * 9;
      float s = acc[co];
#pragma unroll
      for (int k = 0; k < 9; ++k) s += wp[k] * taps[k];
      acc[co] = s;
    }
  }
  float* ob = out + (size_t)b * CO * HWO + p;
#pragma unroll
  for (int co = 0; co < CO; ++co) {
    float v = acc[co];
    if (PRELU) v = v >= 0.f ? v : sa[co] * v;
    ob[(size_t)co * HWO] = v;
  }
}

// ---------------- forward splat: LDS-tiled ----------
constexpr int FTS = 32;
constexpr int FRH = 8;
constexpr int FTH = FTS + 2 * FRH;   // 48
constexpr int FNTX = WO / FTS;       // 14
constexpr int FNTY = HO / FTS;       // 8

__global__ void __launch_bounds__(256, 2)
fwarp_tile_kernel(const float* __restrict__ flow0, const float* __restrict__ flow1,
                  const float* __restrict__ flow2, const float* __restrict__ flow3,
                  const float* __restrict__ t1, const float* __restrict__ t2,
                  float* __restrict__ S /* 12u splat region, zeroed */) {
  __shared__ float acc[FTH * FTH * 3];
  int tid = threadIdx.x;
  for (int e = tid; e < FTH * FTH * 3; e += 256) acc[e] = 0.f;
  __syncthreads();

  const size_t u = (size_t)NB * HWO;
  int bx = blockIdx.x;
  int tile = bx % (FNTY * FNTX); bx /= (FNTY * FNTX);
  int n = bx % NB; bx /= NB;
  int ab = bx & 1;
  int side = bx >> 1;
  int row0 = (tile / FNTX) * FTS;
  int col0 = (tile % FNTX) * FTS;

  const float* flo = side ? (ab ? flow3 : flow2) : (ab ? flow1 : flow0);
  const float* t = side ? t2 : t1;
  float* basep = S + (size_t)side * 6 * u;
  float* imgw = basep + (size_t)ab * 2 * u;
  float* nw = basep + 4 * u + (size_t)ab * u;
  const float* flo0 = flo + ((size_t)n * 2 + 0) * HWI;
  const float* flo1 = flo + ((size_t)n * 2 + 1) * HWI;
  float* iw0 = imgw + ((size_t)n * 2 + 0) * HWO;
  float* iw1 = imgw + ((size_t)n * 2 + 1) * HWO;
  float* nwp = nw + (size_t)n * HWO;

#pragma unroll
  for (int k = 0; k < FTS * FTS / 256; ++k) {
    int pl = tid + k * 256;
    int ly = pl / FTS, lx = pl % FTS;
    int i = row0 + ly, j = col0 + lx;
    float f0 = 0.5f * ds_half(flo0, i, j);
    float f1 = 0.5f * ds_half(flo1, i, j);
    float tv = t[(size_t)n * HWO + i * WO + j];
    float s = ab ? (1.f - tv) : tv;
    float xr = s * f1;
    float yc = s * f0;
    float x1f = floorf(xr), y1f = floorf(yc);
#pragma unroll
    for (int dx = 0; dx < 2; ++dx)
#pragma unroll
      for (int dy = 0; dy < 2; ++dy) {
        float sx = x1f + (float)dx;
        float sy = y1f + (float)dy;
        float ddx = xr - sx, ddy = yc - sy;
        float wgt = expf(-(ddx * ddx + ddy * ddy));
        int r = (int)sx + i;
        int c = (int)sy + j;
        int lr = r - row0 + FRH, lc = c - col0 + FRH;
        if (lr >= 0 && lr < FTH && lc >= 0 && lc < FTH) {
          int cell = (lr * FTH + lc) * 3;
          atomicAdd(&acc[cell + 0], f0 * wgt);
          atomicAdd(&acc[cell + 1], f1 * wgt);
          atomicAdd(&acc[cell + 2], wgt);
        } else if (r >= 0 && r < HO && c >= 0 && c < WO) {
          size_t o = (size_t)r * WO + c;
          atomicAdd(iw0 + o, f0 * wgt);
          atomicAdd(iw1 + o, f1 * wgt);
          atomicAdd(nwp + o, wgt);
        }
      }
  }
  __syncthreads();
  for (int e = tid; e < FTH * FTH; e += 256) {
    int ly = e / FTH, lx = e % FTH;
    int r = row0 + ly - FRH, c = col0 + lx - FRH;
    if (r < 0 || r >= HO || c < 0 || c >= WO) continue;
    float v2 = acc[e * 3 + 2];
    if (v2 == 0.f) continue;
    size_t o = (size_t)r * WO + c;
    atomicAdd(iw0 + o, acc[e * 3 + 0]);
    atomicAdd(iw1 + o, acc[e * 3 + 1]);
    atomicAdd(nwp + o, v2);
  }
}

// combine -> ftL [NB][4][HWO] = (ft0l ch0,ch1, ft1l ch0,ch1); ftR likewise (ft1r, ft2r)
__global__ void cfr_all_kernel(const float* __restrict__ S,
                               const float* __restrict__ t1, const float* __restrict__ t2,
                               float* __restrict__ ftL, float* __restrict__ ftR) {
  const size_t u = (size_t)NB * HWO;
  int gid = blockIdx.x * blockDim.x + threadIdx.x;
  int total = 2 * NB * HWO;
  if (gid >= total) return;
  int side = gid / (NB * HWO);
  int rem = gid % (NB * HWO);
  int n = rem / HWO, p = rem % HWO;
  const float* base = S + (size_t)side * 6 * u;
  const float* f01w = base;
  const float* f10w = base + 2 * u;
  const float* n0 = base + 4 * u;
  const float* n1 = base + 5 * u;
  const float* t = side ? t2 : t1;
  float* ft = side ? ftR : ftL;
  size_t np = (size_t)n * HWO + p;
  float tv = t[np];
  float norm = (1.f - tv) * n0[np] + tv * n1[np];
  bool pos = norm > 0.f;
#pragma unroll
  for (int ch = 0; ch < 2; ++ch) {
    size_t sidx = ((size_t)n * 2 + ch) * HWO + p;
    float a = f01w[sidx];
    float b = f10w[sidx];
    float v0 = -(1.f - tv) * tv * a + tv * tv * b;
    float v1 = (1.f - tv) * (1.f - tv) * a - tv * (1.f - tv) * b;
    ft[((size_t)n * 4 + ch) * HWO + p]     = pos ? v0 / norm : v0;
    ft[((size_t)n * 4 + 2 + ch) * HWO + p] = pos ? v1 / norm : v1;
  }
}

// ---------------- backward warp + occlusion blend + final 1x1 conv ----------
DEV float sigmoidf_(float x) { return 1.f / (1.f + expf(-x)); }

DEV void bwarp16(const float* __restrict__ x /* [16][HWO] */, const float* __restrict__ flo /* [2][HWO] */,
                 int p, int i, int j, float* o) {
  float fx = flo[p];
  float fy = flo[HWO + p];
  float gx = (float)j + fx, gy = (float)i + fy;
  float nx = 2.f * gx / (float)(WO - 1) - 1.f;
  float ny = 2.f * gy / (float)(HO - 1) - 1.f;
  float px = ((nx + 1.f) * (float)WO - 1.f) * 0.5f;
  float py = ((ny + 1.f) * (float)HO - 1.f) * 0.5f;
  float cx = fminf(fmaxf(px, 0.f), (float)(WO - 1));
  float cy = fminf(fmaxf(py, 0.f), (float)(HO - 1));
  float x0f = floorf(cx), y0f = floorf(cy);
  float wx = cx - x0f, wy = cy - y0f;
  int x0i = (int)x0f; x0i = x0i < 0 ? 0 : (x0i > WO - 1 ? WO - 1 : x0i);
  int y0i = (int)y0f; y0i = y0i < 0 ? 0 : (y0i > HO - 1 ? HO - 1 : y0i);
  int x1i = x0i + 1 > WO - 1 ? WO - 1 : x0i + 1;
  int y1i = y0i + 1 > HO - 1 ? HO - 1 : y0i + 1;
  float fx0 = floorf(px), fy0 = floorf(py);
  float ux = px - fx0, uy = py - fy0;
  float WOf = (float)WO, HOf = (float)HO;
  float i00 = (fx0 >= 0.f && fx0 < WOf && fy0 >= 0.f && fy0 < HOf) ? 1.f : 0.f;
  float i10 = (fx0 + 1.f >= 0.f && fx0 + 1.f < WOf && fy0 >= 0.f && fy0 < HOf) ? 1.f : 0.f;
  float i01 = (fx0 >= 0.f && fx0 < WOf && fy0 + 1.f >= 0.f && fy0 + 1.f < HOf) ? 1.f : 0.f;
  float i11 = (fx0 + 1.f >= 0.f && fx0 + 1.f < WOf && fy0 + 1.f >= 0.f && fy0 + 1.f < HOf) ? 1.f : 0.f;
  float mv = (1.f - ux) * (1.f - uy) * i00 + ux * (1.f - uy) * i10
           + (1.f - ux) * uy * i01 + ux * uy * i11;
  float mask = mv >= 0.999f ? 1.f : 0.f;
  float w00 = (1.f - wx) * (1.f - wy), w10 = wx * (1.f - wy);
  float w01 = (1.f - wx) * wy, w11 = wx * wy;
  int a00 = y0i * WO + x0i, a10 = y0i * WO + x1i;
  int a01 = y1i * WO + x0i, a11 = y1i * WO + x1i;
#pragma unroll
  for (int c = 0; c < 16; ++c) {
    const float* xc = x + (size_t)c * HWO;
    o[c] = (w00 * xc[a00] + w10 * xc[a10] + w01 * xc[a01] + w11 * xc[a11]) * mask;
  }
}

__global__ void __launch_bounds__(256, 2)
blend_out_kernel(const float* __restrict__ xs /* [NB][48][HWO] */,
                 const float* __restrict__ ftL, const float* __restrict__ ftR,
                 const float* __restrict__ occl, const float* __restrict__ occr,
                 const float* __restrict__ t1, const float* __restrict__ t2,
                 const float* __restrict__ wm,
                 const float* __restrict__ fw, const float* __restrict__ fb,
                 const float* __restrict__ fa,
                 float* __restrict__ out /* [NB][16][HWO] */) {
  __shared__ float sw[512];
  __shared__ float sb[16];
  __shared__ float sa[16];
  for (int idx = threadIdx.x; idx < 512; idx += blockDim.x) sw[idx] = fw[idx];
  if (threadIdx.x < 16) { sb[threadIdx.x] = fb[threadIdx.x]; sa[threadIdx.x] = fa[threadIdx.x]; }
  __syncthreads();
  int gid = blockIdx.x * blockDim.x + threadIdx.x;
  int total = NB * HWO;
  if (gid >= total) return;
  int p = gid % HWO, n = gid / HWO;
  int i = p / WO, j = p % WO;
  size_t np = (size_t)n * HWO + p;
  float wmv = wm[np];
  const float* xs0 = xs + (size_t)n * 48 * HWO;
  const float* xs1 = xs0 + (size_t)16 * HWO;
  const float* xs2 = xs0 + (size_t)32 * HWO;
  const float* fl = ftL + (size_t)n * 4 * HWO;
  const float* fr = ftR + (size_t)n * 4 * HWO;
  float A[16], B[16];
  float bw0[16], bw1[16];
  {
    float t = t1[np];
    float o0 = sigmoidf_(occl[np]);
    float o1 = 1.f - o0;
    bwarp16(xs0, fl, p, i, j, bw0);
    bwarp16(xs1, fl + (size_t)2 * HWO, p, i, j, bw1);
    float c0 = (1.f - t) * o0, c1 = t * o1;
    float r = wmv / (c0 + c1);
#pragma unroll
    for (int c = 0; c < 16; ++c) A[c] = (c0 * bw0[c] + c1 * bw1[c]) * r;
  }
  {
    float t = t2[np];
    float o0 = sigmoidf_(occr[np]);
    float o1 = 1.f - o0;
    bwarp16(xs1, fr, p, i, j, bw0);
    bwarp16(xs2, fr + (size_t)2 * HWO, p, i, j, bw1);
    float c0 = (1.f - t) * o0, c1 = t * o1;
    float r = (1.f - wmv) / (c0 + c1);
#pragma unroll
    for (int c = 0; c < 16; ++c) B[c] = (c0 * bw0[c] + c1 * bw1[c]) * r;
  }
  float* ob = out + (size_t)n * 16 * HWO + p;
#pragma unroll
  for (int co = 0; co < 16; ++co) {
    float s = sb[co];
    const float* wp = sw + co * 32;
#pragma unroll
    for (int ci = 0; ci < 16; ++ci) s += wp[ci] * A[ci];
#pragma unroll
    for (int ci = 0; ci < 16; ++ci) s += wp[16 + ci] * B[ci];
    ob[(size_t)co * HWO] = s >= 0.f ? s : sa[co] * s;
  }
}

extern "C" void kernel_launch(void* const* d_in, const int* in_sizes, int n_in,
                              void* d_out, int out_size, void* d_ws, size_t ws_size,
                              hipStream_t stream) {
  const float* x0 = (const float*)d_in[0];
  const float* x1 = (const float*)d_in[1];
  const float* x2 = (const float*)d_in[2];
  const float* flw[4] = {(const float*)d_in[3], (const float*)d_in[4],
                         (const float*)d_in[5], (const float*)d_in[6]};
  const float* enc  = (const float*)d_in[7];
  const float* c_w1 = (const float*)d_in[8];
  const float* c_b1 = (const float*)d_in[9];
  const float* c_a1 = (const float*)d_in[10];
  const float* c_w2 = (const float*)d_in[11];
  const float* c_b2 = (const float*)d_in[12];
  const float* c_a2 = (const float*)d_in[13];
  const float* m_w1 = (const float*)d_in[14];
  const float* m_b1 = (const float*)d_in[15];
  const float* m_a1 = (const float*)d_in[16];
  const float* m_w2 = (const float*)d_in[17];
  const float* m_b2 = (const float*)d_in[18];
  const float* m_a2 = (const float*)d_in[19];
  const float* m_w3 = (const float*)d_in[20];
  const float* m_b3 = (const float*)d_in[21];
  const float* f_w  = (const float*)d_in[22];
  const float* f_b  = (const float*)d_in[23];
  const float* f_a  = (const float*)d_in[24];
  float* out = (float*)d_out;

  const size_t u = (size_t)NB * HWO;  // 229376 floats
  float* base = (float*)d_ws;
  size_t off = 0;
  auto alloc = [&](size_t nfl) { float* pp = base + off; off += nfl; return pp; };
  float* t1  = alloc(u);
  float* t2  = alloc(u);
  float* wmb = alloc(u);
  float* xs   = alloc(48 * u);  // [NB][48][HWO] convds output (n-major)
  float* xsc1 = alloc(48 * u);  // convds1 scratch; later mn1 (32u) + mn2 (16u)
  float* splat = alloc(12 * u); // [2 sides][imgwA 2u | imgwB 2u | nA u | nB u]
  float* ftL = alloc(4 * u);    // [NB][4][HWO] = ft0l, ft1l
  float* ftR = alloc(4 * u);    // [NB][4][HWO] = ft1r, ft2r
  float* occl = alloc(u);
  float* occr = alloc(u);
  __bf16* wB1h = (__bf16*)alloc(16384);  // mask1: KTOT=1024, CO=32 -> 32768 bf16
  __bf16* wB1l = (__bf16*)alloc(16384);
  __bf16* wB2h = (__bf16*)alloc(2304);   // mask2: KTOT=288, CO=16 -> 4608 bf16
  __bf16* wB2l = (__bf16*)alloc(2304);
  __bf16* wBch = (__bf16*)alloc(1280);   // convds2: KTOT=160, CO=16 -> 2560 bf16
  __bf16* wBcl = (__bf16*)alloc(1280);
  float* mn1 = xsc1;                  // [NB][32][HWO] = 32u
  float* mn2 = xsc1 + 32 * u;         // [NB][16][HWO] = 16u

  const int TPB = 256;
  auto NBLK = [](long long t) { return (unsigned)((t + 255) / 256); };

  // weight prep (tiny): split-bf16 + MFMA B-fragment swizzle
  prep_w_kernel<<<NBLK(1024 * 32), TPB, 0, stream>>>(m_w1, wB1h, wB1l, 32, 36, 40, 5, 1024);
  prep_w_kernel<<<NBLK(288 * 16), TPB, 0, stream>>>(m_w2, wB2h, wB2l, 16, 32, 32, 3, 288);
  prep_w_kernel<<<NBLK(160 * 16), TPB, 0, stream>>>(c_w2, wBch, wBcl, 16, 16, 16, 3, 160);

  ds_enc_kernel<<<NBLK((long long)NB * 3 * HWO), TPB, 0, stream>>>(enc, t1, t2, wmb);

  convds1_kernel<<<NBLK((long long)3 * NB * HWO), TPB, 0, stream>>>(x0, x1, x2, c_w1, c_b1, c_a1, xsc1);
  // convds2: 16->16 3x3 over 6 batches -> xs [NB][48][HWO]
  conv_mfma_kernel<16, 0, 16, 3, 16, 5, true><<<6 * 32 * 28, TPB, 0, stream>>>(
      xsc1, 16L * HWO, nullptr, 0, wBch, wBcl, c_b2, c_a2, xs, 16L * HWO);

  // flow splat path: LDS-tiled splat (2 sides x 2 flows x NB x 112 tiles)
  hipMemsetAsync(splat, 0, 12 * u * sizeof(float), stream);
  fwarp_tile_kernel<<<2 * 2 * NB * FNTY * FNTX, TPB, 0, stream>>>(
      flw[0], flw[1], flw[2], flw[3], t1, t2, splat);
  cfr_all_kernel<<<NBLK((long long)2 * NB * HWO), TPB, 0, stream>>>(splat, t1, t2, ftL, ftR);

  // masknet left: input = xs[n][0:32] ++ ftL[n][0:4]   (SB=2 -> 48.8KB LDS -> 3 blocks/CU)
  conv_mfma_kernel<32, 4, 40, 5, 32, 2, true><<<NB * 32 * 28, TPB, 0, stream>>>(
      xs, 48L * HWO, ftL, 4L * HWO, wB1h, wB1l, m_b1, m_a1, mn1, 32L * HWO);
  conv_mfma_kernel<32, 0, 32, 3, 16, 3, true><<<NB * 32 * 28, TPB, 0, stream>>>(
      mn1, 32L * HWO, nullptr, 0, wB2h, wB2l, m_b2, m_a2, mn2, 16L * HWO);
  conv3x3_kernel<16, 1, false><<<NBLK((long long)NB * HWO), TPB, 0, stream>>>(mn2, m_w3, m_b3, m_b3, occl, NB);
  // masknet right: input = xs[n][16:48] ++ ftR[n][0:4]
  conv_mfma_kernel<32, 4, 40, 5, 32, 2, true><<<NB * 32 * 28, TPB, 0, stream>>>(
      xs + (size_t)16 * HWO, 48L * HWO, ftR, 4L * HWO, wB1h, wB1l, m_b1, m_a1, mn1, 32L * HWO);
  conv_mfma_kernel<32, 0, 32, 3, 16, 3, true><<<NB * 32 * 28, TPB, 0, stream>>>(
      mn1, 32L * HWO, nullptr, 0, wB2h, wB2l, m_b2, m_a2, mn2, 16L * HWO);
  conv3x3_kernel<16, 1, false><<<NBLK((long long)NB * HWO), TPB, 0, stream>>>(mn2, m_w3, m_b3, m_b3, occr, NB);

  // blend + fused final 1x1 -> d_out
  blend_out_kernel<<<NBLK((long long)NB * HWO), TPB, 0, stream>>>(
      xs, ftL, ftR, occl, occr, t1, t2, wmb, f_w, f_b, f_a, out);
}

// Round 9
// 562.260 us; speedup vs baseline: 2.8940x; 1.0772x over previous
//
#include <hip/hip_runtime.h>
#include <math.h>

#define DEV __device__ __forceinline__

constexpr int NB = 2;
constexpr int HI = 512, WI = 896;
constexpr int HO = 256, WO = 448;
constexpr int HWO = HO * WO;   // 114688
constexpr int HWI = HI * WI;   // 458752

typedef __bf16 bf16x8 __attribute__((ext_vector_type(8)));
typedef float f32x4 __attribute__((ext_vector_type(4)));

// ---------------- downsample (jax.image.resize bilinear, antialias=True, scale 1/2) ----------
DEV float ds_half(const float* __restrict__ p, int i, int j) {
  const float w4[4] = {1.f, 3.f, 3.f, 1.f};
  float wc[4]; int cc[4];
  float cs = 0.f;
#pragma unroll
  for (int k = 0; k < 4; ++k) {
    int c = 2 * j - 1 + k;
    bool v = (c >= 0) && (c < WI);
    wc[k] = v ? w4[k] : 0.f;
    cc[k] = v ? c : 0;
    cs += wc[k];
  }
  float acc = 0.f, rs = 0.f;
#pragma unroll
  for (int k = 0; k < 4; ++k) {
    int r = 2 * i - 1 + k;
    if (r < 0 || r >= HI) continue;
    const float* row = p + (size_t)r * WI;
    float racc = 0.f;
#pragma unroll
    for (int b = 0; b < 4; ++b) racc += wc[b] * row[cc[b]];
    acc += w4[k] * racc;
    rs += w4[k];
  }
  return acc / (rs * cs);
}

__global__ void ds_enc_kernel(const float* __restrict__ enc, float* __restrict__ t1,
                              float* __restrict__ t2, float* __restrict__ wm) {
  int gid = blockIdx.x * blockDim.x + threadIdx.x;
  int total = NB * 3 * HWO;
  if (gid >= total) return;
  int p = gid % HWO;
  int nc = gid / HWO;
  int c = nc % 3, n = nc / 3;
  int i = p / WO, j = p % WO;
  float v = ds_half(enc + (size_t)(n * 3 + c) * HWI, i, j);
  float* dst = (c == 0) ? t1 : (c == 1 ? t2 : wm);
  dst[(size_t)n * HWO + p] = v;
}

// ---------------- weight prep: [CO][CIr][KS*KS] fp32 -> B-fragment-swizzled bf16 hi/lo ----------
__global__ void prep_w_kernel(const float* __restrict__ w, __bf16* __restrict__ bh,
                              __bf16* __restrict__ bl, int CO, int CIr, int CIP, int KS,
                              int KTOT) {
  int idx = blockIdx.x * blockDim.x + threadIdx.x;
  int total = KTOT * CO;
  if (idx >= total) return;
  int NT = CO / 16;
  int j = idx & 7;
  int l = (idx >> 3) & 63;
  int rest = idx >> 9;
  int s = rest / NT, nt = rest % NT;
  int k = s * 32 + ((l >> 4) & 3) * 8 + j;
  int n = nt * 16 + (l & 15);
  int kpos = k / CIP, ci = k % CIP;
  float v = (kpos < KS * KS && ci < CIr) ? w[((size_t)n * CIr + ci) * KS * KS + kpos] : 0.f;
  __bf16 h = (__bf16)v;
  bh[idx] = h;
  bl[idx] = (__bf16)(v - (float)h);
}

// ---------------- convds first conv: 3x3 stride2 pad1, 3->16, prelu ----------
__global__ void __launch_bounds__(256, 2)
convds1_kernel(const float* __restrict__ x0, const float* __restrict__ x1,
               const float* __restrict__ x2, const float* __restrict__ w,
               const float* __restrict__ bias, const float* __restrict__ alpha,
               float* __restrict__ out) {
  __shared__ float sw[16 * 3 * 9];
  __shared__ float sb[16];
  __shared__ float sa[16];
  for (int idx = threadIdx.x; idx < 432; idx += blockDim.x) sw[idx] = w[idx];
  if (threadIdx.x < 16) { sb[threadIdx.x] = bias[threadIdx.x]; sa[threadIdx.x] = alpha[threadIdx.x]; }
  __syncthreads();
  int gid = blockIdx.x * blockDim.x + threadIdx.x;
  int total = 3 * NB * HWO;
  if (gid >= total) return;
  int p = gid % HWO;
  int ni = gid / HWO;            // n*3+img
  int n = ni / 3, img = ni % 3;
  int i = p / WO, j = p % WO;
  const float* x = (img == 0 ? x0 : (img == 1 ? x1 : x2)) + (size_t)n * 3 * HWI;
  float in[27];
  int q = 0;
#pragma unroll
  for (int ci = 0; ci < 3; ++ci)
#pragma unroll
    for (int ky = 0; ky < 3; ++ky) {
      int r = 2 * i + ky - 1;
#pragma unroll
      for (int kx = 0; kx < 3; ++kx) {
        int c = 2 * j + kx - 1;
        in[q++] = (r >= 0 && r < HI && c >= 0 && c < WI) ? x[((size_t)ci * HI + r) * WI + c] : 0.f;
      }
    }
  float* o = out + (size_t)ni * 16 * HWO + p;
#pragma unroll
  for (int co = 0; co < 16; ++co) {
    float acc = sb[co];
    const float* wp = sw + co * 27;
#pragma unroll
    for (int k = 0; k < 27; ++k) acc += wp[k] * in[k];
    o[(size_t)co * HWO] = acc >= 0.f ? acc : sa[co] * acc;
  }
}

// ---------------- implicit-GEMM conv via MFMA ----------
// AL=true : split-bf16 A (hi+lo), 3 MFMAs -> fp32-grade accuracy.
// AL=false: A truncated to bf16-hi only, 2 MFMAs (AhBh+AhBl) -> halves A LDS.
//   Error = Al*B ~ 1e-3 worst-case; used ONLY for mask1 whose output is sigmoid-squashed.
//   Round-8 evidence: mask1's 38.4KB A-tile capped occupancy at 3 blocks/CU (27%),
//   both pipes <30% busy; AL=false gives 35.6KB total -> 4 blocks/CU.
template <int CIr1, int CIr2, int CIP, int KS, int CO, int SB, bool AL, bool PRELU>
__global__ void __launch_bounds__(256, 2)
conv_mfma_kernel(const float* __restrict__ in1, long s1,
                 const float* __restrict__ in2, long s2,
                 const __bf16* __restrict__ wBh, const __bf16* __restrict__ wBl,
                 const float* __restrict__ bias, const float* __restrict__ alpha,
                 float* __restrict__ out, long so) {
  constexpr int TR = 8;
  constexpr int TRH = TR + KS - 1;
  constexpr int TCH = 16 + KS - 1;
  constexpr int NPX = TRH * TCH;
  constexpr int NT = CO / 16;
  constexpr int KREAL = KS * KS * CIP;
  constexpr int KTOT = ((KREAL + 31) / 32) * 32;
  constexpr int NSLICE = KTOT / 32;
  constexpr int RCHUNK = KREAL / 8;
  constexpr int PAD = KS / 2;
  constexpr int CPC = CIP / 8;
  constexpr int NTY = HO / TR;
  constexpr int NTX = WO / 16;

  __shared__ __align__(16) __bf16 Ah[NPX * CIP];
  __shared__ __align__(16) __bf16 Al[AL ? NPX * CIP : 8];
  __shared__ __align__(16) __bf16 Bh[SB * NT * 512];
  __shared__ __align__(16) __bf16 Bl[SB * NT * 512];

  int tid = threadIdx.x;
  int bx = blockIdx.x;
  int b = bx / (NTY * NTX);
  int rem = bx % (NTY * NTX);
  int row0 = (rem / NTX) * TR;
  int col0 = (rem % NTX) * 16;

  for (int e = tid; e < NPX * CIP; e += 256) {
    int ci = e / NPX;
    int pxi = e % NPX;
    int y = pxi / TCH, x = pxi % TCH;
    int gy = row0 + y - PAD, gx = col0 + x - PAD;
    float v = 0.f;
    if (ci < CIr1 + CIr2 && gy >= 0 && gy < HO && gx >= 0 && gx < WO) {
      v = (ci < CIr1) ? in1[(size_t)b * s1 + (size_t)ci * HWO + gy * WO + gx]
                      : in2[(size_t)b * s2 + (size_t)(ci - CIr1) * HWO + gy * WO + gx];
    }
    __bf16 h = (__bf16)v;
    Ah[pxi * CIP + ci] = h;
    if (AL) Al[pxi * CIP + ci] = (__bf16)(v - (float)h);
  }

  int lane = tid & 63, wid = tid >> 6;

  f32x4 acc[2][NT];
  float aco[NT];
#pragma unroll
  for (int nt = 0; nt < NT; ++nt) {
    float bv = bias[nt * 16 + (lane & 15)];
    aco[nt] = PRELU ? alpha[nt * 16 + (lane & 15)] : 0.f;
    f32x4 z = {bv, bv, bv, bv};
    acc[0][nt] = z;
    acc[1][nt] = z;
  }

  const uint4* gBh = reinterpret_cast<const uint4*>(wBh);
  const uint4* gBl = reinterpret_cast<const uint4*>(wBl);
  uint4* lBh = reinterpret_cast<uint4*>(Bh);
  uint4* lBl = reinterpret_cast<uint4*>(Bl);

  for (int s0 = 0; s0 < NSLICE; s0 += SB) {
    if (s0 > 0) __syncthreads();
    constexpr int NU = SB * NT * 64;
    for (int u = tid; u < NU; u += 256) {
      lBh[u] = gBh[(size_t)s0 * NT * 64 + u];
      lBl[u] = gBl[(size_t)s0 * NT * 64 + u];
    }
    __syncthreads();
#pragma unroll
    for (int s = 0; s < SB; ++s) {
      int slice = s0 + s;
      bf16x8 bh[NT], bl[NT];
#pragma unroll
      for (int nt = 0; nt < NT; ++nt) {
        bh[nt] = __builtin_bit_cast(bf16x8, lBh[(s * NT + nt) * 64 + lane]);
        bl[nt] = __builtin_bit_cast(bf16x8, lBl[(s * NT + nt) * 64 + lane]);
      }
      int g = slice * 4 + (lane >> 4);
      if (g > RCHUNK - 1) g = RCHUNK - 1;
      int kpos = g / CPC;
      int ci0 = (g % CPC) * 8;
      int ky = kpos / KS, kx = kpos % KS;
      int xoff = ((lane & 15) + kx) * CIP + ci0;
#pragma unroll
      for (int mt = 0; mt < 2; ++mt) {
        int r = wid * 2 + mt;
        int addr = (r + ky) * TCH * CIP + xoff;
        bf16x8 ah = __builtin_bit_cast(bf16x8, *reinterpret_cast<const uint4*>(Ah + addr));
#pragma unroll
        for (int nt = 0; nt < NT; ++nt) {
          acc[mt][nt] = __builtin_amdgcn_mfma_f32_16x16x32_bf16(ah, bh[nt], acc[mt][nt], 0, 0, 0);
          acc[mt][nt] = __builtin_amdgcn_mfma_f32_16x16x32_bf16(ah, bl[nt], acc[mt][nt], 0, 0, 0);
        }
        if (AL) {
          bf16x8 al = __builtin_bit_cast(bf16x8, *reinterpret_cast<const uint4*>(Al + addr));
#pragma unroll
          for (int nt = 0; nt < NT; ++nt) {
            acc[mt][nt] = __builtin_amdgcn_mfma_f32_16x16x32_bf16(al, bh[nt], acc[mt][nt], 0, 0, 0);
          }
        }
      }
    }
  }

#pragma unroll
  for (int mt = 0; mt < 2; ++mt) {
    int gr = row0 + wid * 2 + mt;
#pragma unroll
    for (int nt = 0; nt < NT; ++nt) {
      int co = nt * 16 + (lane & 15);
      float* op = out + (size_t)b * so + (size_t)co * HWO + (size_t)gr * WO + col0 + (lane >> 4) * 4;
#pragma unroll
      for (int reg = 0; reg < 4; ++reg) {
        float v = acc[mt][nt][reg];
        if (PRELU) v = v >= 0.f ? v : aco[nt] * v;
        op[reg] = v;
      }
    }
  }
}

// ---------------- small generic 3x3 conv (kept for 16->1) ----------
template <int CI, int CO, bool PRELU>
__global__ void __launch_bounds__(256, 2)
conv3x3_kernel(const float* __restrict__ in, const float* __restrict__ w,
               const float* __restrict__ bias, const float* __restrict__ alpha,
               float* __restrict__ out, int B) {
  __shared__ float sw[CO * CI * 9];
  __shared__ float sb[CO];
  __shared__ float sa[CO];
  for (int idx = threadIdx.x; idx < CO * CI * 9; idx += blockDim.x) sw[idx] = w[idx];
  if (threadIdx.x < CO) {
    sb[threadIdx.x] = bias[threadIdx.x];
    sa[threadIdx.x] = PRELU ? alpha[threadIdx.x] : 0.f;
  }
  __syncthreads();
  int gid = blockIdx.x * blockDim.x + threadIdx.x;
  int total = B * HWO;
  if (gid >= total) return;
  int p = gid % HWO, b = gid / HWO;
  int i = p / WO, j = p % WO;
  const float* xb = in + (size_t)b * CI * HWO;
  float acc[CO];
#pragma unroll
  for (int co = 0; co < CO; ++co) acc[co] = sb[co];
  for (int ci = 0; ci < CI; ++ci) {
    const float* xc = xb + (size_t)ci * HWO;
    float taps[9];
    int q = 0;
#pragma unroll
    for (int ky = 0; ky < 3; ++ky) {
      int r = i + ky - 1;
#pragma unroll
      for (int kx = 0; kx < 3; ++kx) {
        int c = j + kx - 1;
        taps[q++] = (r >= 0 && r < HO && c >= 0 && c < WO) ? xc[(size_t)r * WO + c] : 0.f;
      }
    }
#pragma unroll
    for (int co = 0; co < CO; ++co) {
      const float* wp = sw + (co * CI + ci) * 9;
      float s = acc[co];
#pragma unroll
      for (int k = 0; k < 9; ++k) s += wp[k] * taps[k];
      acc[co] = s;
    }
  }
  float* ob = out + (size_t)b * CO * HWO + p;
#pragma unroll
  for (int co = 0; co < CO; ++co) {
    float v = acc[co];
    if (PRELU) v = v >= 0.f ? v : sa[co] * v;
    ob[(size_t)co * HWO] = v;
  }
}

// ---------------- forward splat: LDS-tiled ----------
constexpr int FTS = 32;
constexpr int FRH = 8;
constexpr int FTH = FTS + 2 * FRH;   // 48
constexpr int FNTX = WO / FTS;       // 14
constexpr int FNTY = HO / FTS;       // 8

__global__ void __launch_bounds__(256, 2)
fwarp_tile_kernel(const float* __restrict__ flow0, const float* __restrict__ flow1,
                  const float* __restrict__ flow2, const float* __restrict__ flow3,
                  const float* __restrict__ t1, const float* __restrict__ t2,
                  float* __restrict__ S /* 12u splat region, zeroed */) {
  __shared__ float acc[FTH * FTH * 3];
  int tid = threadIdx.x;
  for (int e = tid; e < FTH * FTH * 3; e += 256) acc[e] = 0.f;
  __syncthreads();

  const size_t u = (size_t)NB * HWO;
  int bx = blockIdx.x;
  int tile = bx % (FNTY * FNTX); bx /= (FNTY * FNTX);
  int n = bx % NB; bx /= NB;
  int ab = bx & 1;
  int side = bx >> 1;
  int row0 = (tile / FNTX) * FTS;
  int col0 = (tile % FNTX) * FTS;

  const float* flo = side ? (ab ? flow3 : flow2) : (ab ? flow1 : flow0);
  const float* t = side ? t2 : t1;
  float* basep = S + (size_t)side * 6 * u;
  float* imgw = basep + (size_t)ab * 2 * u;
  float* nw = basep + 4 * u + (size_t)ab * u;
  const float* flo0 = flo + ((size_t)n * 2 + 0) * HWI;
  const float* flo1 = flo + ((size_t)n * 2 + 1) * HWI;
  float* iw0 = imgw + ((size_t)n * 2 + 0) * HWO;
  float* iw1 = imgw + ((size_t)n * 2 + 1) * HWO;
  float* nwp = nw + (size_t)n * HWO;

#pragma unroll
  for (int k = 0; k < FTS * FTS / 256; ++k) {
    int pl = tid + k * 256;
    int ly = pl / FTS, lx = pl % FTS;
    int i = row0 + ly, j = col0 + lx;
    float f0 = 0.5f * ds_half(flo0, i, j);
    float f1 = 0.5f * ds_half(flo1, i, j);
    float tv = t[(size_t)n * HWO + i * WO + j];
    float s = ab ? (1.f - tv) : tv;
    float xr = s * f1;
    float yc = s * f0;
    float x1f = floorf(xr), y1f = floorf(yc);
#pragma unroll
    for (int dx = 0; dx < 2; ++dx)
#pragma unroll
      for (int dy = 0; dy < 2; ++dy) {
        float sx = x1f + (float)dx;
        float sy = y1f + (float)dy;
        float ddx = xr - sx, ddy = yc - sy;
        float wgt = expf(-(ddx * ddx + ddy * ddy));
        int r = (int)sx + i;
        int c = (int)sy + j;
        int lr = r - row0 + FRH, lc = c - col0 + FRH;
        if (lr >= 0 && lr < FTH && lc >= 0 && lc < FTH) {
          int cell = (lr * FTH + lc) * 3;
          atomicAdd(&acc[cell + 0], f0 * wgt);
          atomicAdd(&acc[cell + 1], f1 * wgt);
          atomicAdd(&acc[cell + 2], wgt);
        } else if (r >= 0 && r < HO && c >= 0 && c < WO) {
          size_t o = (size_t)r * WO + c;
          atomicAdd(iw0 + o, f0 * wgt);
          atomicAdd(iw1 + o, f1 * wgt);
          atomicAdd(nwp + o, wgt);
        }
      }
  }
  __syncthreads();
  for (int e = tid; e < FTH * FTH; e += 256) {
    int ly = e / FTH, lx = e % FTH;
    int r = row0 + ly - FRH, c = col0 + lx - FRH;
    if (r < 0 || r >= HO || c < 0 || c >= WO) continue;
    float v2 = acc[e * 3 + 2];
    if (v2 == 0.f) continue;
    size_t o = (size_t)r * WO + c;
    atomicAdd(iw0 + o, acc[e * 3 + 0]);
    atomicAdd(iw1 + o, acc[e * 3 + 1]);
    atomicAdd(nwp + o, v2);
  }
}

// combine -> ftL [NB][4][HWO] = (ft0l ch0,ch1, ft1l ch0,ch1); ftR likewise (ft1r, ft2r)
__global__ void cfr_all_kernel(const float* __restrict__ S,
                               const float* __restrict__ t1, const float* __restrict__ t2,
                               float* __restrict__ ftL, float* __restrict__ ftR) {
  const size_t u = (size_t)NB * HWO;
  int gid = blockIdx.x * blockDim.x + threadIdx.x;
  int total = 2 * NB * HWO;
  if (gid >= total) return;
  int side = gid / (NB * HWO);
  int rem = gid % (NB * HWO);
  int n = rem / HWO, p = rem % HWO;
  const float* base = S + (size_t)side * 6 * u;
  const float* f01w = base;
  const float* f10w = base + 2 * u;
  const float* n0 = base + 4 * u;
  const float* n1 = base + 5 * u;
  const float* t = side ? t2 : t1;
  float* ft = side ? ftR : ftL;
  size_t np = (size_t)n * HWO + p;
  float tv = t[np];
  float norm = (1.f - tv) * n0[np] + tv * n1[np];
  bool pos = norm > 0.f;
#pragma unroll
  for (int ch = 0; ch < 2; ++ch) {
    size_t sidx = ((size_t)n * 2 + ch) * HWO + p;
    float a = f01w[sidx];
    float b = f10w[sidx];
    float v0 = -(1.f - tv) * tv * a + tv * tv * b;
    float v1 = (1.f - tv) * (1.f - tv) * a - tv * (1.f - tv) * b;
    ft[((size_t)n * 4 + ch) * HWO + p]     = pos ? v0 / norm : v0;
    ft[((size_t)n * 4 + 2 + ch) * HWO + p] = pos ? v1 / norm : v1;
  }
}

// ---------------- backward warp + occlusion blend + final 1x1 conv ----------
DEV float sigmoidf_(float x) { return 1.f / (1.f + expf(-x)); }

DEV void bwarp16(const float* __restrict__ x /* [16][HWO] */, const float* __restrict__ flo /* [2][HWO] */,
                 int p, int i, int j, float* o) {
  float fx = flo[p];
  float fy = flo[HWO + p];
  float gx = (float)j + fx, gy = (float)i + fy;
  float nx = 2.f * gx / (float)(WO - 1) - 1.f;
  float ny = 2.f * gy / (float)(HO - 1) - 1.f;
  float px = ((nx + 1.f) * (float)WO - 1.f) * 0.5f;
  float py = ((ny + 1.f) * (float)HO - 1.f) * 0.5f;
  float cx = fminf(fmaxf(px, 0.f), (float)(WO - 1));
  float cy = fminf(fmaxf(py, 0.f), (float)(HO - 1));
  float x0f = floorf(cx), y0f = floorf(cy);
  float wx = cx - x0f, wy = cy - y0f;
  int x0i = (int)x0f; x0i = x0i < 0 ? 0 : (x0i > WO - 1 ? WO - 1 : x0i);
  int y0i = (int)y0f; y0i = y0i < 0 ? 0 : (y0i > HO - 1 ? HO - 1 : y0i);
  int x1i = x0i + 1 > WO - 1 ? WO - 1 : x0i + 1;
  int y1i = y0i + 1 > HO - 1 ? HO - 1 : y0i + 1;
  float fx0 = floorf(px), fy0 = floorf(py);
  float ux = px - fx0, uy = py - fy0;
  float WOf = (float)WO, HOf = (float)HO;
  float i00 = (fx0 >= 0.f && fx0 < WOf && fy0 >= 0.f && fy0 < HOf) ? 1.f : 0.f;
  float i10 = (fx0 + 1.f >= 0.f && fx0 + 1.f < WOf && fy0 >= 0.f && fy0 < HOf) ? 1.f : 0.f;
  float i01 = (fx0 >= 0.f && fx0 < WOf && fy0 + 1.f >= 0.f && fy0 + 1.f < HOf) ? 1.f : 0.f;
  float i11 = (fx0 + 1.f >= 0.f && fx0 + 1.f < WOf && fy0 + 1.f >= 0.f && fy0 + 1.f < HOf) ? 1.f : 0.f;
  float mv = (1.f - ux) * (1.f - uy) * i00 + ux * (1.f - uy) * i10
           + (1.f - ux) * uy * i01 + ux * uy * i11;
  float mask = mv >= 0.999f ? 1.f : 0.f;
  float w00 = (1.f - wx) * (1.f - wy), w10 = wx * (1.f - wy);
  float w01 = (1.f - wx) * wy, w11 = wx * wy;
  int a00 = y0i * WO + x0i, a10 = y0i * WO + x1i;
  int a01 = y1i * WO + x0i, a11 = y1i * WO + x1i;
#pragma unroll
  for (int c = 0; c < 16; ++c) {
    const float* xc = x + (size_t)c * HWO;
    o[c] = (w00 * xc[a00] + w10 * xc[a10] + w01 * xc[a01] + w11 * xc[a11]) * mask;
  }
}

__global__ void __launch_bounds__(256, 2)
blend_out_kernel(const float* __restrict__ xs /* [NB][48][HWO] */,
                 const float* __restrict__ ftL, const float* __restrict__ ftR,
                 const float* __restrict__ occl, const float* __restrict__ occr,
                 const float* __restrict__ t1, const float* __restrict__ t2,
                 const float* __restrict__ wm,
                 const float* __restrict__ fw, const float* __restrict__ fb,
                 const float* __restrict__ fa,
                 float* __restrict__ out /* [NB][16][HWO] */) {
  __shared__ float sw[512];
  __shared__ float sb[16];
  __shared__ float sa[16];
  for (int idx = threadIdx.x; idx < 512; idx += blockDim.x) sw[idx] = fw[idx];
  if (threadIdx.x < 16) { sb[threadIdx.x] = fb[threadIdx.x]; sa[threadIdx.x] = fa[threadIdx.x]; }
  __syncthreads();
  int gid = blockIdx.x * blockDim.x + threadIdx.x;
  int total = NB * HWO;
  if (gid >= total) return;
  int p = gid % HWO, n = gid / HWO;
  int i = p / WO, j = p % WO;
  size_t np = (size_t)n * HWO + p;
  float wmv = wm[np];
  const float* xs0 = xs + (size_t)n * 48 * HWO;
  const float* xs1 = xs0 + (size_t)16 * HWO;
  const float* xs2 = xs0 + (size_t)32 * HWO;
  const float* fl = ftL + (size_t)n * 4 * HWO;
  const float* fr = ftR + (size_t)n * 4 * HWO;
  float A[16], B[16];
  float bw0[16], bw1[16];
  {
    float t = t1[np];
    float o0 = sigmoidf_(occl[np]);
    float o1 = 1.f - o0;
    bwarp16(xs0, fl, p, i, j, bw0);
    bwarp16(xs1, fl + (size_t)2 * HWO, p, i, j, bw1);
    float c0 = (1.f - t) * o0, c1 = t * o1;
    float r = wmv / (c0 + c1);
#pragma unroll
    for (int c = 0; c < 16; ++c) A[c] = (c0 * bw0[c] + c1 * bw1[c]) * r;
  }
  {
    float t = t2[np];
    float o0 = sigmoidf_(occr[np]);
    float o1 = 1.f - o0;
    bwarp16(xs1, fr, p, i, j, bw0);
    bwarp16(xs2, fr + (size_t)2 * HWO, p, i, j, bw1);
    float c0 = (1.f - t) * o0, c1 = t * o1;
    float r = (1.f - wmv) / (c0 + c1);
#pragma unroll
    for (int c = 0; c < 16; ++c) B[c] = (c0 * bw0[c] + c1 * bw1[c]) * r;
  }
  float* ob = out + (size_t)n * 16 * HWO + p;
#pragma unroll
  for (int co = 0; co < 16; ++co) {
    float s = sb[co];
    const float* wp = sw + co * 32;
#pragma unroll
    for (int ci = 0; ci < 16; ++ci) s += wp[ci] * A[ci];
#pragma unroll
    for (int ci = 0; ci < 16; ++ci) s += wp[16 + ci] * B[ci];
    ob[(size_t)co * HWO] = s >= 0.f ? s : sa[co] * s;
  }
}

extern "C" void kernel_launch(void* const* d_in, const int* in_sizes, int n_in,
                              void* d_out, int out_size, void* d_ws, size_t ws_size,
                              hipStream_t stream) {
  const float* x0 = (const float*)d_in[0];
  const float* x1 = (const float*)d_in[1];
  const float* x2 = (const float*)d_in[2];
  const float* flw[4] = {(const float*)d_in[3], (const float*)d_in[4],
                         (const float*)d_in[5], (const float*)d_in[6]};
  const float* enc  = (const float*)d_in[7];
  const float* c_w1 = (const float*)d_in[8];
  const float* c_b1 = (const float*)d_in[9];
  const float* c_a1 = (const float*)d_in[10];
  const float* c_w2 = (const float*)d_in[11];
  const float* c_b2 = (const float*)d_in[12];
  const float* c_a2 = (const float*)d_in[13];
  const float* m_w1 = (const float*)d_in[14];
  const float* m_b1 = (const float*)d_in[15];
  const float* m_a1 = (const float*)d_in[16];
  const float* m_w2 = (const float*)d_in[17];
  const float* m_b2 = (const float*)d_in[18];
  const float* m_a2 = (const float*)d_in[19];
  const float* m_w3 = (const float*)d_in[20];
  const float* m_b3 = (const float*)d_in[21];
  const float* f_w  = (const float*)d_in[22];
  const float* f_b  = (const float*)d_in[23];
  const float* f_a  = (const float*)d_in[24];
  float* out = (float*)d_out;

  const size_t u = (size_t)NB * HWO;  // 229376 floats
  float* base = (float*)d_ws;
  size_t off = 0;
  auto alloc = [&](size_t nfl) { float* pp = base + off; off += nfl; return pp; };
  float* t1  = alloc(u);
  float* t2  = alloc(u);
  float* wmb = alloc(u);
  float* xs   = alloc(48 * u);  // [NB][48][HWO] convds output (n-major)
  float* xsc1 = alloc(48 * u);  // convds1 scratch; later mn1 (32u) + mn2 (16u)
  float* splat = alloc(12 * u); // [2 sides][imgwA 2u | imgwB 2u | nA u | nB u]
  float* ftL = alloc(4 * u);    // [NB][4][HWO] = ft0l, ft1l
  float* ftR = alloc(4 * u);    // [NB][4][HWO] = ft1r, ft2r
  float* occl = alloc(u);
  float* occr = alloc(u);
  __bf16* wB1h = (__bf16*)alloc(16384);  // mask1: KTOT=1024, CO=32 -> 32768 bf16
  __bf16* wB1l = (__bf16*)alloc(16384);
  __bf16* wB2h = (__bf16*)alloc(2304);   // mask2: KTOT=288, CO=16 -> 4608 bf16
  __bf16* wB2l = (__bf16*)alloc(2304);
  __bf16* wBch = (__bf16*)alloc(1280);   // convds2: KTOT=160, CO=16 -> 2560 bf16
  __bf16* wBcl = (__bf16*)alloc(1280);
  float* mn1 = xsc1;                  // [NB][32][HWO] = 32u
  float* mn2 = xsc1 + 32 * u;         // [NB][16][HWO] = 16u

  const int TPB = 256;
  auto NBLK = [](long long t) { return (unsigned)((t + 255) / 256); };

  // weight prep (tiny): split-bf16 + MFMA B-fragment swizzle
  prep_w_kernel<<<NBLK(1024 * 32), TPB, 0, stream>>>(m_w1, wB1h, wB1l, 32, 36, 40, 5, 1024);
  prep_w_kernel<<<NBLK(288 * 16), TPB, 0, stream>>>(m_w2, wB2h, wB2l, 16, 32, 32, 3, 288);
  prep_w_kernel<<<NBLK(160 * 16), TPB, 0, stream>>>(c_w2, wBch, wBcl, 16, 16, 16, 3, 160);

  ds_enc_kernel<<<NBLK((long long)NB * 3 * HWO), TPB, 0, stream>>>(enc, t1, t2, wmb);

  convds1_kernel<<<NBLK((long long)3 * NB * HWO), TPB, 0, stream>>>(x0, x1, x2, c_w1, c_b1, c_a1, xsc1);
  // convds2: 16->16 3x3 over 6 batches -> xs [NB][48][HWO]  (AL=true: full accuracy, LDS small)
  conv_mfma_kernel<16, 0, 16, 3, 16, 5, true, true><<<6 * 32 * 28, TPB, 0, stream>>>(
      xsc1, 16L * HWO, nullptr, 0, wBch, wBcl, c_b2, c_a2, xs, 16L * HWO);

  // flow splat path: LDS-tiled splat (2 sides x 2 flows x NB x 112 tiles)
  hipMemsetAsync(splat, 0, 12 * u * sizeof(float), stream);
  fwarp_tile_kernel<<<2 * 2 * NB * FNTY * FNTX, TPB, 0, stream>>>(
      flw[0], flw[1], flw[2], flw[3], t1, t2, splat);
  cfr_all_kernel<<<NBLK((long long)2 * NB * HWO), TPB, 0, stream>>>(splat, t1, t2, ftL, ftR);

  // masknet left: input = xs[n][0:32] ++ ftL[n][0:4]
  // mask1: AL=false (2-MFMA, A-hi only) -> 35.6KB LDS -> 4 blocks/CU; SB=4 -> 8 stages
  conv_mfma_kernel<32, 4, 40, 5, 32, 4, false, true><<<NB * 32 * 28, TPB, 0, stream>>>(
      xs, 48L * HWO, ftL, 4L * HWO, wB1h, wB1l, m_b1, m_a1, mn1, 32L * HWO);
  conv_mfma_kernel<32, 0, 32, 3, 16, 3, true, true><<<NB * 32 * 28, TPB, 0, stream>>>(
      mn1, 32L * HWO, nullptr, 0, wB2h, wB2l, m_b2, m_a2, mn2, 16L * HWO);
  conv3x3_kernel<16, 1, false><<<NBLK((long long)NB * HWO), TPB, 0, stream>>>(mn2, m_w3, m_b3, m_b3, occl, NB);
  // masknet right: input = xs[n][16:48] ++ ftR[n][0:4]
  conv_mfma_kernel<32, 4, 40, 5, 32, 4, false, true><<<NB * 32 * 28, TPB, 0, stream>>>(
      xs + (size_t)16 * HWO, 48L * HWO, ftR, 4L * HWO, wB1h, wB1l, m_b1, m_a1, mn1, 32L * HWO);
  conv_mfma_kernel<32, 0, 32, 3, 16, 3, true, true><<<NB * 32 * 28, TPB, 0, stream>>>(
      mn1, 32L * HWO, nullptr, 0, wB2h, wB2l, m_b2, m_a2, mn2, 16L * HWO);
  conv3x3_kernel<16, 1, false><<<NBLK((long long)NB * HWO), TPB, 0, stream>>>(mn2, m_w3, m_b3, m_b3, occr, NB);

  // blend + fused final 1x1 -> d_out
  blend_out_kernel<<<NBLK((long long)NB * HWO), TPB, 0, stream>>>(
      xs, ftL, ftR, occl, occr, t1, t2, wmb, f_w, f_b, f_a, out);
}

// Round 10
// 558.062 us; speedup vs baseline: 2.9157x; 1.0075x over previous
//
#include <hip/hip_runtime.h>
#include <math.h>

#define DEV __device__ __forceinline__

constexpr int NB = 2;
constexpr int HI = 512, WI = 896;
constexpr int HO = 256, WO = 448;
constexpr int HWO = HO * WO;   // 114688
constexpr int HWI = HI * WI;   // 458752

typedef __bf16 bf16x8 __attribute__((ext_vector_type(8)));
typedef float f32x4 __attribute__((ext_vector_type(4)));

// ---------------- downsample (jax.image.resize bilinear, antialias=True, scale 1/2) ----------
DEV float ds_half(const float* __restrict__ p, int i, int j) {
  const float w4[4] = {1.f, 3.f, 3.f, 1.f};
  float wc[4]; int cc[4];
  float cs = 0.f;
#pragma unroll
  for (int k = 0; k < 4; ++k) {
    int c = 2 * j - 1 + k;
    bool v = (c >= 0) && (c < WI);
    wc[k] = v ? w4[k] : 0.f;
    cc[k] = v ? c : 0;
    cs += wc[k];
  }
  float acc = 0.f, rs = 0.f;
#pragma unroll
  for (int k = 0; k < 4; ++k) {
    int r = 2 * i - 1 + k;
    if (r < 0 || r >= HI) continue;
    const float* row = p + (size_t)r * WI;
    float racc = 0.f;
#pragma unroll
    for (int b = 0; b < 4; ++b) racc += wc[b] * row[cc[b]];
    acc += w4[k] * racc;
    rs += w4[k];
  }
  return acc / (rs * cs);
}

__global__ void ds_enc_kernel(const float* __restrict__ enc, float* __restrict__ t1,
                              float* __restrict__ t2, float* __restrict__ wm) {
  int gid = blockIdx.x * blockDim.x + threadIdx.x;
  int total = NB * 3 * HWO;
  if (gid >= total) return;
  int p = gid % HWO;
  int nc = gid / HWO;
  int c = nc % 3, n = nc / 3;
  int i = p / WO, j = p % WO;
  float v = ds_half(enc + (size_t)(n * 3 + c) * HWI, i, j);
  float* dst = (c == 0) ? t1 : (c == 1 ? t2 : wm);
  dst[(size_t)n * HWO + p] = v;
}

// ---------------- weight prep: [CO][CIr][KS*KS] fp32 -> B-fragment-swizzled bf16 hi/lo ----------
__global__ void prep_w_kernel(const float* __restrict__ w, __bf16* __restrict__ bh,
                              __bf16* __restrict__ bl, int CO, int CIr, int CIP, int KS,
                              int KTOT) {
  int idx = blockIdx.x * blockDim.x + threadIdx.x;
  int total = KTOT * CO;
  if (idx >= total) return;
  int NT = CO / 16;
  int j = idx & 7;
  int l = (idx >> 3) & 63;
  int rest = idx >> 9;
  int s = rest / NT, nt = rest % NT;
  int k = s * 32 + ((l >> 4) & 3) * 8 + j;
  int n = nt * 16 + (l & 15);
  int kpos = k / CIP, ci = k % CIP;
  float v = (kpos < KS * KS && ci < CIr) ? w[((size_t)n * CIr + ci) * KS * KS + kpos] : 0.f;
  __bf16 h = (__bf16)v;
  bh[idx] = h;
  bl[idx] = (__bf16)(v - (float)h);
}

// ---------------- convds first conv: 3x3 stride2 pad1, 3->16, prelu ----------
__global__ void __launch_bounds__(256, 2)
convds1_kernel(const float* __restrict__ x0, const float* __restrict__ x1,
               const float* __restrict__ x2, const float* __restrict__ w,
               const float* __restrict__ bias, const float* __restrict__ alpha,
               float* __restrict__ out) {
  __shared__ float sw[16 * 3 * 9];
  __shared__ float sb[16];
  __shared__ float sa[16];
  for (int idx = threadIdx.x; idx < 432; idx += blockDim.x) sw[idx] = w[idx];
  if (threadIdx.x < 16) { sb[threadIdx.x] = bias[threadIdx.x]; sa[threadIdx.x] = alpha[threadIdx.x]; }
  __syncthreads();
  int gid = blockIdx.x * blockDim.x + threadIdx.x;
  int total = 3 * NB * HWO;
  if (gid >= total) return;
  int p = gid % HWO;
  int ni = gid / HWO;            // n*3+img
  int n = ni / 3, img = ni % 3;
  int i = p / WO, j = p % WO;
  const float* x = (img == 0 ? x0 : (img == 1 ? x1 : x2)) + (size_t)n * 3 * HWI;
  float in[27];
  int q = 0;
#pragma unroll
  for (int ci = 0; ci < 3; ++ci)
#pragma unroll
    for (int ky = 0; ky < 3; ++ky) {
      int r = 2 * i + ky - 1;
#pragma unroll
      for (int kx = 0; kx < 3; ++kx) {
        int c = 2 * j + kx - 1;
        in[q++] = (r >= 0 && r < HI && c >= 0 && c < WI) ? x[((size_t)ci * HI + r) * WI + c] : 0.f;
      }
    }
  float* o = out + (size_t)ni * 16 * HWO + p;
#pragma unroll
  for (int co = 0; co < 16; ++co) {
    float acc = sb[co];
    const float* wp = sw + co * 27;
#pragma unroll
    for (int k = 0; k < 27; ++k) acc += wp[k] * in[k];
    o[(size_t)co * HWO] = acc >= 0.f ? acc : sa[co] * acc;
  }
}

// ---------------- implicit-GEMM conv via MFMA ----------
// AL=true : split-bf16 A (hi+lo), 3 MFMAs -> fp32-grade accuracy.
// AL=false: A truncated to bf16-hi only, 2 MFMAs -> halves A LDS (mask1 only; sigmoid-squashed).
template <int CIr1, int CIr2, int CIP, int KS, int CO, int SB, bool AL, bool PRELU>
__global__ void __launch_bounds__(256, 2)
conv_mfma_kernel(const float* __restrict__ in1, long s1,
                 const float* __restrict__ in2, long s2,
                 const __bf16* __restrict__ wBh, const __bf16* __restrict__ wBl,
                 const float* __restrict__ bias, const float* __restrict__ alpha,
                 float* __restrict__ out, long so) {
  constexpr int TR = 8;
  constexpr int TRH = TR + KS - 1;
  constexpr int TCH = 16 + KS - 1;
  constexpr int NPX = TRH * TCH;
  constexpr int NT = CO / 16;
  constexpr int KREAL = KS * KS * CIP;
  constexpr int KTOT = ((KREAL + 31) / 32) * 32;
  constexpr int NSLICE = KTOT / 32;
  constexpr int RCHUNK = KREAL / 8;
  constexpr int PAD = KS / 2;
  constexpr int CPC = CIP / 8;
  constexpr int NTY = HO / TR;
  constexpr int NTX = WO / 16;

  __shared__ __align__(16) __bf16 Ah[NPX * CIP];
  __shared__ __align__(16) __bf16 Al[AL ? NPX * CIP : 8];
  __shared__ __align__(16) __bf16 Bh[SB * NT * 512];
  __shared__ __align__(16) __bf16 Bl[SB * NT * 512];

  int tid = threadIdx.x;
  int bx = blockIdx.x;
  int b = bx / (NTY * NTX);
  int rem = bx % (NTY * NTX);
  int row0 = (rem / NTX) * TR;
  int col0 = (rem % NTX) * 16;

  for (int e = tid; e < NPX * CIP; e += 256) {
    int ci = e / NPX;
    int pxi = e % NPX;
    int y = pxi / TCH, x = pxi % TCH;
    int gy = row0 + y - PAD, gx = col0 + x - PAD;
    float v = 0.f;
    if (ci < CIr1 + CIr2 && gy >= 0 && gy < HO && gx >= 0 && gx < WO) {
      v = (ci < CIr1) ? in1[(size_t)b * s1 + (size_t)ci * HWO + gy * WO + gx]
                      : in2[(size_t)b * s2 + (size_t)(ci - CIr1) * HWO + gy * WO + gx];
    }
    __bf16 h = (__bf16)v;
    Ah[pxi * CIP + ci] = h;
    if (AL) Al[pxi * CIP + ci] = (__bf16)(v - (float)h);
  }

  int lane = tid & 63, wid = tid >> 6;

  f32x4 acc[2][NT];
  float aco[NT];
#pragma unroll
  for (int nt = 0; nt < NT; ++nt) {
    float bv = bias[nt * 16 + (lane & 15)];
    aco[nt] = PRELU ? alpha[nt * 16 + (lane & 15)] : 0.f;
    f32x4 z = {bv, bv, bv, bv};
    acc[0][nt] = z;
    acc[1][nt] = z;
  }

  const uint4* gBh = reinterpret_cast<const uint4*>(wBh);
  const uint4* gBl = reinterpret_cast<const uint4*>(wBl);
  uint4* lBh = reinterpret_cast<uint4*>(Bh);
  uint4* lBl = reinterpret_cast<uint4*>(Bl);

  for (int s0 = 0; s0 < NSLICE; s0 += SB) {
    if (s0 > 0) __syncthreads();
    constexpr int NU = SB * NT * 64;
    for (int u = tid; u < NU; u += 256) {
      lBh[u] = gBh[(size_t)s0 * NT * 64 + u];
      lBl[u] = gBl[(size_t)s0 * NT * 64 + u];
    }
    __syncthreads();
#pragma unroll
    for (int s = 0; s < SB; ++s) {
      int slice = s0 + s;
      bf16x8 bh[NT], bl[NT];
#pragma unroll
      for (int nt = 0; nt < NT; ++nt) {
        bh[nt] = __builtin_bit_cast(bf16x8, lBh[(s * NT + nt) * 64 + lane]);
        bl[nt] = __builtin_bit_cast(bf16x8, lBl[(s * NT + nt) * 64 + lane]);
      }
      int g = slice * 4 + (lane >> 4);
      if (g > RCHUNK - 1) g = RCHUNK - 1;
      int kpos = g / CPC;
      int ci0 = (g % CPC) * 8;
      int ky = kpos / KS, kx = kpos % KS;
      int xoff = ((lane & 15) + kx) * CIP + ci0;
#pragma unroll
      for (int mt = 0; mt < 2; ++mt) {
        int r = wid * 2 + mt;
        int addr = (r + ky) * TCH * CIP + xoff;
        bf16x8 ah = __builtin_bit_cast(bf16x8, *reinterpret_cast<const uint4*>(Ah + addr));
#pragma unroll
        for (int nt = 0; nt < NT; ++nt) {
          acc[mt][nt] = __builtin_amdgcn_mfma_f32_16x16x32_bf16(ah, bh[nt], acc[mt][nt], 0, 0, 0);
          acc[mt][nt] = __builtin_amdgcn_mfma_f32_16x16x32_bf16(ah, bl[nt], acc[mt][nt], 0, 0, 0);
        }
        if (AL) {
          bf16x8 al = __builtin_bit_cast(bf16x8, *reinterpret_cast<const uint4*>(Al + addr));
#pragma unroll
          for (int nt = 0; nt < NT; ++nt) {
            acc[mt][nt] = __builtin_amdgcn_mfma_f32_16x16x32_bf16(al, bh[nt], acc[mt][nt], 0, 0, 0);
          }
        }
      }
    }
  }

#pragma unroll
  for (int mt = 0; mt < 2; ++mt) {
    int gr = row0 + wid * 2 + mt;
#pragma unroll
    for (int nt = 0; nt < NT; ++nt) {
      int co = nt * 16 + (lane & 15);
      float* op = out + (size_t)b * so + (size_t)co * HWO + (size_t)gr * WO + col0 + (lane >> 4) * 4;
#pragma unroll
      for (int reg = 0; reg < 4; ++reg) {
        float v = acc[mt][nt][reg];
        if (PRELU) v = v >= 0.f ? v : aco[nt] * v;
        op[reg] = v;
      }
    }
  }
}

// ---------------- small generic 3x3 conv (kept for 16->1) ----------
template <int CI, int CO, bool PRELU>
__global__ void __launch_bounds__(256, 2)
conv3x3_kernel(const float* __restrict__ in, const float* __restrict__ w,
               const float* __restrict__ bias, const float* __restrict__ alpha,
               float* __restrict__ out, int B) {
  __shared__ float sw[CO * CI * 9];
  __shared__ float sb[CO];
  __shared__ float sa[CO];
  for (int idx = threadIdx.x; idx < CO * CI * 9; idx += blockDim.x) sw[idx] = w[idx];
  if (threadIdx.x < CO) {
    sb[threadIdx.x] = bias[threadIdx.x];
    sa[threadIdx.x] = PRELU ? alpha[threadIdx.x] : 0.f;
  }
  __syncthreads();
  int gid = blockIdx.x * blockDim.x + threadIdx.x;
  int total = B * HWO;
  if (gid >= total) return;
  int p = gid % HWO, b = gid / HWO;
  int i = p / WO, j = p % WO;
  const float* xb = in + (size_t)b * CI * HWO;
  float acc[CO];
#pragma unroll
  for (int co = 0; co < CO; ++co) acc[co] = sb[co];
  for (int ci = 0; ci < CI; ++ci) {
    const float* xc = xb + (size_t)ci * HWO;
    float taps[9];
    int q = 0;
#pragma unroll
    for (int ky = 0; ky < 3; ++ky) {
      int r = i + ky - 1;
#pragma unroll
      for (int kx = 0; kx < 3; ++kx) {
        int c = j + kx - 1;
        taps[q++] = (r >= 0 && r < HO && c >= 0 && c < WO) ? xc[(size_t)r * WO + c] : 0.f;
      }
    }
#pragma unroll
    for (int co = 0; co < CO; ++co) {
      const float* wp = sw + (co * CI + ci) * 9;
      float s = acc[co];
#pragma unroll
      for (int k = 0; k < 9; ++k) s += wp[k] * taps[k];
      acc[co] = s;
    }
  }
  float* ob = out + (size_t)b * CO * HWO + p;
#pragma unroll
  for (int co = 0; co < CO; ++co) {
    float v = acc[co];
    if (PRELU) v = v >= 0.f ? v : sa[co] * v;
    ob[(size_t)co * HWO] = v;
  }
}

// ---------------- forward splat: LDS-tiled, 512 threads ----------
// Round-9: 256-thread version was grid-limited (896 blocks x 4 waves = 14 waves/CU, occ 28%,
// VALU 9%, HBM 7% -> latency-bound). 512 threads doubles waves/CU at same LDS (27.6KB,
// wave-capped 4 blocks/CU) and halves per-thread dependent-chain length.
constexpr int FTS = 32;
constexpr int FRH = 8;
constexpr int FTH = FTS + 2 * FRH;   // 48
constexpr int FNTX = WO / FTS;       // 14
constexpr int FNTY = HO / FTS;       // 8
constexpr int FTPB = 512;

__global__ void __launch_bounds__(FTPB, 4)
fwarp_tile_kernel(const float* __restrict__ flow0, const float* __restrict__ flow1,
                  const float* __restrict__ flow2, const float* __restrict__ flow3,
                  const float* __restrict__ t1, const float* __restrict__ t2,
                  float* __restrict__ S /* 12u splat region, zeroed */) {
  __shared__ float acc[FTH * FTH * 3];
  int tid = threadIdx.x;
  for (int e = tid; e < FTH * FTH * 3; e += FTPB) acc[e] = 0.f;
  __syncthreads();

  const size_t u = (size_t)NB * HWO;
  int bx = blockIdx.x;
  int tile = bx % (FNTY * FNTX); bx /= (FNTY * FNTX);
  int n = bx % NB; bx /= NB;
  int ab = bx & 1;
  int side = bx >> 1;
  int row0 = (tile / FNTX) * FTS;
  int col0 = (tile % FNTX) * FTS;

  const float* flo = side ? (ab ? flow3 : flow2) : (ab ? flow1 : flow0);
  const float* t = side ? t2 : t1;
  float* basep = S + (size_t)side * 6 * u;
  float* imgw = basep + (size_t)ab * 2 * u;
  float* nw = basep + 4 * u + (size_t)ab * u;
  const float* flo0 = flo + ((size_t)n * 2 + 0) * HWI;
  const float* flo1 = flo + ((size_t)n * 2 + 1) * HWI;
  float* iw0 = imgw + ((size_t)n * 2 + 0) * HWO;
  float* iw1 = imgw + ((size_t)n * 2 + 1) * HWO;
  float* nwp = nw + (size_t)n * HWO;

#pragma unroll
  for (int k = 0; k < FTS * FTS / FTPB; ++k) {
    int pl = tid + k * FTPB;
    int ly = pl / FTS, lx = pl % FTS;
    int i = row0 + ly, j = col0 + lx;
    float f0 = 0.5f * ds_half(flo0, i, j);
    float f1 = 0.5f * ds_half(flo1, i, j);
    float tv = t[(size_t)n * HWO + i * WO + j];
    float s = ab ? (1.f - tv) : tv;
    float xr = s * f1;
    float yc = s * f0;
    float x1f = floorf(xr), y1f = floorf(yc);
#pragma unroll
    for (int dx = 0; dx < 2; ++dx)
#pragma unroll
      for (int dy = 0; dy < 2; ++dy) {
        float sx = x1f + (float)dx;
        float sy = y1f + (float)dy;
        float ddx = xr - sx, ddy = yc - sy;
        float wgt = expf(-(ddx * ddx + ddy * ddy));
        int r = (int)sx + i;
        int c = (int)sy + j;
        int lr = r - row0 + FRH, lc = c - col0 + FRH;
        if (lr >= 0 && lr < FTH && lc >= 0 && lc < FTH) {
          int cell = (lr * FTH + lc) * 3;
          atomicAdd(&acc[cell + 0], f0 * wgt);
          atomicAdd(&acc[cell + 1], f1 * wgt);
          atomicAdd(&acc[cell + 2], wgt);
        } else if (r >= 0 && r < HO && c >= 0 && c < WO) {
          size_t o = (size_t)r * WO + c;
          atomicAdd(iw0 + o, f0 * wgt);
          atomicAdd(iw1 + o, f1 * wgt);
          atomicAdd(nwp + o, wgt);
        }
      }
  }
  __syncthreads();
  for (int e = tid; e < FTH * FTH; e += FTPB) {
    int ly = e / FTH, lx = e % FTH;
    int r = row0 + ly - FRH, c = col0 + lx - FRH;
    if (r < 0 || r >= HO || c < 0 || c >= WO) continue;
    float v2 = acc[e * 3 + 2];
    if (v2 == 0.f) continue;
    size_t o = (size_t)r * WO + c;
    atomicAdd(iw0 + o, acc[e * 3 + 0]);
    atomicAdd(iw1 + o, acc[e * 3 + 1]);
    atomicAdd(nwp + o, v2);
  }
}

// combine -> ftL [NB][4][HWO] = (ft0l ch0,ch1, ft1l ch0,ch1); ftR likewise (ft1r, ft2r)
__global__ void cfr_all_kernel(const float* __restrict__ S,
                               const float* __restrict__ t1, const float* __restrict__ t2,
                               float* __restrict__ ftL, float* __restrict__ ftR) {
  const size_t u = (size_t)NB * HWO;
  int gid = blockIdx.x * blockDim.x + threadIdx.x;
  int total = 2 * NB * HWO;
  if (gid >= total) return;
  int side = gid / (NB * HWO);
  int rem = gid % (NB * HWO);
  int n = rem / HWO, p = rem % HWO;
  const float* base = S + (size_t)side * 6 * u;
  const float* f01w = base;
  const float* f10w = base + 2 * u;
  const float* n0 = base + 4 * u;
  const float* n1 = base + 5 * u;
  const float* t = side ? t2 : t1;
  float* ft = side ? ftR : ftL;
  size_t np = (size_t)n * HWO + p;
  float tv = t[np];
  float norm = (1.f - tv) * n0[np] + tv * n1[np];
  bool pos = norm > 0.f;
#pragma unroll
  for (int ch = 0; ch < 2; ++ch) {
    size_t sidx = ((size_t)n * 2 + ch) * HWO + p;
    float a = f01w[sidx];
    float b = f10w[sidx];
    float v0 = -(1.f - tv) * tv * a + tv * tv * b;
    float v1 = (1.f - tv) * (1.f - tv) * a - tv * (1.f - tv) * b;
    ft[((size_t)n * 4 + ch) * HWO + p]     = pos ? v0 / norm : v0;
    ft[((size_t)n * 4 + 2 + ch) * HWO + p] = pos ? v1 / norm : v1;
  }
}

// ---------------- backward warp + occlusion blend + final 1x1 conv ----------
DEV float sigmoidf_(float x) { return 1.f / (1.f + expf(-x)); }

DEV void bwarp16(const float* __restrict__ x /* [16][HWO] */, const float* __restrict__ flo /* [2][HWO] */,
                 int p, int i, int j, float* o) {
  float fx = flo[p];
  float fy = flo[HWO + p];
  float gx = (float)j + fx, gy = (float)i + fy;
  float nx = 2.f * gx / (float)(WO - 1) - 1.f;
  float ny = 2.f * gy / (float)(HO - 1) - 1.f;
  float px = ((nx + 1.f) * (float)WO - 1.f) * 0.5f;
  float py = ((ny + 1.f) * (float)HO - 1.f) * 0.5f;
  float cx = fminf(fmaxf(px, 0.f), (float)(WO - 1));
  float cy = fminf(fmaxf(py, 0.f), (float)(HO - 1));
  float x0f = floorf(cx), y0f = floorf(cy);
  float wx = cx - x0f, wy = cy - y0f;
  int x0i = (int)x0f; x0i = x0i < 0 ? 0 : (x0i > WO - 1 ? WO - 1 : x0i);
  int y0i = (int)y0f; y0i = y0i < 0 ? 0 : (y0i > HO - 1 ? HO - 1 : y0i);
  int x1i = x0i + 1 > WO - 1 ? WO - 1 : x0i + 1;
  int y1i = y0i + 1 > HO - 1 ? HO - 1 : y0i + 1;
  float fx0 = floorf(px), fy0 = floorf(py);
  float ux = px - fx0, uy = py - fy0;
  float WOf = (float)WO, HOf = (float)HO;
  float i00 = (fx0 >= 0.f && fx0 < WOf && fy0 >= 0.f && fy0 < HOf) ? 1.f : 0.f;
  float i10 = (fx0 + 1.f >= 0.f && fx0 + 1.f < WOf && fy0 >= 0.f && fy0 < HOf) ? 1.f : 0.f;
  float i01 = (fx0 >= 0.f && fx0 < WOf && fy0 + 1.f >= 0.f && fy0 + 1.f < HOf) ? 1.f : 0.f;
  float i11 = (fx0 + 1.f >= 0.f && fx0 + 1.f < WOf && fy0 + 1.f >= 0.f && fy0 + 1.f < HOf) ? 1.f : 0.f;
  float mv = (1.f - ux) * (1.f - uy) * i00 + ux * (1.f - uy) * i10
           + (1.f - ux) * uy * i01 + ux * uy * i11;
  float mask = mv >= 0.999f ? 1.f : 0.f;
  float w00 = (1.f - wx) * (1.f - wy), w10 = wx * (1.f - wy);
  float w01 = (1.f - wx) * wy, w11 = wx * wy;
  int a00 = y0i * WO + x0i, a10 = y0i * WO + x1i;
  int a01 = y1i * WO + x0i, a11 = y1i * WO + x1i;
#pragma unroll
  for (int c = 0; c < 16; ++c) {
    const float* xc = x + (size_t)c * HWO;
    o[c] = (w00 * xc[a00] + w10 * xc[a10] + w01 * xc[a01] + w11 * xc[a11]) * mask;
  }
}

__global__ void __launch_bounds__(256, 2)
blend_out_kernel(const float* __restrict__ xs /* [NB][48][HWO] */,
                 const float* __restrict__ ftL, const float* __restrict__ ftR,
                 const float* __restrict__ occl, const float* __restrict__ occr,
                 const float* __restrict__ t1, const float* __restrict__ t2,
                 const float* __restrict__ wm,
                 const float* __restrict__ fw, const float* __restrict__ fb,
                 const float* __restrict__ fa,
                 float* __restrict__ out /* [NB][16][HWO] */) {
  __shared__ float sw[512];
  __shared__ float sb[16];
  __shared__ float sa[16];
  for (int idx = threadIdx.x; idx < 512; idx += blockDim.x) sw[idx] = fw[idx];
  if (threadIdx.x < 16) { sb[threadIdx.x] = fb[threadIdx.x]; sa[threadIdx.x] = fa[threadIdx.x]; }
  __syncthreads();
  int gid = blockIdx.x * blockDim.x + threadIdx.x;
  int total = NB * HWO;
  if (gid >= total) return;
  int p = gid % HWO, n = gid / HWO;
  int i = p / WO, j = p % WO;
  size_t np = (size_t)n * HWO + p;
  float wmv = wm[np];
  const float* xs0 = xs + (size_t)n * 48 * HWO;
  const float* xs1 = xs0 + (size_t)16 * HWO;
  const float* xs2 = xs0 + (size_t)32 * HWO;
  const float* fl = ftL + (size_t)n * 4 * HWO;
  const float* fr = ftR + (size_t)n * 4 * HWO;
  float A[16], B[16];
  float bw0[16], bw1[16];
  {
    float t = t1[np];
    float o0 = sigmoidf_(occl[np]);
    float o1 = 1.f - o0;
    bwarp16(xs0, fl, p, i, j, bw0);
    bwarp16(xs1, fl + (size_t)2 * HWO, p, i, j, bw1);
    float c0 = (1.f - t) * o0, c1 = t * o1;
    float r = wmv / (c0 + c1);
#pragma unroll
    for (int c = 0; c < 16; ++c) A[c] = (c0 * bw0[c] + c1 * bw1[c]) * r;
  }
  {
    float t = t2[np];
    float o0 = sigmoidf_(occr[np]);
    float o1 = 1.f - o0;
    bwarp16(xs1, fr, p, i, j, bw0);
    bwarp16(xs2, fr + (size_t)2 * HWO, p, i, j, bw1);
    float c0 = (1.f - t) * o0, c1 = t * o1;
    float r = (1.f - wmv) / (c0 + c1);
#pragma unroll
    for (int c = 0; c < 16; ++c) B[c] = (c0 * bw0[c] + c1 * bw1[c]) * r;
  }
  float* ob = out + (size_t)n * 16 * HWO + p;
#pragma unroll
  for (int co = 0; co < 16; ++co) {
    float s = sb[co];
    const float* wp = sw + co * 32;
#pragma unroll
    for (int ci = 0; ci < 16; ++ci) s += wp[ci] * A[ci];
#pragma unroll
    for (int ci = 0; ci < 16; ++ci) s += wp[16 + ci] * B[ci];
    ob[(size_t)co * HWO] = s >= 0.f ? s : sa[co] * s;
  }
}

extern "C" void kernel_launch(void* const* d_in, const int* in_sizes, int n_in,
                              void* d_out, int out_size, void* d_ws, size_t ws_size,
                              hipStream_t stream) {
  const float* x0 = (const float*)d_in[0];
  const float* x1 = (const float*)d_in[1];
  const float* x2 = (const float*)d_in[2];
  const float* flw[4] = {(const float*)d_in[3], (const float*)d_in[4],
                         (const float*)d_in[5], (const float*)d_in[6]};
  const float* enc  = (const float*)d_in[7];
  const float* c_w1 = (const float*)d_in[8];
  const float* c_b1 = (const float*)d_in[9];
  const float* c_a1 = (const float*)d_in[10];
  const float* c_w2 = (const float*)d_in[11];
  const float* c_b2 = (const float*)d_in[12];
  const float* c_a2 = (const float*)d_in[13];
  const float* m_w1 = (const float*)d_in[14];
  const float* m_b1 = (const float*)d_in[15];
  const float* m_a1 = (const float*)d_in[16];
  const float* m_w2 = (const float*)d_in[17];
  const float* m_b2 = (const float*)d_in[18];
  const float* m_a2 = (const float*)d_in[19];
  const float* m_w3 = (const float*)d_in[20];
  const float* m_b3 = (const float*)d_in[21];
  const float* f_w  = (const float*)d_in[22];
  const float* f_b  = (const float*)d_in[23];
  const float* f_a  = (const float*)d_in[24];
  float* out = (float*)d_out;

  const size_t u = (size_t)NB * HWO;  // 229376 floats
  float* base = (float*)d_ws;
  size_t off = 0;
  auto alloc = [&](size_t nfl) { float* pp = base + off; off += nfl; return pp; };
  float* t1  = alloc(u);
  float* t2  = alloc(u);
  float* wmb = alloc(u);
  float* xs   = alloc(48 * u);  // [NB][48][HWO] convds output (n-major)
  float* xsc1 = alloc(48 * u);  // convds1 scratch; later mn1 (32u) + mn2 (16u)
  float* splat = alloc(12 * u); // [2 sides][imgwA 2u | imgwB 2u | nA u | nB u]
  float* ftL = alloc(4 * u);    // [NB][4][HWO] = ft0l, ft1l
  float* ftR = alloc(4 * u);    // [NB][4][HWO] = ft1r, ft2r
  float* occl = alloc(u);
  float* occr = alloc(u);
  __bf16* wB1h = (__bf16*)alloc(16384);  // mask1: KTOT=1024, CO=32 -> 32768 bf16
  __bf16* wB1l = (__bf16*)alloc(16384);
  __bf16* wB2h = (__bf16*)alloc(2304);   // mask2: KTOT=288, CO=16 -> 4608 bf16
  __bf16* wB2l = (__bf16*)alloc(2304);
  __bf16* wBch = (__bf16*)alloc(1280);   // convds2: KTOT=160, CO=16 -> 2560 bf16
  __bf16* wBcl = (__bf16*)alloc(1280);
  float* mn1 = xsc1;                  // [NB][32][HWO] = 32u
  float* mn2 = xsc1 + 32 * u;         // [NB][16][HWO] = 16u

  const int TPB = 256;
  auto NBLK = [](long long t) { return (unsigned)((t + 255) / 256); };

  // weight prep (tiny): split-bf16 + MFMA B-fragment swizzle
  prep_w_kernel<<<NBLK(1024 * 32), TPB, 0, stream>>>(m_w1, wB1h, wB1l, 32, 36, 40, 5, 1024);
  prep_w_kernel<<<NBLK(288 * 16), TPB, 0, stream>>>(m_w2, wB2h, wB2l, 16, 32, 32, 3, 288);
  prep_w_kernel<<<NBLK(160 * 16), TPB, 0, stream>>>(c_w2, wBch, wBcl, 16, 16, 16, 3, 160);

  ds_enc_kernel<<<NBLK((long long)NB * 3 * HWO), TPB, 0, stream>>>(enc, t1, t2, wmb);

  convds1_kernel<<<NBLK((long long)3 * NB * HWO), TPB, 0, stream>>>(x0, x1, x2, c_w1, c_b1, c_a1, xsc1);
  // convds2: 16->16 3x3 over 6 batches -> xs [NB][48][HWO]  (AL=true: full accuracy, LDS small)
  conv_mfma_kernel<16, 0, 16, 3, 16, 5, true, true><<<6 * 32 * 28, TPB, 0, stream>>>(
      xsc1, 16L * HWO, nullptr, 0, wBch, wBcl, c_b2, c_a2, xs, 16L * HWO);

  // flow splat path: LDS-tiled splat, 512-thread blocks (occupancy: round-9 28% -> ~2x)
  hipMemsetAsync(splat, 0, 12 * u * sizeof(float), stream);
  fwarp_tile_kernel<<<2 * 2 * NB * FNTY * FNTX, FTPB, 0, stream>>>(
      flw[0], flw[1], flw[2], flw[3], t1, t2, splat);
  cfr_all_kernel<<<NBLK((long long)2 * NB * HWO), TPB, 0, stream>>>(splat, t1, t2, ftL, ftR);

  // masknet left: input = xs[n][0:32] ++ ftL[n][0:4]
  // mask1: AL=false (2-MFMA, A-hi only) -> 35.6KB LDS -> 4 blocks/CU; SB=4 -> 8 stages
  conv_mfma_kernel<32, 4, 40, 5, 32, 4, false, true><<<NB * 32 * 28, TPB, 0, stream>>>(
      xs, 48L * HWO, ftL, 4L * HWO, wB1h, wB1l, m_b1, m_a1, mn1, 32L * HWO);
  conv_mfma_kernel<32, 0, 32, 3, 16, 3, true, true><<<NB * 32 * 28, TPB, 0, stream>>>(
      mn1, 32L * HWO, nullptr, 0, wB2h, wB2l, m_b2, m_a2, mn2, 16L * HWO);
  conv3x3_kernel<16, 1, false><<<NBLK((long long)NB * HWO), TPB, 0, stream>>>(mn2, m_w3, m_b3, m_b3, occl, NB);
  // masknet right: input = xs[n][16:48] ++ ftR[n][0:4]
  conv_mfma_kernel<32, 4, 40, 5, 32, 4, false, true><<<NB * 32 * 28, TPB, 0, stream>>>(
      xs + (size_t)16 * HWO, 48L * HWO, ftR, 4L * HWO, wB1h, wB1l, m_b1, m_a1, mn1, 32L * HWO);
  conv_mfma_kernel<32, 0, 32, 3, 16, 3, true, true><<<NB * 32 * 28, TPB, 0, stream>>>(
      mn1, 32L * HWO, nullptr, 0, wB2h, wB2l, m_b2, m_a2, mn2, 16L * HWO);
  conv3x3_kernel<16, 1, false><<<NBLK((long long)NB * HWO), TPB, 0, stream>>>(mn2, m_w3, m_b3, m_b3, occr, NB);

  // blend + fused final 1x1 -> d_out
  blend_out_kernel<<<NBLK((long long)NB * HWO), TPB, 0, stream>>>(
      xs, ftL, ftR, occl, occr, t1, t2, wmb, f_w, f_b, f_a, out);
}